// Round 12
// baseline (216.679 us; speedup 1.0000x reference)
//
#include <hip/hip_runtime.h>
#include <hip/hip_bf16.h>

typedef __attribute__((ext_vector_type(8))) short short8;
typedef __attribute__((ext_vector_type(4))) float f32x4;
typedef unsigned int uint;
typedef unsigned short ushort;

constexpr int BATCH = 4;
constexpr int CH    = 256;
constexpr int N     = 4096;   // 64*64
constexpr int DVC   = 768;
constexpr int CIN   = 1024;   // CH + DVC
constexpr int KC    = 512;    // 2*CH
constexpr int PBS   = 5 * 1024 * 1024;  // P per-batch stride (elements)
constexpr int QCH   = 32;     // colsum q-chunks

// ---------------- workspace layout (bytes) ----------------
constexpr size_t OFF_M    = 0;                       // 16384 f32
constexpr size_t OFF_INV  = 64ull << 10;             // 16384 f32
constexpr size_t OFF_VIS  = 128ull << 10;            // 16384 f32
constexpr size_t OFF_MAXV = 192ull << 10;            // 1 f32
constexpr size_t OFF_CNT  = 196ull << 10;            // 16 ints
constexpr size_t OFF_FGI  = 256ull << 10;            // 16384 int
constexpr size_t OFF_BGI  = 320ull << 10;            // 16384 int
constexpr size_t OFF_P2S  = 384ull << 10;            // 16384 int
constexpr size_t OFF_KMC  = 448ull << 10;            // 16384 f32
constexpr size_t OFF_PART = 1ull << 20;              // 4MB colsum partials
constexpr size_t OFF_KWB  = 5ull << 20;              // 512KB bf16
constexpr size_t OFF_FWB  = OFF_KWB + (512ull << 10);// 256KB bf16
constexpr size_t OFF_XT   = 6ull << 20;              // [b][n][256] bf16 = 8MB
constexpr size_t OFF_QC   = 38ull << 20;             // [b][qi][256] bf16 = 8MB
constexpr size_t OFF_KCC  = 46ull << 20;             // [b][ki][256] bf16 = 8MB
constexpr size_t OFF_XC   = 54ull << 20;             // [b][c][4096] bf16 = 8MB
constexpr size_t OFF_AFT  = 62ull << 20;             // [b][n][256] bf16 = 8MB
constexpr size_t OFF_P    = 70ull << 20;             // compact P bf16, 4 x PBS = 40MB

// ---------------- helpers ----------------
__device__ __forceinline__ ushort f2bf(float f) {
    __hip_bfloat16 h = __float2bfloat16(f);
    return __builtin_bit_cast(ushort, h);
}
__device__ __forceinline__ float bf2f(ushort u) {
    uint v = (uint)u << 16;
    return __builtin_bit_cast(float, v);
}

typedef const __attribute__((address_space(1))) uint* gptr_t;
typedef __attribute__((address_space(3))) uint* lptr_t;
__device__ __forceinline__ void gload_lds16(const void* g, void* l) {
    __builtin_amdgcn_global_load_lds((gptr_t)g, (lptr_t)l, 16, 0, 0);
}

// ---------------- shared GEMM mainloop ----------------
template<int WM, int WN>
__device__ __forceinline__ void gemm_core(
    const ushort* __restrict__ A0, int lda, int m0,
    const ushort* __restrict__ B0, int ldb0, int kend0,
    const ushort* __restrict__ B1, int ldb1,
    int n0, int K,
    ushort* AsL, ushort* BsL, f32x4 acc[4][4])
{
    constexpr int NW = WM * WN, BM = WM * 64, BN = WN * 64;
    const int t = threadIdx.x, lane = t & 63, wid = t >> 6;
    const int wm = (wid / WN) * 64, wn = (wid % WN) * 64;

    for (int k0 = 0; k0 < K; k0 += 64) {
        #pragma unroll
        for (int c = wid; c < BM / 8; c += NW) {
            const ushort* g = A0 + (size_t)(m0 + c * 8 + (lane >> 3)) * lda + (k0 + (lane & 7) * 8);
            gload_lds16(g, AsL + c * 512);
        }
        const ushort* Bsrc = (k0 < kend0) ? B0 : B1;
        const int ldb = (k0 < kend0) ? ldb0 : ldb1;
        const int kc  = (k0 < kend0) ? k0 : (k0 - kend0);
        #pragma unroll
        for (int c = wid; c < BN / 8; c += NW) {
            const ushort* g = Bsrc + (size_t)(n0 + c * 8 + (lane >> 3)) * ldb + (kc + (lane & 7) * 8);
            gload_lds16(g, BsL + c * 512);
        }
        __syncthreads();

        const int ra = wm + (lane & 15), rb = wn + (lane & 15), ko = (lane >> 4) * 8;
        #pragma unroll
        for (int kk = 0; kk < 64; kk += 32) {
            short8 a[4], b[4];
            #pragma unroll
            for (int i = 0; i < 4; i++) a[i] = *(const short8*)(AsL + (ra + i * 16) * 64 + kk + ko);
            #pragma unroll
            for (int j = 0; j < 4; j++) b[j] = *(const short8*)(BsL + (rb + j * 16) * 64 + kk + ko);
            #pragma unroll
            for (int i = 0; i < 4; i++)
                #pragma unroll
                for (int j = 0; j < 4; j++)
                    acc[i][j] = __builtin_amdgcn_mfma_f32_16x16x32_bf16(a[i], b[j], acc[i][j], 0, 0, 0);
        }
        __syncthreads();
    }
}

__device__ __forceinline__ void zero_acc(f32x4 acc[4][4]) {
    f32x4 z = {0.f, 0.f, 0.f, 0.f};
    #pragma unroll
    for (int i = 0; i < 4; i++)
        #pragma unroll
        for (int j = 0; j < 4; j++) acc[i][j] = z;
}

// ---------------- prep: maskpool + vis/maxv init + weight conversion ----------------
__global__ void k_prep(const float* __restrict__ mask, const float* __restrict__ Kw,
                       const float* __restrict__ fw, float* __restrict__ m,
                       float* __restrict__ vis, uint* __restrict__ maxv,
                       ushort* __restrict__ Kwb, ushort* __restrict__ fwb)
{
    const int bid = blockIdx.x;
    if (bid < 64) {
        int idx = bid * 256 + threadIdx.x;
        int b = idx >> 12, p = idx & 4095;
        int y = p >> 6, x = p & 63;
        const float* base = mask + (size_t)b * 512 * 512 + (y * 8) * 512 + x * 8;
        float mx = 0.f;
        for (int dy = 0; dy < 8; dy++) {
            #pragma unroll
            for (int dx = 0; dx < 8; dx++) mx = fmaxf(mx, base[dy * 512 + dx]);
        }
        m[idx] = (mx > 0.f) ? 1.f : 0.f;
        vis[idx] = 0.f;
        if (idx == 0) maxv[0] = 0u;
    } else {
        int i = (bid - 64) * 256 + threadIdx.x;
        if (i < CH * CIN) Kwb[i] = f2bf(Kw[i]);
        else              fwb[i - CH * CIN] = f2bf(fw[i - CH * CIN]);
    }
}

__global__ __launch_bounds__(256) void k_scan(
    const float* __restrict__ m, int* __restrict__ fgi, int* __restrict__ bgi,
    int* __restrict__ counts, float* __restrict__ kmc, int* __restrict__ p2s)
{
    const int b = blockIdx.x, t = threadIdx.x;
    const float* mb = m + (size_t)b * N;
    __shared__ int sfg[256], sbg[256];
    bool isf[16];
    int cf = 0, cb_ = 0;
    #pragma unroll
    for (int j = 0; j < 16; j++) {
        bool f = mb[t * 16 + j] != 0.f;
        isf[j] = f; cf += f ? 1 : 0; cb_ += f ? 0 : 1;
    }
    sfg[t] = cf; sbg[t] = cb_;
    __syncthreads();
    for (int off = 1; off < 256; off <<= 1) {
        int vf = (t >= off) ? sfg[t - off] : 0;
        int vb = (t >= off) ? sbg[t - off] : 0;
        __syncthreads();
        sfg[t] += vf; sbg[t] += vb;
        __syncthreads();
    }
    int basef = sfg[t] - cf, baseb = sbg[t] - cb_;
    int nfg = sfg[255], nbg = sbg[255];
    #pragma unroll
    for (int j = 0; j < 16; j++) {
        int p = t * 16 + j;
        if (isf[j]) { fgi[b * N + basef] = p; p2s[b * N + p] = basef | (1 << 30); basef++; }
        else        { bgi[b * N + baseb] = p; p2s[b * N + p] = baseb; baseb++; }
    }
    if (t == 0) {
        counts[b * 4 + 0] = nfg;
        counts[b * 4 + 1] = (nfg + 127) & ~127;
        counts[b * 4 + 2] = nbg;
        counts[b * 4 + 3] = (nbg + 127) & ~127;
    }
    for (int j = t; j < N; j += 256) kmc[b * N + j] = (j < nbg) ? 1.f : 0.f;
}

// ---------------- transpose x: f32 [b][C][4096] -> bf16 [b][4096][C] ----------------
__global__ __launch_bounds__(256) void k_tr(const float* __restrict__ src,
                                            ushort* __restrict__ dst, int C)
{
    __shared__ float Ls[64][65];
    const int ci0 = blockIdx.x * 64, n0 = blockIdx.y * 64, b = blockIdx.z;
    const float* s = src + (size_t)b * C * 4096;
    const int t = threadIdx.x;
    #pragma unroll
    for (int it = 0; it < 4; it++) {
        int f4 = it * 256 + t;
        int r = f4 >> 4, c4 = f4 & 15;
        float4 v = *(const float4*)(s + (size_t)(ci0 + r) * 4096 + n0 + c4 * 4);
        Ls[r][c4 * 4 + 0] = v.x; Ls[r][c4 * 4 + 1] = v.y;
        Ls[r][c4 * 4 + 2] = v.z; Ls[r][c4 * 4 + 3] = v.w;
    }
    __syncthreads();
    ushort* d = dst + (size_t)b * 4096 * C;
    #pragma unroll
    for (int it = 0; it < 8; it++) {
        int p = it * 256 + t;
        int rn = p >> 5, cc2 = p & 31;
        uint val = (uint)f2bf(Ls[cc2 * 2][rn]) | ((uint)f2bf(Ls[cc2 * 2 + 1][rn]) << 16);
        *(uint*)(d + (size_t)(n0 + rn) * C + ci0 + cc2 * 2) = val;
    }
}

// gather-transpose V compact from bf16 xT: xc[b][c][j] = xT[b][bgi[j]][c]
__global__ __launch_bounds__(256) void k_vgather(
    const ushort* __restrict__ xT, const int* __restrict__ bgi,
    const int* __restrict__ counts, ushort* __restrict__ xc)
{
    __shared__ ushort Xs[64][264];
    const int b = blockIdx.y;
    const int ki0 = blockIdx.x * 64;
    const int nbg = counts[b * 4 + 2], nbgp = counts[b * 4 + 3];
    if (ki0 >= nbgp) return;
    const int t = threadIdx.x;
    const int j = t >> 2, part = t & 3;
    const int ki = ki0 + j;
    if (ki < nbg) {
        const ushort* src = xT + ((size_t)b * N + bgi[(size_t)b * N + ki]) * CH + part * 64;
        #pragma unroll
        for (int q = 0; q < 8; q++)
            *(uint4*)&Xs[j][part * 64 + q * 8] = *(const uint4*)(src + q * 8);
    } else {
        uint4 z = {0, 0, 0, 0};
        #pragma unroll
        for (int q = 0; q < 8; q++)
            *(uint4*)&Xs[j][part * 64 + q * 8] = z;
    }
    __syncthreads();
    const int c = t;
    ushort* dst = xc + ((size_t)b * CH + c) * N + ki0;
    uint w[32];
    #pragma unroll
    for (int jj = 0; jj < 32; jj++)
        w[jj] = (uint)Xs[2 * jj][c] | ((uint)Xs[2 * jj + 1][c] << 16);
    #pragma unroll
    for (int q = 0; q < 8; q++) {
        uint4 o = { w[q * 4], w[q * 4 + 1], w[q * 4 + 2], w[q * 4 + 3] };
        *(uint4*)(dst + q * 8) = o;
    }
}

// ---------------- feats GEMM (dense, BN=32; fused dvt-transpose + bias/L2-norm/scatter)
__global__ __launch_bounds__(256) void k_feats(
    const ushort* __restrict__ Kwb, const ushort* __restrict__ xT,
    const float* __restrict__ dvt, const float* __restrict__ Kb,
    const int* __restrict__ p2s, ushort* __restrict__ Qc, ushort* __restrict__ Kc)
{
    __shared__ ushort As[256 * 64];   // 32 KB
    __shared__ ushort Bs[32 * 64];    // 4 KB
    __shared__ float  Ls[64][33];     // 8.25 KB
    __shared__ float  red[4][32];
    const int b = blockIdx.z;
    const int n0 = blockIdx.x * 32;
    const int t = threadIdx.x, lane = t & 63, wid = t >> 6;
    const ushort* xTb = xT + (size_t)b * N * CH;
    const float* dvb = dvt + (size_t)b * DVC * N;
    f32x4 acc[4][2];
    {
        f32x4 z = {0.f, 0.f, 0.f, 0.f};
        #pragma unroll
        for (int i = 0; i < 4; i++) { acc[i][0] = z; acc[i][1] = z; }
    }

    for (int k0 = 0; k0 < 256; k0 += 64) {
        #pragma unroll
        for (int c = wid; c < 32; c += 4)
            gload_lds16(Kwb + (size_t)(c * 8 + (lane >> 3)) * CIN + k0 + (lane & 7) * 8, As + c * 512);
        gload_lds16(xTb + (size_t)(n0 + wid * 8 + (lane >> 3)) * CH + k0 + (lane & 7) * 8, Bs + wid * 512);
        __syncthreads();
        const int ra = wid * 64 + (lane & 15), rb = lane & 15, ko = (lane >> 4) * 8;
        #pragma unroll
        for (int kk = 0; kk < 64; kk += 32) {
            short8 a[4], bb[2];
            #pragma unroll
            for (int i = 0; i < 4; i++) a[i] = *(const short8*)(As + (ra + i * 16) * 64 + kk + ko);
            #pragma unroll
            for (int j = 0; j < 2; j++) bb[j] = *(const short8*)(Bs + (rb + j * 16) * 64 + kk + ko);
            #pragma unroll
            for (int i = 0; i < 4; i++)
                #pragma unroll
                for (int j = 0; j < 2; j++)
                    acc[i][j] = __builtin_amdgcn_mfma_f32_16x16x32_bf16(a[i], bb[j], acc[i][j], 0, 0, 0);
        }
        __syncthreads();
    }
    for (int k0 = 256; k0 < 1024; k0 += 64) {
        #pragma unroll
        for (int c = wid; c < 32; c += 4)
            gload_lds16(Kwb + (size_t)(c * 8 + (lane >> 3)) * CIN + k0 + (lane & 7) * 8, As + c * 512);
        const float* dsrc = dvb + (size_t)(k0 - 256) * N + n0;
        #pragma unroll
        for (int it = 0; it < 2; it++) {
            int f4 = it * 256 + t;
            int r = f4 >> 3, c4 = (f4 & 7) * 4;
            float4 v = *(const float4*)(dsrc + (size_t)r * N + c4);
            Ls[r][c4 + 0] = v.x; Ls[r][c4 + 1] = v.y;
            Ls[r][c4 + 2] = v.z; Ls[r][c4 + 3] = v.w;
        }
        __syncthreads();
        {
            int rn = t & 31;
            int ks = (t >> 5) * 8;
            #pragma unroll
            for (int j2 = 0; j2 < 4; j2++) {
                int kk = ks + j2 * 2;
                uint val = (uint)f2bf(Ls[kk][rn]) | ((uint)f2bf(Ls[kk + 1][rn]) << 16);
                int idx = (rn * 64 + kk) ^ ((rn & 7) << 3);
                *(uint*)(Bs + idx) = val;
            }
        }
        __syncthreads();
        const int ra = wid * 64 + (lane & 15), rb = lane & 15, ko = (lane >> 4) * 8;
        #pragma unroll
        for (int kk = 0; kk < 64; kk += 32) {
            short8 a[4], bb[2];
            #pragma unroll
            for (int i = 0; i < 4; i++) a[i] = *(const short8*)(As + (ra + i * 16) * 64 + kk + ko);
            #pragma unroll
            for (int j = 0; j < 2; j++) {
                int row = rb + j * 16;
                int idx = (row * 64 + kk + ko) ^ ((row & 7) << 3);
                bb[j] = *(const short8*)(Bs + idx);
            }
            #pragma unroll
            for (int i = 0; i < 4; i++)
                #pragma unroll
                for (int j = 0; j < 2; j++)
                    acc[i][j] = __builtin_amdgcn_mfma_f32_16x16x32_bf16(a[i], bb[j], acc[i][j], 0, 0, 0);
        }
        __syncthreads();
    }

    const int wm = wid * 64;
    float sj[2] = {0.f, 0.f};
    #pragma unroll
    for (int i = 0; i < 4; i++) {
        int mbase = wm + i * 16 + ((lane >> 4) * 4);
        float4 bias = *(const float4*)(Kb + mbase);
        #pragma unroll
        for (int j = 0; j < 2; j++) {
            acc[i][j][0] += bias.x; acc[i][j][1] += bias.y;
            acc[i][j][2] += bias.z; acc[i][j][3] += bias.w;
            sj[j] += acc[i][j][0] * acc[i][j][0] + acc[i][j][1] * acc[i][j][1]
                   + acc[i][j][2] * acc[i][j][2] + acc[i][j][3] * acc[i][j][3];
        }
    }
    #pragma unroll
    for (int j = 0; j < 2; j++) {
        sj[j] += __shfl_xor(sj[j], 16);
        sj[j] += __shfl_xor(sj[j], 32);
    }
    if (lane < 16) {
        red[wid][lane]      = sj[0];
        red[wid][16 + lane] = sj[1];
    }
    __syncthreads();
    const int* pb = p2s + (size_t)b * N + n0;
    #pragma unroll
    for (int j = 0; j < 2; j++) {
        int n = j * 16 + (lane & 15);
        float s = red[0][n] + red[1][n] + red[2][n] + red[3][n];
        float invn = 1.f / (sqrtf(s) + 1e-8f);
        int sl = pb[n];
        ushort* dst = (sl & (1 << 30)) ? Qc : Kc;
        int slot = sl & 0x3FFFFFFF;
        ushort* drow = dst + ((size_t)b * N + slot) * CH;
        #pragma unroll
        for (int i = 0; i < 4; i++) {
            int mbase = wm + i * 16 + ((lane >> 4) * 4);
            ushort4 o = { f2bf(acc[i][j][0] * invn), f2bf(acc[i][j][1] * invn),
                          f2bf(acc[i][j][2] * invn), f2bf(acc[i][j][3] * invn) };
            *(ushort4*)(drow + mbase) = o;
        }
    }
}

// ---------------- fused attention: QK^T + exp + rowsum + PV + normalize + scatter ----------------
// block = (b, 32 fg-slots). Loops over bg-key tiles of 64; K and V time-share one 32KB LDS buffer.
// Writes: P (for colsum), inv (for colsum), AFt (normalized PV output, scattered dense).
__global__ __launch_bounds__(256) void k_attn(
    const ushort* __restrict__ Qc, const ushort* __restrict__ Kc,
    const ushort* __restrict__ xc, const float* __restrict__ kmc,
    const int* __restrict__ fgi, const int* __restrict__ counts,
    ushort* __restrict__ P, float* __restrict__ inv, ushort* __restrict__ AFt)
{
    const int b = blockIdx.y;
    const int n0 = blockIdx.x * 32;
    const int nfg = counts[b * 4], nfgp = counts[b * 4 + 1], nbgp = counts[b * 4 + 3];
    if (n0 >= nfgp) return;
    __shared__ ushort Qs[32 * 256];   // 16 KB
    __shared__ ushort SH[64 * 256];   // 32 KB, K tile then V tile (time-shared)
    __shared__ ushort Ps[32 * 64];    // 4 KB
    __shared__ float  rs[4][32];
    __shared__ float  invs[32];
    const int t = threadIdx.x, lane = t & 63, wid = t >> 6;

    // stage Q tile (32 rows x 256 ch)
    const ushort* Qb = Qc + ((size_t)b * N + n0) * CH;
    #pragma unroll
    for (int c = wid; c < 16; c += 4)
        gload_lds16(Qb + (size_t)(c * 2 + (lane >> 5)) * CH + (lane & 31) * 8, Qs + c * 512);
    if (lane < 32) rs[wid][lane] = 0.f;
    __syncthreads();

    // preload Q fragments: 8 k-chunks x 2 q-halves (64 VGPR)
    short8 qf[8][2];
    #pragma unroll
    for (int kc = 0; kc < 8; kc++)
        #pragma unroll
        for (int i = 0; i < 2; i++)
            qf[kc][i] = *(const short8*)(Qs + (size_t)(i * 16 + (lane & 15)) * 256 + kc * 32 + (lane >> 4) * 8);

    f32x4 acc_o[4][2];
    { f32x4 z = {0.f,0.f,0.f,0.f};
      #pragma unroll
      for (int i = 0; i < 4; i++) { acc_o[i][0] = z; acc_o[i][1] = z; } }

    const ushort* Kcb = Kc + (size_t)b * N * CH;
    const ushort* xcb = xc + (size_t)b * CH * N;
    ushort* Pb = P + (size_t)b * PBS;
    const int kq = wid * 16;
    const int nsteps = nbgp >> 6;

    for (int s = 0; s < nsteps; s++) {
        const int k0s = s * 64;
        __syncthreads();                       // B1: prev PV / P-write done with SH, Ps
        #pragma unroll
        for (int c = wid; c < 32; c += 4)      // stage K (64 x 256)
            gload_lds16(Kcb + (size_t)(k0s + c * 2 + (lane >> 5)) * CH + (lane & 31) * 8, SH + c * 512);
        __syncthreads();                       // B2: K ready

        f32x4 acc_s[2];
        { f32x4 z = {0.f,0.f,0.f,0.f}; acc_s[0] = z; acc_s[1] = z; }
        #pragma unroll
        for (int kc = 0; kc < 8; kc++) {
            short8 bk = *(const short8*)(SH + (size_t)(kq + (lane & 15)) * 256 + kc * 32 + (lane >> 4) * 8);
            acc_s[0] = __builtin_amdgcn_mfma_f32_16x16x32_bf16(qf[kc][0], bk, acc_s[0], 0, 0, 0);
            acc_s[1] = __builtin_amdgcn_mfma_f32_16x16x32_bf16(qf[kc][1], bk, acc_s[1], 0, 0, 0);
        }
        __syncthreads();                       // B3: QK reads of SH done
        #pragma unroll
        for (int c = wid; c < 32; c += 4)      // stage V (256 x 64)
            gload_lds16(xcb + (size_t)(c * 8 + (lane >> 3)) * N + k0s + (lane & 7) * 8, SH + c * 512);

        // epilogue (overlaps V stage): exp, Ps, deterministic rowsum
        float km = kmc[(size_t)b * N + k0s + kq + (lane & 15)];
        #pragma unroll
        for (int i = 0; i < 2; i++) {
            float rsum[4];
            #pragma unroll
            for (int r = 0; r < 4; r++) {
                float p = (km != 0.f) ? __expf(20.f * acc_s[i][r] - 20.f) : 0.f;
                int q = i * 16 + (lane >> 4) * 4 + r;
                Ps[q * 64 + kq + (lane & 15)] = f2bf(p);
                float ss = p;
                ss += __shfl_xor(ss, 1); ss += __shfl_xor(ss, 2);
                ss += __shfl_xor(ss, 4); ss += __shfl_xor(ss, 8);
                rsum[r] = ss;
            }
            if ((lane & 15) == 0) {
                #pragma unroll
                for (int r = 0; r < 4; r++)
                    rs[wid][i * 16 + (lane >> 4) * 4 + r] += rsum[r];
            }
        }
        __syncthreads();                       // B4: V ready + Ps complete
        {                                      // P global write (1 uint4/thread)
            int row = t >> 3, c8 = (t & 7) * 8;
            *(uint4*)(Pb + (size_t)(n0 + row) * nbgp + k0s + c8) = *(const uint4*)(Ps + row * 64 + c8);
        }
        #pragma unroll
        for (int kc2 = 0; kc2 < 2; kc2++) {    // PV: 256c x 32q over kb=64
            short8 av[4], bp[2];
            #pragma unroll
            for (int i = 0; i < 4; i++)
                av[i] = *(const short8*)(SH + (size_t)(wid * 64 + i * 16 + (lane & 15)) * 64 + kc2 * 32 + (lane >> 4) * 8);
            #pragma unroll
            for (int j = 0; j < 2; j++)
                bp[j] = *(const short8*)(Ps + (size_t)(j * 16 + (lane & 15)) * 64 + kc2 * 32 + (lane >> 4) * 8);
            #pragma unroll
            for (int i = 0; i < 4; i++)
                #pragma unroll
                for (int j = 0; j < 2; j++)
                    acc_o[i][j] = __builtin_amdgcn_mfma_f32_16x16x32_bf16(av[i], bp[j], acc_o[i][j], 0, 0, 0);
        }
    }
    __syncthreads();
    if (t < 32) {
        float ssum = rs[0][t] + rs[1][t] + rs[2][t] + rs[3][t];
        float iv = (ssum > 0.f) ? 1.f / ssum : 0.f;
        invs[t] = iv;
        inv[(size_t)b * N + n0 + t] = iv;
    }
    __syncthreads();
    const int* fb = fgi + (size_t)b * N;
    #pragma unroll
    for (int j = 0; j < 2; j++) {
        int qi = n0 + j * 16 + (lane & 15);
        if (qi < nfg) {
            float iq = invs[j * 16 + (lane & 15)];
            int qp = fb[qi];
            ushort* Ab = AFt + ((size_t)b * N + qp) * CH;
            #pragma unroll
            for (int i = 0; i < 4; i++) {
                int mbase = wid * 64 + i * 16 + (lane >> 4) * 4;
                ushort4 o = { f2bf(acc_o[i][j][0] * iq), f2bf(acc_o[i][j][1] * iq),
                              f2bf(acc_o[i][j][2] * iq), f2bf(acc_o[i][j][3] * iq) };
                *(ushort4*)(Ab + mbase) = o;
            }
        }
    }
}

// ---------------- fused GEMM + blend (dense) ----------------
__global__ __launch_bounds__(128) void k_fused(
    const ushort* __restrict__ fwb, const ushort* __restrict__ AFt,
    const ushort* __restrict__ xT, const float* __restrict__ x,
    const float* __restrict__ m_, float* __restrict__ out)
{
    __shared__ ushort SH[(64 + 128) * 64];
    const int b = blockIdx.z;
    const int n0 = blockIdx.x * 128, m0 = blockIdx.y * 64;
    const int lane = threadIdx.x & 63, wid = threadIdx.x >> 6;
    const int wn = (wid & 1) * 64;
    f32x4 acc[4][4]; zero_acc(acc);
    gemm_core<1, 2>(fwb, KC, m0,
                    AFt + (size_t)b * N * CH, CH, CH,
                    xT + (size_t)b * N * CH, CH,
                    n0, KC, SH, SH + 64 * 64, acc);
    const float* mb = m_ + (size_t)b * N;
    const float* xc_ = x + (size_t)b * CH * N;
    float* ob = out + (size_t)b * CH * N;
    #pragma unroll
    for (int j = 0; j < 4; j++) {
        int n = n0 + wn + j * 16 + (lane & 15);
        float mv = mb[n];
        #pragma unroll
        for (int i = 0; i < 4; i++) {
            int mbase = m0 + i * 16 + ((lane >> 4) * 4);
            #pragma unroll
            for (int r = 0; r < 4; r++) {
                int c = mbase + r;
                ob[(size_t)c * N + n] = (mv != 0.f) ? acc[i][j][r] : xc_[(size_t)c * N + n];
            }
        }
    }
}

// ---------------- colsum (coalesced, row-major sweep) ----------------
__global__ __launch_bounds__(256) void k_colsum(
    const ushort* __restrict__ P, const float* __restrict__ inv,
    const int* __restrict__ counts, float* __restrict__ part)
{
    const int b = blockIdx.z, qc = blockIdx.y, t = threadIdx.x;
    const int nfg = counts[b * 4], nbgp = counts[b * 4 + 3];
    const int ki0 = blockIdx.x * 2048 + t * 8;
    if (ki0 >= nbgp) return;
    const int qchunk = (nfg + QCH - 1) / QCH;
    const int q0 = qc * qchunk, q1 = min(q0 + qchunk, nfg);
    const ushort* base = P + (size_t)b * PBS + (size_t)q0 * nbgp + ki0;
    const float* ib = inv + (size_t)b * N;
    float acc[8] = {};
    int q = q0;
    for (; q + 4 <= q1; q += 4) {
        uint4 v0 = *(const uint4*)(base);
        uint4 v1 = *(const uint4*)(base + (size_t)nbgp);
        uint4 v2 = *(const uint4*)(base + 2 * (size_t)nbgp);
        uint4 v3 = *(const uint4*)(base + 3 * (size_t)nbgp);
        float i0 = ib[q], i1 = ib[q + 1], i2 = ib[q + 2], i3 = ib[q + 3];
        const ushort* u0 = (const ushort*)&v0;
        const ushort* u1 = (const ushort*)&v1;
        const ushort* u2 = (const ushort*)&v2;
        const ushort* u3 = (const ushort*)&v3;
        #pragma unroll
        for (int e = 0; e < 8; e++)
            acc[e] += bf2f(u0[e]) * i0 + bf2f(u1[e]) * i1 + bf2f(u2[e]) * i2 + bf2f(u3[e]) * i3;
        base += 4 * (size_t)nbgp;
    }
    for (; q < q1; q++) {
        uint4 v = *(const uint4*)(base);
        float iq = ib[q];
        const ushort* u = (const ushort*)&v;
        #pragma unroll
        for (int e = 0; e < 8; e++) acc[e] += bf2f(u[e]) * iq;
        base += (size_t)nbgp;
    }
    float* pp = part + (size_t)qc * (BATCH * N) + (size_t)b * N + ki0;
    float4 o0 = {acc[0], acc[1], acc[2], acc[3]};
    float4 o1 = {acc[4], acc[5], acc[6], acc[7]};
    *(float4*)(pp)     = o0;
    *(float4*)(pp + 4) = o1;
}

// reduce colsum partials, scatter to vis, track global max (uint atomicMax, vis>=0)
__global__ void k_colsum_final(const float* __restrict__ part, const int* __restrict__ bgi,
                               const int* __restrict__ counts, float* __restrict__ vis,
                               uint* __restrict__ maxv)
{
    int g = blockIdx.x * 256 + threadIdx.x;
    int b = g >> 12, ki = g & 4095;
    int t = threadIdx.x;
    float s = 0.f;
    if (ki < counts[b * 4 + 2]) {
        #pragma unroll
        for (int j = 0; j < QCH; j++) s += part[(size_t)j * (BATCH * N) + g];
        vis[(size_t)b * N + bgi[(size_t)b * N + ki]] = s;
    }
    __shared__ float red[256];
    red[t] = s; __syncthreads();
    for (int st = 128; st > 0; st >>= 1) { if (t < st) red[t] = fmaxf(red[t], red[t + st]); __syncthreads(); }
    if (t == 0) atomicMax(maxv, __float_as_uint(red[0]));
}

__global__ void k_attmask(const float* __restrict__ vis, const float* __restrict__ maxv,
                          float* __restrict__ amask)
{
    int idx = blockIdx.x * 256 + threadIdx.x;
    int b = idx >> 18;
    int r = idx & 262143;
    int Y = r >> 9, X = r & 511;
    amask[idx] = vis[(size_t)b * N + (Y >> 3) * 64 + (X >> 3)] / maxv[0];
}

// ---------------- launch ----------------
extern "C" void kernel_launch(void* const* d_in, const int* in_sizes, int n_in,
                              void* d_out, int out_size, void* d_ws, size_t ws_size,
                              hipStream_t stream)
{
    const float* x    = (const float*)d_in[0];
    const float* mask = (const float*)d_in[1];
    const float* dvt  = (const float*)d_in[2];
    const float* Kw   = (const float*)d_in[3];
    const float* Kb   = (const float*)d_in[4];
    const float* fw   = (const float*)d_in[5];
    float* out = (float*)d_out;

    char* ws = (char*)d_ws;
    float*  m    = (float*)(ws + OFF_M);
    float*  inv  = (float*)(ws + OFF_INV);
    float*  vis  = (float*)(ws + OFF_VIS);
    float*  maxv = (float*)(ws + OFF_MAXV);
    int*    cnt  = (int*)  (ws + OFF_CNT);
    int*    fgi  = (int*)  (ws + OFF_FGI);
    int*    bgi  = (int*)  (ws + OFF_BGI);
    int*    p2s  = (int*)  (ws + OFF_P2S);
    float*  kmc  = (float*)(ws + OFF_KMC);
    float*  part = (float*)(ws + OFF_PART);
    ushort* Kwb  = (ushort*)(ws + OFF_KWB);
    ushort* fwb  = (ushort*)(ws + OFF_FWB);
    ushort* xT   = (ushort*)(ws + OFF_XT);
    ushort* Qc   = (ushort*)(ws + OFF_QC);
    ushort* Kcc  = (ushort*)(ws + OFF_KCC);
    ushort* xc   = (ushort*)(ws + OFF_XC);
    ushort* AFt  = (ushort*)(ws + OFF_AFT);
    ushort* P    = (ushort*)(ws + OFF_P);

    k_prep       <<<dim3(64 + (CH * CIN + CH * KC) / 256), 256, 0, stream>>>(
                     mask, Kw, fw, m, vis, (uint*)maxv, Kwb, fwb);
    k_scan       <<<dim3(BATCH), 256, 0, stream>>>(m, fgi, bgi, cnt, kmc, p2s);
    k_tr         <<<dim3(CH / 64, 64, BATCH), 256, 0, stream>>>(x, xT, CH);
    k_feats      <<<dim3(N / 32, 1, BATCH), 256, 0, stream>>>(Kwb, xT, dvt, Kb, p2s, Qc, Kcc);
    k_vgather    <<<dim3(N / 64, BATCH), 256, 0, stream>>>(xT, bgi, cnt, xc);
    k_attn       <<<dim3(N / 32, BATCH), 256, 0, stream>>>(Qc, Kcc, xc, kmc, fgi, cnt, P, inv, AFt);
    k_colsum     <<<dim3(2, QCH, BATCH), 256, 0, stream>>>(P, inv, cnt, part);
    k_colsum_final<<<dim3(BATCH * N / 256), 256, 0, stream>>>(part, bgi, cnt, vis, (uint*)maxv);
    k_fused      <<<dim3(N / 128, CH / 64, BATCH), 128, 0, stream>>>(fwb, AFt, xT, x, m, out);
    k_attmask    <<<dim3(BATCH * 512 * 512 / 256), 256, 0, stream>>>(vis, maxv, out + (size_t)BATCH * CH * N);
}

// Round 13
// 170.007 us; speedup vs baseline: 1.2745x; 1.2745x over previous
//
#include <hip/hip_runtime.h>
#include <hip/hip_bf16.h>

typedef __attribute__((ext_vector_type(8))) short short8;
typedef __attribute__((ext_vector_type(4))) float f32x4;
typedef unsigned int uint;
typedef unsigned short ushort;

constexpr int BATCH = 4;
constexpr int CH    = 256;
constexpr int N     = 4096;   // 64*64
constexpr int DVC   = 768;
constexpr int CIN   = 1024;   // CH + DVC
constexpr int KC    = 512;    // 2*CH
constexpr int PBS   = 5 * 1024 * 1024;  // P per-batch stride (elements)
constexpr int QCH   = 32;     // colsum q-chunks
constexpr int SPLITK = 4;     // att_fore K-split

// ---------------- workspace layout (bytes) ----------------
constexpr size_t OFF_M    = 0;                       // 16384 f32
constexpr size_t OFF_INV  = 64ull << 10;             // 16384 f32
constexpr size_t OFF_VIS  = 128ull << 10;            // 16384 f32
constexpr size_t OFF_MAXV = 192ull << 10;            // 1 f32
constexpr size_t OFF_CNT  = 196ull << 10;            // 16 ints
constexpr size_t OFF_FGI  = 256ull << 10;            // 16384 int
constexpr size_t OFF_BGI  = 320ull << 10;            // 16384 int
constexpr size_t OFF_P2S  = 384ull << 10;            // 16384 int
constexpr size_t OFF_KMC  = 448ull << 10;            // 16384 f32
constexpr size_t OFF_PART = 1ull << 20;              // 4MB partials
constexpr size_t OFF_KWB  = 5ull << 20;              // 512KB bf16
constexpr size_t OFF_FWB  = OFF_KWB + (512ull << 10);// 256KB bf16
constexpr size_t OFF_XT   = 6ull << 20;              // [b][n][256] bf16 = 8MB
constexpr size_t OFF_QC   = 38ull << 20;             // [b][qi][256] bf16 = 8MB
constexpr size_t OFF_KCC  = 46ull << 20;             // [b][ki][256] bf16 = 8MB
constexpr size_t OFF_XC   = 54ull << 20;             // [b][c][4096] bf16 = 8MB
constexpr size_t OFF_AFT  = 62ull << 20;             // [b][n][256] bf16 = 8MB
constexpr size_t OFF_P    = 70ull << 20;             // compact P bf16, 4 x PBS = 40MB
constexpr size_t OFF_AFP  = 110ull << 20;            // bf16 partials [sk][b][qi][c] = 32MB

// ---------------- helpers ----------------
__device__ __forceinline__ ushort f2bf(float f) {
    __hip_bfloat16 h = __float2bfloat16(f);
    return __builtin_bit_cast(ushort, h);
}
__device__ __forceinline__ float bf2f(ushort u) {
    uint v = (uint)u << 16;
    return __builtin_bit_cast(float, v);
}

typedef const __attribute__((address_space(1))) uint* gptr_t;
typedef __attribute__((address_space(3))) uint* lptr_t;
__device__ __forceinline__ void gload_lds16(const void* g, void* l) {
    __builtin_amdgcn_global_load_lds((gptr_t)g, (lptr_t)l, 16, 0, 0);
}

// ---------------- shared GEMM mainloop ----------------
template<int WM, int WN>
__device__ __forceinline__ void gemm_core(
    const ushort* __restrict__ A0, int lda, int m0,
    const ushort* __restrict__ B0, int ldb0, int kend0,
    const ushort* __restrict__ B1, int ldb1,
    int n0, int K,
    ushort* AsL, ushort* BsL, f32x4 acc[4][4])
{
    constexpr int NW = WM * WN, BM = WM * 64, BN = WN * 64;
    const int t = threadIdx.x, lane = t & 63, wid = t >> 6;
    const int wm = (wid / WN) * 64, wn = (wid % WN) * 64;

    for (int k0 = 0; k0 < K; k0 += 64) {
        #pragma unroll
        for (int c = wid; c < BM / 8; c += NW) {
            const ushort* g = A0 + (size_t)(m0 + c * 8 + (lane >> 3)) * lda + (k0 + (lane & 7) * 8);
            gload_lds16(g, AsL + c * 512);
        }
        const ushort* Bsrc = (k0 < kend0) ? B0 : B1;
        const int ldb = (k0 < kend0) ? ldb0 : ldb1;
        const int kc  = (k0 < kend0) ? k0 : (k0 - kend0);
        #pragma unroll
        for (int c = wid; c < BN / 8; c += NW) {
            const ushort* g = Bsrc + (size_t)(n0 + c * 8 + (lane >> 3)) * ldb + (kc + (lane & 7) * 8);
            gload_lds16(g, BsL + c * 512);
        }
        __syncthreads();

        const int ra = wm + (lane & 15), rb = wn + (lane & 15), ko = (lane >> 4) * 8;
        #pragma unroll
        for (int kk = 0; kk < 64; kk += 32) {
            short8 a[4], b[4];
            #pragma unroll
            for (int i = 0; i < 4; i++) a[i] = *(const short8*)(AsL + (ra + i * 16) * 64 + kk + ko);
            #pragma unroll
            for (int j = 0; j < 4; j++) b[j] = *(const short8*)(BsL + (rb + j * 16) * 64 + kk + ko);
            #pragma unroll
            for (int i = 0; i < 4; i++)
                #pragma unroll
                for (int j = 0; j < 4; j++)
                    acc[i][j] = __builtin_amdgcn_mfma_f32_16x16x32_bf16(a[i], b[j], acc[i][j], 0, 0, 0);
        }
        __syncthreads();
    }
}

__device__ __forceinline__ void zero_acc(f32x4 acc[4][4]) {
    f32x4 z = {0.f, 0.f, 0.f, 0.f};
    #pragma unroll
    for (int i = 0; i < 4; i++)
        #pragma unroll
        for (int j = 0; j < 4; j++) acc[i][j] = z;
}

// ---------------- mask + compaction ----------------
__global__ void k_maskpool(const float* __restrict__ mask, float* __restrict__ m,
                           float* __restrict__ vis, uint* __restrict__ maxv)
{
    int idx = blockIdx.x * 256 + threadIdx.x;
    int b = idx >> 12, p = idx & 4095;
    int y = p >> 6, x = p & 63;
    const float* base = mask + (size_t)b * 512 * 512 + (y * 8) * 512 + x * 8;
    float mx = 0.f;
    for (int dy = 0; dy < 8; dy++) {
        #pragma unroll
        for (int dx = 0; dx < 8; dx++) mx = fmaxf(mx, base[dy * 512 + dx]);
    }
    m[idx] = (mx > 0.f) ? 1.f : 0.f;
    vis[idx] = 0.f;
    if (idx == 0) maxv[0] = 0u;
}

__global__ __launch_bounds__(256) void k_scan(
    const float* __restrict__ m, int* __restrict__ fgi, int* __restrict__ bgi,
    int* __restrict__ counts, float* __restrict__ kmc, int* __restrict__ p2s)
{
    const int b = blockIdx.x, t = threadIdx.x;
    const float* mb = m + (size_t)b * N;
    __shared__ int sfg[256], sbg[256];
    bool isf[16];
    int cf = 0, cb_ = 0;
    #pragma unroll
    for (int j = 0; j < 16; j++) {
        bool f = mb[t * 16 + j] != 0.f;
        isf[j] = f; cf += f ? 1 : 0; cb_ += f ? 0 : 1;
    }
    sfg[t] = cf; sbg[t] = cb_;
    __syncthreads();
    for (int off = 1; off < 256; off <<= 1) {
        int vf = (t >= off) ? sfg[t - off] : 0;
        int vb = (t >= off) ? sbg[t - off] : 0;
        __syncthreads();
        sfg[t] += vf; sbg[t] += vb;
        __syncthreads();
    }
    int basef = sfg[t] - cf, baseb = sbg[t] - cb_;
    int nfg = sfg[255], nbg = sbg[255];
    #pragma unroll
    for (int j = 0; j < 16; j++) {
        int p = t * 16 + j;
        if (isf[j]) { fgi[b * N + basef] = p; p2s[b * N + p] = basef | (1 << 30); basef++; }
        else        { bgi[b * N + baseb] = p; p2s[b * N + p] = baseb; baseb++; }
    }
    if (t == 0) {
        counts[b * 4 + 0] = nfg;
        counts[b * 4 + 1] = (nfg + 127) & ~127;
        counts[b * 4 + 2] = nbg;
        counts[b * 4 + 3] = (nbg + 127) & ~127;
    }
    for (int j = t; j < N; j += 256) kmc[b * N + j] = (j < nbg) ? 1.f : 0.f;
}

// ---------------- weight/feature prep ----------------
__global__ void k_wconv(const float* __restrict__ Kw, const float* __restrict__ fw,
                        ushort* __restrict__ Kwb, ushort* __restrict__ fwb)
{
    int i = blockIdx.x * 256 + threadIdx.x;
    if (i < CH * CIN) Kwb[i] = f2bf(Kw[i]);
    else              fwb[i - CH * CIN] = f2bf(fw[i - CH * CIN]);
}

__global__ __launch_bounds__(256) void k_tr(const float* __restrict__ src,
                                            ushort* __restrict__ dst, int C)
{
    __shared__ float Ls[64][65];
    const int ci0 = blockIdx.x * 64, n0 = blockIdx.y * 64, b = blockIdx.z;
    const float* s = src + (size_t)b * C * 4096;
    const int t = threadIdx.x;
    #pragma unroll
    for (int it = 0; it < 4; it++) {
        int f4 = it * 256 + t;
        int r = f4 >> 4, c4 = f4 & 15;
        float4 v = *(const float4*)(s + (size_t)(ci0 + r) * 4096 + n0 + c4 * 4);
        Ls[r][c4 * 4 + 0] = v.x; Ls[r][c4 * 4 + 1] = v.y;
        Ls[r][c4 * 4 + 2] = v.z; Ls[r][c4 * 4 + 3] = v.w;
    }
    __syncthreads();
    ushort* d = dst + (size_t)b * 4096 * C;
    #pragma unroll
    for (int it = 0; it < 8; it++) {
        int p = it * 256 + t;
        int rn = p >> 5, cc2 = p & 31;
        uint val = (uint)f2bf(Ls[cc2 * 2][rn]) | ((uint)f2bf(Ls[cc2 * 2 + 1][rn]) << 16);
        *(uint*)(d + (size_t)(n0 + rn) * C + ci0 + cc2 * 2) = val;
    }
}

// gather-transpose V compact from bf16 xT: xc[b][c][j] = xT[b][bgi[j]][c]
__global__ __launch_bounds__(256) void k_vgather(
    const ushort* __restrict__ xT, const int* __restrict__ bgi,
    const int* __restrict__ counts, ushort* __restrict__ xc)
{
    __shared__ ushort Xs[64][264];
    const int b = blockIdx.y;
    const int ki0 = blockIdx.x * 64;
    const int nbg = counts[b * 4 + 2], nbgp = counts[b * 4 + 3];
    if (ki0 >= nbgp) return;
    const int t = threadIdx.x;
    const int j = t >> 2, part = t & 3;
    const int ki = ki0 + j;
    if (ki < nbg) {
        const ushort* src = xT + ((size_t)b * N + bgi[(size_t)b * N + ki]) * CH + part * 64;
        #pragma unroll
        for (int q = 0; q < 8; q++)
            *(uint4*)&Xs[j][part * 64 + q * 8] = *(const uint4*)(src + q * 8);
    } else {
        uint4 z = {0, 0, 0, 0};
        #pragma unroll
        for (int q = 0; q < 8; q++)
            *(uint4*)&Xs[j][part * 64 + q * 8] = z;
    }
    __syncthreads();
    const int c = t;
    ushort* dst = xc + ((size_t)b * CH + c) * N + ki0;
    uint w[32];
    #pragma unroll
    for (int jj = 0; jj < 32; jj++)
        w[jj] = (uint)Xs[2 * jj][c] | ((uint)Xs[2 * jj + 1][c] << 16);
    #pragma unroll
    for (int q = 0; q < 8; q++) {
        uint4 o = { w[q * 4], w[q * 4 + 1], w[q * 4 + 2], w[q * 4 + 3] };
        *(uint4*)(dst + q * 8) = o;
    }
}

// ---------------- feats GEMM (dense, fused dvt-transpose + bias/L2-norm/scatter) ----------------
__global__ __launch_bounds__(256) void k_feats(
    const ushort* __restrict__ Kwb, const ushort* __restrict__ xT,
    const float* __restrict__ dvt, const float* __restrict__ Kb,
    const int* __restrict__ p2s, ushort* __restrict__ Qc, ushort* __restrict__ Kc)
{
    __shared__ ushort As[256 * 64];   // 32 KB
    __shared__ ushort Bs[64 * 64];    // 8 KB
    __shared__ float  Ls[64][65];     // 16.25 KB (f32 transpose staging)
    __shared__ float  red[4][64];
    const int b = blockIdx.z;
    const int n0 = blockIdx.x * 64;
    const int t = threadIdx.x, lane = t & 63, wid = t >> 6;
    const ushort* xTb = xT + (size_t)b * N * CH;
    const float* dvb = dvt + (size_t)b * DVC * N;
    f32x4 acc[4][4]; zero_acc(acc);

    // phase 1: k = 0..255, B from xT (linear LDS)
    for (int k0 = 0; k0 < 256; k0 += 64) {
        #pragma unroll
        for (int c = wid; c < 32; c += 4)
            gload_lds16(Kwb + (size_t)(c * 8 + (lane >> 3)) * CIN + k0 + (lane & 7) * 8, As + c * 512);
        #pragma unroll
        for (int c = wid; c < 8; c += 4)
            gload_lds16(xTb + (size_t)(n0 + c * 8 + (lane >> 3)) * CH + k0 + (lane & 7) * 8, Bs + c * 512);
        __syncthreads();
        const int ra = wid * 64 + (lane & 15), rb = lane & 15, ko = (lane >> 4) * 8;
        #pragma unroll
        for (int kk = 0; kk < 64; kk += 32) {
            short8 a[4], bb[4];
            #pragma unroll
            for (int i = 0; i < 4; i++) a[i] = *(const short8*)(As + (ra + i * 16) * 64 + kk + ko);
            #pragma unroll
            for (int j = 0; j < 4; j++) bb[j] = *(const short8*)(Bs + (rb + j * 16) * 64 + kk + ko);
            #pragma unroll
            for (int i = 0; i < 4; i++)
                #pragma unroll
                for (int j = 0; j < 4; j++)
                    acc[i][j] = __builtin_amdgcn_mfma_f32_16x16x32_bf16(a[i], bb[j], acc[i][j], 0, 0, 0);
        }
        __syncthreads();
    }
    // phase 2: k = 256..1023, B transposed in-kernel from dvt f32, XOR-swizzled
    for (int k0 = 256; k0 < 1024; k0 += 64) {
        #pragma unroll
        for (int c = wid; c < 32; c += 4)
            gload_lds16(Kwb + (size_t)(c * 8 + (lane >> 3)) * CIN + k0 + (lane & 7) * 8, As + c * 512);
        const float* dsrc = dvb + (size_t)(k0 - 256) * N + n0;
        #pragma unroll
        for (int it = 0; it < 4; it++) {
            int f4 = it * 256 + t;
            int r = f4 >> 4, c4 = (f4 & 15) * 4;
            float4 v = *(const float4*)(dsrc + (size_t)r * N + c4);
            Ls[r][c4 + 0] = v.x; Ls[r][c4 + 1] = v.y;
            Ls[r][c4 + 2] = v.z; Ls[r][c4 + 3] = v.w;
        }
        __syncthreads();
        {
            int rn = t >> 2;            // n row 0..63
            int ks = (t & 3) * 16;      // k start
            #pragma unroll
            for (int j2 = 0; j2 < 8; j2++) {
                int kk = ks + j2 * 2;
                uint val = (uint)f2bf(Ls[kk][rn]) | ((uint)f2bf(Ls[kk + 1][rn]) << 16);
                int idx = (rn * 64 + kk) ^ ((rn & 7) << 3);
                *(uint*)(Bs + idx) = val;
            }
        }
        __syncthreads();
        const int ra = wid * 64 + (lane & 15), rb = lane & 15, ko = (lane >> 4) * 8;
        #pragma unroll
        for (int kk = 0; kk < 64; kk += 32) {
            short8 a[4], bb[4];
            #pragma unroll
            for (int i = 0; i < 4; i++) a[i] = *(const short8*)(As + (ra + i * 16) * 64 + kk + ko);
            #pragma unroll
            for (int j = 0; j < 4; j++) {
                int row = rb + j * 16;
                int idx = (row * 64 + kk + ko) ^ ((row & 7) << 3);
                bb[j] = *(const short8*)(Bs + idx);
            }
            #pragma unroll
            for (int i = 0; i < 4; i++)
                #pragma unroll
                for (int j = 0; j < 4; j++)
                    acc[i][j] = __builtin_amdgcn_mfma_f32_16x16x32_bf16(a[i], bb[j], acc[i][j], 0, 0, 0);
        }
        __syncthreads();
    }

    // epilogue: bias, per-position L2 norm (cross-wave), scatter to Qc/Kc
    const int wm = wid * 64;
    float sj[4] = {0.f, 0.f, 0.f, 0.f};
    #pragma unroll
    for (int i = 0; i < 4; i++) {
        int mbase = wm + i * 16 + ((lane >> 4) * 4);
        float4 bias = *(const float4*)(Kb + mbase);
        #pragma unroll
        for (int j = 0; j < 4; j++) {
            acc[i][j][0] += bias.x; acc[i][j][1] += bias.y;
            acc[i][j][2] += bias.z; acc[i][j][3] += bias.w;
            sj[j] += acc[i][j][0] * acc[i][j][0] + acc[i][j][1] * acc[i][j][1]
                   + acc[i][j][2] * acc[i][j][2] + acc[i][j][3] * acc[i][j][3];
        }
    }
    #pragma unroll
    for (int j = 0; j < 4; j++) {
        sj[j] += __shfl_xor(sj[j], 16);
        sj[j] += __shfl_xor(sj[j], 32);
    }
    if (lane < 16) {
        #pragma unroll
        for (int j = 0; j < 4; j++) red[wid][j * 16 + lane] = sj[j];
    }
    __syncthreads();
    const int* pb = p2s + (size_t)b * N + n0;
    #pragma unroll
    for (int j = 0; j < 4; j++) {
        int n = j * 16 + (lane & 15);
        float s = red[0][n] + red[1][n] + red[2][n] + red[3][n];
        float invn = 1.f / (sqrtf(s) + 1e-8f);
        int sl = pb[n];
        ushort* dst = (sl & (1 << 30)) ? Qc : Kc;
        int slot = sl & 0x3FFFFFFF;
        ushort* drow = dst + ((size_t)b * N + slot) * CH;
        #pragma unroll
        for (int i = 0; i < 4; i++) {
            int mbase = wm + i * 16 + ((lane >> 4) * 4);
            ushort4 o = { f2bf(acc[i][j][0] * invn), f2bf(acc[i][j][1] * invn),
                          f2bf(acc[i][j][2] * invn), f2bf(acc[i][j][3] * invn) };
            *(ushort4*)(drow + mbase) = o;
        }
    }
}

// ---------------- score GEMM (compact, 128q x 64k tiles, 2 waves) ----------------
__global__ __launch_bounds__(128) void k_score(
    const ushort* __restrict__ Qc, const ushort* __restrict__ Kc,
    const float* __restrict__ kmc, const int* __restrict__ counts,
    ushort* __restrict__ P)
{
    const int b = blockIdx.z;
    const int nfgp = counts[b * 4 + 1], nbgp = counts[b * 4 + 3];
    const int m0 = blockIdx.y * 128;   // q tile
    const int n0 = blockIdx.x * 64;    // k tile
    if (m0 >= nfgp || n0 >= nbgp) return;
    __shared__ ushort SH[(128 + 64) * 64];
    const int t = threadIdx.x, lane = t & 63, wid = t >> 6;
    const ushort* Qb = Qc + (size_t)b * N * CH;
    const ushort* Kb_ = Kc + (size_t)b * N * CH;
    f32x4 acc[4][4]; zero_acc(acc);
    gemm_core<2, 1>(Qb, CH, m0, Kb_, CH, CH, Kb_, CH, n0, CH, SH, SH + 128 * 64, acc);

    const int wm = wid * 64;
    float km[4];
    #pragma unroll
    for (int j = 0; j < 4; j++) km[j] = kmc[(size_t)b * N + n0 + j * 16 + (lane & 15)];

    ushort* Cs = SH;   // 128 x 64 repack
    #pragma unroll
    for (int i = 0; i < 4; i++) {
        int rbase = wm + i * 16 + ((lane >> 4) * 4);
        #pragma unroll
        for (int j = 0; j < 4; j++) {
            int cl = j * 16 + (lane & 15);
            #pragma unroll
            for (int r = 0; r < 4; r++) {
                float p = (km[j] != 0.f) ? __expf(20.f * acc[i][j][r] - 20.f) : 0.f;
                Cs[(rbase + r) * 64 + cl] = f2bf(p);
            }
        }
    }
    __syncthreads();
    ushort* Pb = P + (size_t)b * PBS;
    #pragma unroll
    for (int it = 0; it < 8; it++) {
        int v8 = it * 128 + t;
        int row = v8 >> 3, c8 = (v8 & 7) * 8;
        *(uint4*)(Pb + (size_t)(m0 + row) * nbgp + n0 + c8) = *(const uint4*)(Cs + row * 64 + c8);
    }
}

// rowsum -> inv[qi] (compact, wave per row)
__global__ __launch_bounds__(256) void k_rowsum(
    const ushort* __restrict__ P, const int* __restrict__ counts,
    float* __restrict__ inv)
{
    const int t = threadIdx.x, lane = t & 63, wid = t >> 6;
    const int g = blockIdx.x * 4 + wid;
    const int b = g >> 12, qi = g & 4095;
    const int nfgp = counts[b * 4 + 1], nbgp = counts[b * 4 + 3];
    if (qi >= nfgp) return;
    const ushort* row = P + (size_t)b * PBS + (size_t)qi * nbgp;
    float s = 0.f;
    for (int it = 0; it < 8; it++) {
        int base = it * 512 + lane * 8;
        if (base < nbgp) {
            uint4 v = *(const uint4*)(row + base);
            const ushort* u = (const ushort*)&v;
            #pragma unroll
            for (int e = 0; e < 8; e++) s += bf2f(u[e]);
        }
    }
    #pragma unroll
    for (int mm = 1; mm < 64; mm <<= 1) s += __shfl_xor(s, mm);
    if (lane == 0) inv[g] = (s > 0.f) ? 1.f / s : 0.f;
}

// ---------------- PV GEMM (compact, BM=256, split-K bf16 partials) ----------------
__global__ __launch_bounds__(256) void k_att_fore(
    const ushort* __restrict__ xc, const ushort* __restrict__ P,
    const int* __restrict__ counts, ushort* __restrict__ AFp)
{
    const int b = blockIdx.z & (BATCH - 1);
    const int sk = blockIdx.z / BATCH;
    const int nfgp = counts[b * 4 + 1], nbgp = counts[b * 4 + 3];
    const int n0 = blockIdx.x * 64;    // qi tile
    if (n0 >= nfgp) return;
    const int kchunk = ((nbgp / 64 + SPLITK - 1) / SPLITK) * 64;
    const int k0s = sk * kchunk;
    const int len = min(kchunk, nbgp - k0s);

    const int lane = threadIdx.x & 63, wid = threadIdx.x >> 6;
    f32x4 acc[4][4]; zero_acc(acc);
    if (len > 0) {
        __shared__ ushort SH[(256 + 64) * 64];
        const ushort* Pb = P + (size_t)b * PBS + k0s;
        gemm_core<4, 1>(xc + (size_t)b * CH * N + k0s, N, 0,
                        Pb, nbgp, 1 << 30, Pb, nbgp,
                        n0, len, SH, SH + 256 * 64, acc);
    }
    ushort* Ap = AFp + ((size_t)(sk * BATCH + b) * N) * CH;
    const int wm = wid * 64;
    #pragma unroll
    for (int j = 0; j < 4; j++) {
        int qi = n0 + j * 16 + (lane & 15);
        #pragma unroll
        for (int i = 0; i < 4; i++) {
            int mbase = wm + i * 16 + ((lane >> 4) * 4);
            ushort4 o = { f2bf(acc[i][j][0]), f2bf(acc[i][j][1]),
                          f2bf(acc[i][j][2]), f2bf(acc[i][j][3]) };
            *(ushort4*)(Ap + (size_t)qi * CH + mbase) = o;
        }
    }
}

// reduce bf16 partials, scale by inv, scatter to dense AFt (bf16)
__global__ __launch_bounds__(256) void k_afreduce(
    const ushort* __restrict__ AFp, const float* __restrict__ inv,
    const int* __restrict__ fgi, const int* __restrict__ counts,
    ushort* __restrict__ AFt)
{
    const int t = threadIdx.x, lane = t & 63, wid = t >> 6;
    const int g = blockIdx.x * 4 + wid;       // b*N + qi
    const int b = g >> 12, qi = g & 4095;
    if (qi >= counts[b * 4]) return;          // nfg
    const size_t rowoff = ((size_t)b * N + qi) * CH + lane * 4;
    float s0 = 0.f, s1 = 0.f, s2 = 0.f, s3 = 0.f;
    #pragma unroll
    for (int sk = 0; sk < SPLITK; sk++) {
        ushort4 v = *(const ushort4*)(AFp + (size_t)sk * BATCH * N * CH + rowoff);
        s0 += bf2f(v.x); s1 += bf2f(v.y); s2 += bf2f(v.z); s3 += bf2f(v.w);
    }
    float iq = inv[g];
    int q = fgi[g];
    ushort4 o = { f2bf(s0 * iq), f2bf(s1 * iq), f2bf(s2 * iq), f2bf(s3 * iq) };
    *(ushort4*)(AFt + ((size_t)b * N + q) * CH + lane * 4) = o;
}

// ---------------- fused GEMM + blend (dense) ----------------
__global__ __launch_bounds__(128) void k_fused(
    const ushort* __restrict__ fwb, const ushort* __restrict__ AFt,
    const ushort* __restrict__ xT, const float* __restrict__ x,
    const float* __restrict__ m_, float* __restrict__ out)
{
    __shared__ ushort SH[(64 + 128) * 64];
    const int b = blockIdx.z;
    const int n0 = blockIdx.x * 128, m0 = blockIdx.y * 64;
    const int lane = threadIdx.x & 63, wid = threadIdx.x >> 6;
    const int wn = (wid & 1) * 64;
    f32x4 acc[4][4]; zero_acc(acc);
    gemm_core<1, 2>(fwb, KC, m0,
                    AFt + (size_t)b * N * CH, CH, CH,
                    xT + (size_t)b * N * CH, CH,
                    n0, KC, SH, SH + 64 * 64, acc);
    const float* mb = m_ + (size_t)b * N;
    const float* xc_ = x + (size_t)b * CH * N;
    float* ob = out + (size_t)b * CH * N;
    #pragma unroll
    for (int j = 0; j < 4; j++) {
        int n = n0 + wn + j * 16 + (lane & 15);
        float mv = mb[n];
        #pragma unroll
        for (int i = 0; i < 4; i++) {
            int mbase = m0 + i * 16 + ((lane >> 4) * 4);
            #pragma unroll
            for (int r = 0; r < 4; r++) {
                int c = mbase + r;
                ob[(size_t)c * N + n] = (mv != 0.f) ? acc[i][j][r] : xc_[(size_t)c * N + n];
            }
        }
    }
}

// ---------------- colsum (coalesced, row-major sweep) ----------------
__global__ __launch_bounds__(256) void k_colsum(
    const ushort* __restrict__ P, const float* __restrict__ inv,
    const int* __restrict__ counts, float* __restrict__ part)
{
    const int b = blockIdx.z, qc = blockIdx.y, t = threadIdx.x;
    const int nfg = counts[b * 4], nbgp = counts[b * 4 + 3];
    const int ki0 = blockIdx.x * 2048 + t * 8;
    if (ki0 >= nbgp) return;
    const int qchunk = (nfg + QCH - 1) / QCH;
    const int q0 = qc * qchunk, q1 = min(q0 + qchunk, nfg);
    const ushort* base = P + (size_t)b * PBS + (size_t)q0 * nbgp + ki0;
    const float* ib = inv + (size_t)b * N;
    float acc[8] = {};
    int q = q0;
    for (; q + 4 <= q1; q += 4) {
        uint4 v0 = *(const uint4*)(base);
        uint4 v1 = *(const uint4*)(base + (size_t)nbgp);
        uint4 v2 = *(const uint4*)(base + 2 * (size_t)nbgp);
        uint4 v3 = *(const uint4*)(base + 3 * (size_t)nbgp);
        float i0 = ib[q], i1 = ib[q + 1], i2 = ib[q + 2], i3 = ib[q + 3];
        const ushort* u0 = (const ushort*)&v0;
        const ushort* u1 = (const ushort*)&v1;
        const ushort* u2 = (const ushort*)&v2;
        const ushort* u3 = (const ushort*)&v3;
        #pragma unroll
        for (int e = 0; e < 8; e++)
            acc[e] += bf2f(u0[e]) * i0 + bf2f(u1[e]) * i1 + bf2f(u2[e]) * i2 + bf2f(u3[e]) * i3;
        base += 4 * (size_t)nbgp;
    }
    for (; q < q1; q++) {
        uint4 v = *(const uint4*)(base);
        float iq = ib[q];
        const ushort* u = (const ushort*)&v;
        #pragma unroll
        for (int e = 0; e < 8; e++) acc[e] += bf2f(u[e]) * iq;
        base += (size_t)nbgp;
    }
    float* pp = part + (size_t)qc * (BATCH * N) + (size_t)b * N + ki0;
    float4 o0 = {acc[0], acc[1], acc[2], acc[3]};
    float4 o1 = {acc[4], acc[5], acc[6], acc[7]};
    *(float4*)(pp)     = o0;
    *(float4*)(pp + 4) = o1;
}

// reduce colsum partials, scatter to vis, track global max (uint atomicMax, vis>=0)
__global__ void k_colsum_final(const float* __restrict__ part, const int* __restrict__ bgi,
                               const int* __restrict__ counts, float* __restrict__ vis,
                               uint* __restrict__ maxv)
{
    int g = blockIdx.x * 256 + threadIdx.x;
    int b = g >> 12, ki = g & 4095;
    int t = threadIdx.x;
    float s = 0.f;
    if (ki < counts[b * 4 + 2]) {
        #pragma unroll
        for (int j = 0; j < QCH; j++) s += part[(size_t)j * (BATCH * N) + g];
        vis[(size_t)b * N + bgi[(size_t)b * N + ki]] = s;
    }
    __shared__ float red[256];
    red[t] = s; __syncthreads();
    for (int st = 128; st > 0; st >>= 1) { if (t < st) red[t] = fmaxf(red[t], red[t + st]); __syncthreads(); }
    if (t == 0) atomicMax(maxv, __float_as_uint(red[0]));
}

__global__ void k_attmask(const float* __restrict__ vis, const float* __restrict__ maxv,
                          float* __restrict__ amask)
{
    int idx = blockIdx.x * 256 + threadIdx.x;
    int b = idx >> 18;
    int r = idx & 262143;
    int Y = r >> 9, X = r & 511;
    amask[idx] = vis[(size_t)b * N + (Y >> 3) * 64 + (X >> 3)] / maxv[0];
}

// ---------------- launch ----------------
extern "C" void kernel_launch(void* const* d_in, const int* in_sizes, int n_in,
                              void* d_out, int out_size, void* d_ws, size_t ws_size,
                              hipStream_t stream)
{
    const float* x    = (const float*)d_in[0];
    const float* mask = (const float*)d_in[1];
    const float* dvt  = (const float*)d_in[2];
    const float* Kw   = (const float*)d_in[3];
    const float* Kb   = (const float*)d_in[4];
    const float* fw   = (const float*)d_in[5];
    float* out = (float*)d_out;

    char* ws = (char*)d_ws;
    float*  m    = (float*)(ws + OFF_M);
    float*  inv  = (float*)(ws + OFF_INV);
    float*  vis  = (float*)(ws + OFF_VIS);
    float*  maxv = (float*)(ws + OFF_MAXV);
    int*    cnt  = (int*)  (ws + OFF_CNT);
    int*    fgi  = (int*)  (ws + OFF_FGI);
    int*    bgi  = (int*)  (ws + OFF_BGI);
    int*    p2s  = (int*)  (ws + OFF_P2S);
    float*  kmc  = (float*)(ws + OFF_KMC);
    float*  part = (float*)(ws + OFF_PART);
    ushort* Kwb  = (ushort*)(ws + OFF_KWB);
    ushort* fwb  = (ushort*)(ws + OFF_FWB);
    ushort* xT   = (ushort*)(ws + OFF_XT);
    ushort* Qc   = (ushort*)(ws + OFF_QC);
    ushort* Kcc  = (ushort*)(ws + OFF_KCC);
    ushort* xc   = (ushort*)(ws + OFF_XC);
    ushort* AFt  = (ushort*)(ws + OFF_AFT);
    ushort* P    = (ushort*)(ws + OFF_P);
    ushort* AFp  = (ushort*)(ws + OFF_AFP);

    k_maskpool   <<<dim3(BATCH * N / 256), 256, 0, stream>>>(mask, m, vis, (uint*)maxv);
    k_scan       <<<dim3(BATCH), 256, 0, stream>>>(m, fgi, bgi, cnt, kmc, p2s);
    k_wconv      <<<dim3((CH * CIN + CH * KC) / 256), 256, 0, stream>>>(Kw, fw, Kwb, fwb);
    k_tr         <<<dim3(CH / 64, 64, BATCH), 256, 0, stream>>>(x, xT, CH);
    k_feats      <<<dim3(N / 64, 1, BATCH), 256, 0, stream>>>(Kwb, xT, dvt, Kb, p2s, Qc, Kcc);
    k_vgather    <<<dim3(N / 64, BATCH), 256, 0, stream>>>(xT, bgi, cnt, xc);
    k_score      <<<dim3(N / 64, N / 128, BATCH), 128, 0, stream>>>(Qc, Kcc, kmc, cnt, P);
    k_rowsum     <<<dim3(BATCH * N / 4), 256, 0, stream>>>(P, cnt, inv);
    k_att_fore   <<<dim3(N / 64, 1, BATCH * SPLITK), 256, 0, stream>>>(xc, P, cnt, AFp);
    k_afreduce   <<<dim3(BATCH * N / 4), 256, 0, stream>>>(AFp, inv, fgi, cnt, AFt);
    k_colsum     <<<dim3(2, QCH, BATCH), 256, 0, stream>>>(P, inv, cnt, part);
    k_colsum_final<<<dim3(BATCH * N / 256), 256, 0, stream>>>(part, bgi, cnt, vis, (uint*)maxv);
    k_fused      <<<dim3(N / 128, CH / 64, BATCH), 128, 0, stream>>>(fwb, AFt, xT, x, m, out);
    k_attmask    <<<dim3(BATCH * 512 * 512 / 256), 256, 0, stream>>>(vis, maxv, out + (size_t)BATCH * CH * N);
}

// Round 14
// 165.388 us; speedup vs baseline: 1.3101x; 1.0279x over previous
//
#include <hip/hip_runtime.h>
#include <hip/hip_bf16.h>

typedef __attribute__((ext_vector_type(8))) short short8;
typedef __attribute__((ext_vector_type(4))) float f32x4;
typedef unsigned int uint;
typedef unsigned short ushort;

constexpr int BATCH = 4;
constexpr int CH    = 256;
constexpr int N     = 4096;   // 64*64
constexpr int DVC   = 768;
constexpr int CIN   = 1024;   // CH + DVC
constexpr int KC    = 512;    // 2*CH
constexpr int PBS   = 5 * 1024 * 1024;  // P per-batch stride (elements)
constexpr int QCH   = 32;     // colsum q-chunks
constexpr int SPLITK = 4;     // att_fore K-split

// ---------------- workspace layout (bytes) ----------------
constexpr size_t OFF_M    = 0;                       // 16384 f32
constexpr size_t OFF_INV  = 64ull << 10;             // 16384 f32
constexpr size_t OFF_VIS  = 128ull << 10;            // 16384 f32
constexpr size_t OFF_MAXV = 192ull << 10;            // 1 f32
constexpr size_t OFF_CNT  = 196ull << 10;            // 16 ints
constexpr size_t OFF_FGI  = 256ull << 10;            // 16384 int
constexpr size_t OFF_BGI  = 320ull << 10;            // 16384 int
constexpr size_t OFF_P2S  = 384ull << 10;            // 16384 int
constexpr size_t OFF_KMC  = 448ull << 10;            // 16384 f32
constexpr size_t OFF_PART = 1ull << 20;              // 4MB partials
constexpr size_t OFF_KWB  = 5ull << 20;              // 512KB bf16
constexpr size_t OFF_FWB  = OFF_KWB + (512ull << 10);// 256KB bf16
constexpr size_t OFF_XT   = 6ull << 20;              // [b][n][256] bf16 = 8MB
constexpr size_t OFF_QC   = 38ull << 20;             // [b][qi][256] bf16 = 8MB
constexpr size_t OFF_KCC  = 46ull << 20;             // [b][ki][256] bf16 = 8MB
constexpr size_t OFF_XC   = 54ull << 20;             // [b][c][4096] bf16 = 8MB
constexpr size_t OFF_AFT  = 62ull << 20;             // [b][n][256] bf16 = 8MB
constexpr size_t OFF_P    = 70ull << 20;             // compact P bf16, 4 x PBS = 40MB
constexpr size_t OFF_AFP  = 110ull << 20;            // bf16 partials [sk][b][qi][c] = 32MB

// ---------------- helpers ----------------
__device__ __forceinline__ ushort f2bf(float f) {
    __hip_bfloat16 h = __float2bfloat16(f);
    return __builtin_bit_cast(ushort, h);
}
__device__ __forceinline__ float bf2f(ushort u) {
    uint v = (uint)u << 16;
    return __builtin_bit_cast(float, v);
}

typedef const __attribute__((address_space(1))) uint* gptr_t;
typedef __attribute__((address_space(3))) uint* lptr_t;
__device__ __forceinline__ void gload_lds16(const void* g, void* l) {
    __builtin_amdgcn_global_load_lds((gptr_t)g, (lptr_t)l, 16, 0, 0);
}

// ---------------- shared GEMM mainloop ----------------
template<int WM, int WN>
__device__ __forceinline__ void gemm_core(
    const ushort* __restrict__ A0, int lda, int m0,
    const ushort* __restrict__ B0, int ldb0, int kend0,
    const ushort* __restrict__ B1, int ldb1,
    int n0, int K,
    ushort* AsL, ushort* BsL, f32x4 acc[4][4])
{
    constexpr int NW = WM * WN, BM = WM * 64, BN = WN * 64;
    const int t = threadIdx.x, lane = t & 63, wid = t >> 6;
    const int wm = (wid / WN) * 64, wn = (wid % WN) * 64;

    for (int k0 = 0; k0 < K; k0 += 64) {
        #pragma unroll
        for (int c = wid; c < BM / 8; c += NW) {
            const ushort* g = A0 + (size_t)(m0 + c * 8 + (lane >> 3)) * lda + (k0 + (lane & 7) * 8);
            gload_lds16(g, AsL + c * 512);
        }
        const ushort* Bsrc = (k0 < kend0) ? B0 : B1;
        const int ldb = (k0 < kend0) ? ldb0 : ldb1;
        const int kc  = (k0 < kend0) ? k0 : (k0 - kend0);
        #pragma unroll
        for (int c = wid; c < BN / 8; c += NW) {
            const ushort* g = Bsrc + (size_t)(n0 + c * 8 + (lane >> 3)) * ldb + (kc + (lane & 7) * 8);
            gload_lds16(g, BsL + c * 512);
        }
        __syncthreads();

        const int ra = wm + (lane & 15), rb = wn + (lane & 15), ko = (lane >> 4) * 8;
        #pragma unroll
        for (int kk = 0; kk < 64; kk += 32) {
            short8 a[4], b[4];
            #pragma unroll
            for (int i = 0; i < 4; i++) a[i] = *(const short8*)(AsL + (ra + i * 16) * 64 + kk + ko);
            #pragma unroll
            for (int j = 0; j < 4; j++) b[j] = *(const short8*)(BsL + (rb + j * 16) * 64 + kk + ko);
            #pragma unroll
            for (int i = 0; i < 4; i++)
                #pragma unroll
                for (int j = 0; j < 4; j++)
                    acc[i][j] = __builtin_amdgcn_mfma_f32_16x16x32_bf16(a[i], b[j], acc[i][j], 0, 0, 0);
        }
        __syncthreads();
    }
}

__device__ __forceinline__ void zero_acc(f32x4 acc[4][4]) {
    f32x4 z = {0.f, 0.f, 0.f, 0.f};
    #pragma unroll
    for (int i = 0; i < 4; i++)
        #pragma unroll
        for (int j = 0; j < 4; j++) acc[i][j] = z;
}

// ---------------- prep: maskpool + vis/maxv init + weight conversion ----------------
__global__ void k_prep(const float* __restrict__ mask, const float* __restrict__ Kw,
                       const float* __restrict__ fw, float* __restrict__ m,
                       float* __restrict__ vis, uint* __restrict__ maxv,
                       ushort* __restrict__ Kwb, ushort* __restrict__ fwb)
{
    const int bid = blockIdx.x;
    if (bid < 64) {
        int idx = bid * 256 + threadIdx.x;
        int b = idx >> 12, p = idx & 4095;
        int y = p >> 6, x = p & 63;
        const float* base = mask + (size_t)b * 512 * 512 + (y * 8) * 512 + x * 8;
        float mx = 0.f;
        for (int dy = 0; dy < 8; dy++) {
            #pragma unroll
            for (int dx = 0; dx < 8; dx++) mx = fmaxf(mx, base[dy * 512 + dx]);
        }
        m[idx] = (mx > 0.f) ? 1.f : 0.f;
        vis[idx] = 0.f;
        if (idx == 0) maxv[0] = 0u;
    } else {
        int i = (bid - 64) * 256 + threadIdx.x;
        if (i < CH * CIN) Kwb[i] = f2bf(Kw[i]);
        else              fwb[i - CH * CIN] = f2bf(fw[i - CH * CIN]);
    }
}

__global__ __launch_bounds__(256) void k_scan(
    const float* __restrict__ m, int* __restrict__ fgi, int* __restrict__ bgi,
    int* __restrict__ counts, float* __restrict__ kmc, int* __restrict__ p2s)
{
    const int b = blockIdx.x, t = threadIdx.x;
    const float* mb = m + (size_t)b * N;
    __shared__ int sfg[256], sbg[256];
    bool isf[16];
    int cf = 0, cb_ = 0;
    #pragma unroll
    for (int j = 0; j < 16; j++) {
        bool f = mb[t * 16 + j] != 0.f;
        isf[j] = f; cf += f ? 1 : 0; cb_ += f ? 0 : 1;
    }
    sfg[t] = cf; sbg[t] = cb_;
    __syncthreads();
    for (int off = 1; off < 256; off <<= 1) {
        int vf = (t >= off) ? sfg[t - off] : 0;
        int vb = (t >= off) ? sbg[t - off] : 0;
        __syncthreads();
        sfg[t] += vf; sbg[t] += vb;
        __syncthreads();
    }
    int basef = sfg[t] - cf, baseb = sbg[t] - cb_;
    int nfg = sfg[255], nbg = sbg[255];
    #pragma unroll
    for (int j = 0; j < 16; j++) {
        int p = t * 16 + j;
        if (isf[j]) { fgi[b * N + basef] = p; p2s[b * N + p] = basef | (1 << 30); basef++; }
        else        { bgi[b * N + baseb] = p; p2s[b * N + p] = baseb; baseb++; }
    }
    if (t == 0) {
        counts[b * 4 + 0] = nfg;
        counts[b * 4 + 1] = (nfg + 127) & ~127;
        counts[b * 4 + 2] = nbg;
        counts[b * 4 + 3] = (nbg + 127) & ~127;
    }
    for (int j = t; j < N; j += 256) kmc[b * N + j] = (j < nbg) ? 1.f : 0.f;
}

// ---------------- transpose x: f32 [b][C][4096] -> bf16 [b][4096][C] ----------------
__global__ __launch_bounds__(256) void k_tr(const float* __restrict__ src,
                                            ushort* __restrict__ dst, int C)
{
    __shared__ float Ls[64][65];
    const int ci0 = blockIdx.x * 64, n0 = blockIdx.y * 64, b = blockIdx.z;
    const float* s = src + (size_t)b * C * 4096;
    const int t = threadIdx.x;
    #pragma unroll
    for (int it = 0; it < 4; it++) {
        int f4 = it * 256 + t;
        int r = f4 >> 4, c4 = f4 & 15;
        float4 v = *(const float4*)(s + (size_t)(ci0 + r) * 4096 + n0 + c4 * 4);
        Ls[r][c4 * 4 + 0] = v.x; Ls[r][c4 * 4 + 1] = v.y;
        Ls[r][c4 * 4 + 2] = v.z; Ls[r][c4 * 4 + 3] = v.w;
    }
    __syncthreads();
    ushort* d = dst + (size_t)b * 4096 * C;
    #pragma unroll
    for (int it = 0; it < 8; it++) {
        int p = it * 256 + t;
        int rn = p >> 5, cc2 = p & 31;
        uint val = (uint)f2bf(Ls[cc2 * 2][rn]) | ((uint)f2bf(Ls[cc2 * 2 + 1][rn]) << 16);
        *(uint*)(d + (size_t)(n0 + rn) * C + ci0 + cc2 * 2) = val;
    }
}

// gather-transpose V compact from bf16 xT: xc[b][c][j] = xT[b][bgi[j]][c]
__global__ __launch_bounds__(256) void k_vgather(
    const ushort* __restrict__ xT, const int* __restrict__ bgi,
    const int* __restrict__ counts, ushort* __restrict__ xc)
{
    __shared__ ushort Xs[64][264];
    const int b = blockIdx.y;
    const int ki0 = blockIdx.x * 64;
    const int nbg = counts[b * 4 + 2], nbgp = counts[b * 4 + 3];
    if (ki0 >= nbgp) return;
    const int t = threadIdx.x;
    const int j = t >> 2, part = t & 3;
    const int ki = ki0 + j;
    if (ki < nbg) {
        const ushort* src = xT + ((size_t)b * N + bgi[(size_t)b * N + ki]) * CH + part * 64;
        #pragma unroll
        for (int q = 0; q < 8; q++)
            *(uint4*)&Xs[j][part * 64 + q * 8] = *(const uint4*)(src + q * 8);
    } else {
        uint4 z = {0, 0, 0, 0};
        #pragma unroll
        for (int q = 0; q < 8; q++)
            *(uint4*)&Xs[j][part * 64 + q * 8] = z;
    }
    __syncthreads();
    const int c = t;
    ushort* dst = xc + ((size_t)b * CH + c) * N + ki0;
    uint w[32];
    #pragma unroll
    for (int jj = 0; jj < 32; jj++)
        w[jj] = (uint)Xs[2 * jj][c] | ((uint)Xs[2 * jj + 1][c] << 16);
    #pragma unroll
    for (int q = 0; q < 8; q++) {
        uint4 o = { w[q * 4], w[q * 4 + 1], w[q * 4 + 2], w[q * 4 + 3] };
        *(uint4*)(dst + q * 8) = o;
    }
}

// ---------------- feats GEMM (dense, fused dvt-transpose + bias/L2-norm/scatter) ----------------
__global__ __launch_bounds__(256) void k_feats(
    const ushort* __restrict__ Kwb, const ushort* __restrict__ xT,
    const float* __restrict__ dvt, const float* __restrict__ Kb,
    const int* __restrict__ p2s, ushort* __restrict__ Qc, ushort* __restrict__ Kc)
{
    __shared__ ushort As[256 * 64];   // 32 KB
    __shared__ ushort Bs[64 * 64];    // 8 KB
    __shared__ float  Ls[64][65];     // 16.25 KB (f32 transpose staging)
    __shared__ float  red[4][64];
    const int b = blockIdx.z;
    const int n0 = blockIdx.x * 64;
    const int t = threadIdx.x, lane = t & 63, wid = t >> 6;
    const ushort* xTb = xT + (size_t)b * N * CH;
    const float* dvb = dvt + (size_t)b * DVC * N;
    f32x4 acc[4][4]; zero_acc(acc);

    // phase 1: k = 0..255, B from xT (linear LDS)
    for (int k0 = 0; k0 < 256; k0 += 64) {
        #pragma unroll
        for (int c = wid; c < 32; c += 4)
            gload_lds16(Kwb + (size_t)(c * 8 + (lane >> 3)) * CIN + k0 + (lane & 7) * 8, As + c * 512);
        #pragma unroll
        for (int c = wid; c < 8; c += 4)
            gload_lds16(xTb + (size_t)(n0 + c * 8 + (lane >> 3)) * CH + k0 + (lane & 7) * 8, Bs + c * 512);
        __syncthreads();
        const int ra = wid * 64 + (lane & 15), rb = lane & 15, ko = (lane >> 4) * 8;
        #pragma unroll
        for (int kk = 0; kk < 64; kk += 32) {
            short8 a[4], bb[4];
            #pragma unroll
            for (int i = 0; i < 4; i++) a[i] = *(const short8*)(As + (ra + i * 16) * 64 + kk + ko);
            #pragma unroll
            for (int j = 0; j < 4; j++) bb[j] = *(const short8*)(Bs + (rb + j * 16) * 64 + kk + ko);
            #pragma unroll
            for (int i = 0; i < 4; i++)
                #pragma unroll
                for (int j = 0; j < 4; j++)
                    acc[i][j] = __builtin_amdgcn_mfma_f32_16x16x32_bf16(a[i], bb[j], acc[i][j], 0, 0, 0);
        }
        __syncthreads();
    }
    // phase 2: k = 256..1023, B transposed in-kernel from dvt f32, XOR-swizzled
    for (int k0 = 256; k0 < 1024; k0 += 64) {
        #pragma unroll
        for (int c = wid; c < 32; c += 4)
            gload_lds16(Kwb + (size_t)(c * 8 + (lane >> 3)) * CIN + k0 + (lane & 7) * 8, As + c * 512);
        const float* dsrc = dvb + (size_t)(k0 - 256) * N + n0;
        #pragma unroll
        for (int it = 0; it < 4; it++) {
            int f4 = it * 256 + t;
            int r = f4 >> 4, c4 = (f4 & 15) * 4;
            float4 v = *(const float4*)(dsrc + (size_t)r * N + c4);
            Ls[r][c4 + 0] = v.x; Ls[r][c4 + 1] = v.y;
            Ls[r][c4 + 2] = v.z; Ls[r][c4 + 3] = v.w;
        }
        __syncthreads();
        {
            int rn = t >> 2;            // n row 0..63
            int ks = (t & 3) * 16;      // k start
            #pragma unroll
            for (int j2 = 0; j2 < 8; j2++) {
                int kk = ks + j2 * 2;
                uint val = (uint)f2bf(Ls[kk][rn]) | ((uint)f2bf(Ls[kk + 1][rn]) << 16);
                int idx = (rn * 64 + kk) ^ ((rn & 7) << 3);
                *(uint*)(Bs + idx) = val;
            }
        }
        __syncthreads();
        const int ra = wid * 64 + (lane & 15), rb = lane & 15, ko = (lane >> 4) * 8;
        #pragma unroll
        for (int kk = 0; kk < 64; kk += 32) {
            short8 a[4], bb[4];
            #pragma unroll
            for (int i = 0; i < 4; i++) a[i] = *(const short8*)(As + (ra + i * 16) * 64 + kk + ko);
            #pragma unroll
            for (int j = 0; j < 4; j++) {
                int row = rb + j * 16;
                int idx = (row * 64 + kk + ko) ^ ((row & 7) << 3);
                bb[j] = *(const short8*)(Bs + idx);
            }
            #pragma unroll
            for (int i = 0; i < 4; i++)
                #pragma unroll
                for (int j = 0; j < 4; j++)
                    acc[i][j] = __builtin_amdgcn_mfma_f32_16x16x32_bf16(a[i], bb[j], acc[i][j], 0, 0, 0);
        }
        __syncthreads();
    }

    // epilogue: bias, per-position L2 norm (cross-wave), scatter to Qc/Kc
    const int wm = wid * 64;
    float sj[4] = {0.f, 0.f, 0.f, 0.f};
    #pragma unroll
    for (int i = 0; i < 4; i++) {
        int mbase = wm + i * 16 + ((lane >> 4) * 4);
        float4 bias = *(const float4*)(Kb + mbase);
        #pragma unroll
        for (int j = 0; j < 4; j++) {
            acc[i][j][0] += bias.x; acc[i][j][1] += bias.y;
            acc[i][j][2] += bias.z; acc[i][j][3] += bias.w;
            sj[j] += acc[i][j][0] * acc[i][j][0] + acc[i][j][1] * acc[i][j][1]
                   + acc[i][j][2] * acc[i][j][2] + acc[i][j][3] * acc[i][j][3];
        }
    }
    #pragma unroll
    for (int j = 0; j < 4; j++) {
        sj[j] += __shfl_xor(sj[j], 16);
        sj[j] += __shfl_xor(sj[j], 32);
    }
    if (lane < 16) {
        #pragma unroll
        for (int j = 0; j < 4; j++) red[wid][j * 16 + lane] = sj[j];
    }
    __syncthreads();
    const int* pb = p2s + (size_t)b * N + n0;
    #pragma unroll
    for (int j = 0; j < 4; j++) {
        int n = j * 16 + (lane & 15);
        float s = red[0][n] + red[1][n] + red[2][n] + red[3][n];
        float invn = 1.f / (sqrtf(s) + 1e-8f);
        int sl = pb[n];
        ushort* dst = (sl & (1 << 30)) ? Qc : Kc;
        int slot = sl & 0x3FFFFFFF;
        ushort* drow = dst + ((size_t)b * N + slot) * CH;
        #pragma unroll
        for (int i = 0; i < 4; i++) {
            int mbase = wm + i * 16 + ((lane >> 4) * 4);
            ushort4 o = { f2bf(acc[i][j][0] * invn), f2bf(acc[i][j][1] * invn),
                          f2bf(acc[i][j][2] * invn), f2bf(acc[i][j][3] * invn) };
            *(ushort4*)(drow + mbase) = o;
        }
    }
}

// ---------------- score GEMM (compact, 128q x 64k tiles, 2 waves) ----------------
__global__ __launch_bounds__(128) void k_score(
    const ushort* __restrict__ Qc, const ushort* __restrict__ Kc,
    const float* __restrict__ kmc, const int* __restrict__ counts,
    ushort* __restrict__ P)
{
    const int b = blockIdx.z;
    const int nfgp = counts[b * 4 + 1], nbgp = counts[b * 4 + 3];
    const int m0 = blockIdx.y * 128;   // q tile
    const int n0 = blockIdx.x * 64;    // k tile
    if (m0 >= nfgp || n0 >= nbgp) return;
    __shared__ ushort SH[(128 + 64) * 64];
    const int t = threadIdx.x, lane = t & 63, wid = t >> 6;
    const ushort* Qb = Qc + (size_t)b * N * CH;
    const ushort* Kb_ = Kc + (size_t)b * N * CH;
    f32x4 acc[4][4]; zero_acc(acc);
    gemm_core<2, 1>(Qb, CH, m0, Kb_, CH, CH, Kb_, CH, n0, CH, SH, SH + 128 * 64, acc);

    const int wm = wid * 64;
    float km[4];
    #pragma unroll
    for (int j = 0; j < 4; j++) km[j] = kmc[(size_t)b * N + n0 + j * 16 + (lane & 15)];

    ushort* Cs = SH;   // 128 x 64 repack
    #pragma unroll
    for (int i = 0; i < 4; i++) {
        int rbase = wm + i * 16 + ((lane >> 4) * 4);
        #pragma unroll
        for (int j = 0; j < 4; j++) {
            int cl = j * 16 + (lane & 15);
            #pragma unroll
            for (int r = 0; r < 4; r++) {
                float p = (km[j] != 0.f) ? __expf(20.f * acc[i][j][r] - 20.f) : 0.f;
                Cs[(rbase + r) * 64 + cl] = f2bf(p);
            }
        }
    }
    __syncthreads();
    ushort* Pb = P + (size_t)b * PBS;
    #pragma unroll
    for (int it = 0; it < 8; it++) {
        int v8 = it * 128 + t;
        int row = v8 >> 3, c8 = (v8 & 7) * 8;
        *(uint4*)(Pb + (size_t)(m0 + row) * nbgp + n0 + c8) = *(const uint4*)(Cs + row * 64 + c8);
    }
}

// ---------------- PV GEMM (compact, BM=256, split-K bf16 partials) ----------------
__global__ __launch_bounds__(256) void k_att_fore(
    const ushort* __restrict__ xc, const ushort* __restrict__ P,
    const int* __restrict__ counts, ushort* __restrict__ AFp)
{
    const int b = blockIdx.z & (BATCH - 1);
    const int sk = blockIdx.z / BATCH;
    const int nfgp = counts[b * 4 + 1], nbgp = counts[b * 4 + 3];
    const int n0 = blockIdx.x * 64;    // qi tile
    if (n0 >= nfgp) return;
    const int kchunk = ((nbgp / 64 + SPLITK - 1) / SPLITK) * 64;
    const int k0s = sk * kchunk;
    const int len = min(kchunk, nbgp - k0s);

    const int lane = threadIdx.x & 63, wid = threadIdx.x >> 6;
    f32x4 acc[4][4]; zero_acc(acc);
    if (len > 0) {
        __shared__ ushort SH[(256 + 64) * 64];
        const ushort* Pb = P + (size_t)b * PBS + k0s;
        gemm_core<4, 1>(xc + (size_t)b * CH * N + k0s, N, 0,
                        Pb, nbgp, 1 << 30, Pb, nbgp,
                        n0, len, SH, SH + 256 * 64, acc);
    }
    ushort* Ap = AFp + ((size_t)(sk * BATCH + b) * N) * CH;
    const int wm = wid * 64;
    #pragma unroll
    for (int j = 0; j < 4; j++) {
        int qi = n0 + j * 16 + (lane & 15);
        #pragma unroll
        for (int i = 0; i < 4; i++) {
            int mbase = wm + i * 16 + ((lane >> 4) * 4);
            ushort4 o = { f2bf(acc[i][j][0]), f2bf(acc[i][j][1]),
                          f2bf(acc[i][j][2]), f2bf(acc[i][j][3]) };
            *(ushort4*)(Ap + (size_t)qi * CH + mbase) = o;
        }
    }
}

// ---------------- fused rowsum + AF reduce: wave per (b,qi) ----------------
// sweep P row -> sum -> inv; then reduce SPLITK bf16 partials, scale, scatter AFt.
__global__ __launch_bounds__(256) void k_rowaf(
    const ushort* __restrict__ P, const ushort* __restrict__ AFp,
    const int* __restrict__ fgi, const int* __restrict__ counts,
    float* __restrict__ inv, ushort* __restrict__ AFt)
{
    const int t = threadIdx.x, lane = t & 63, wid = t >> 6;
    const int g = blockIdx.x * 4 + wid;       // b*N + qi
    const int b = g >> 12, qi = g & 4095;
    const int nfgp = counts[b * 4 + 1], nbgp = counts[b * 4 + 3];
    if (qi >= nfgp) return;
    const ushort* row = P + (size_t)b * PBS + (size_t)qi * nbgp;
    float s = 0.f;
    for (int it = 0; it < 8; it++) {
        int base = it * 512 + lane * 8;
        if (base < nbgp) {
            uint4 v = *(const uint4*)(row + base);
            const ushort* u = (const ushort*)&v;
            #pragma unroll
            for (int e = 0; e < 8; e++) s += bf2f(u[e]);
        }
    }
    #pragma unroll
    for (int mm = 1; mm < 64; mm <<= 1) s += __shfl_xor(s, mm);
    float iq = (s > 0.f) ? 1.f / s : 0.f;
    if (lane == 0) inv[g] = iq;
    if (qi < counts[b * 4]) {                  // nfg: real fg rows only
        const size_t rowoff = ((size_t)b * N + qi) * CH + lane * 4;
        float s0 = 0.f, s1 = 0.f, s2 = 0.f, s3 = 0.f;
        #pragma unroll
        for (int sk = 0; sk < SPLITK; sk++) {
            ushort4 v = *(const ushort4*)(AFp + (size_t)sk * BATCH * N * CH + rowoff);
            s0 += bf2f(v.x); s1 += bf2f(v.y); s2 += bf2f(v.z); s3 += bf2f(v.w);
        }
        int q = fgi[g];
        ushort4 o = { f2bf(s0 * iq), f2bf(s1 * iq), f2bf(s2 * iq), f2bf(s3 * iq) };
        *(ushort4*)(AFt + ((size_t)b * N + q) * CH + lane * 4) = o;
    }
}

// ---------------- fused GEMM + blend (dense) ----------------
__global__ __launch_bounds__(128) void k_fused(
    const ushort* __restrict__ fwb, const ushort* __restrict__ AFt,
    const ushort* __restrict__ xT, const float* __restrict__ x,
    const float* __restrict__ m_, float* __restrict__ out)
{
    __shared__ ushort SH[(64 + 128) * 64];
    const int b = blockIdx.z;
    const int n0 = blockIdx.x * 128, m0 = blockIdx.y * 64;
    const int lane = threadIdx.x & 63, wid = threadIdx.x >> 6;
    const int wn = (wid & 1) * 64;
    f32x4 acc[4][4]; zero_acc(acc);
    gemm_core<1, 2>(fwb, KC, m0,
                    AFt + (size_t)b * N * CH, CH, CH,
                    xT + (size_t)b * N * CH, CH,
                    n0, KC, SH, SH + 64 * 64, acc);
    const float* mb = m_ + (size_t)b * N;
    const float* xc_ = x + (size_t)b * CH * N;
    float* ob = out + (size_t)b * CH * N;
    #pragma unroll
    for (int j = 0; j < 4; j++) {
        int n = n0 + wn + j * 16 + (lane & 15);
        float mv = mb[n];
        #pragma unroll
        for (int i = 0; i < 4; i++) {
            int mbase = m0 + i * 16 + ((lane >> 4) * 4);
            #pragma unroll
            for (int r = 0; r < 4; r++) {
                int c = mbase + r;
                ob[(size_t)c * N + n] = (mv != 0.f) ? acc[i][j][r] : xc_[(size_t)c * N + n];
            }
        }
    }
}

// ---------------- colsum (coalesced, row-major sweep) ----------------
__global__ __launch_bounds__(256) void k_colsum(
    const ushort* __restrict__ P, const float* __restrict__ inv,
    const int* __restrict__ counts, float* __restrict__ part)
{
    const int b = blockIdx.z, qc = blockIdx.y, t = threadIdx.x;
    const int nfg = counts[b * 4], nbgp = counts[b * 4 + 3];
    const int ki0 = blockIdx.x * 2048 + t * 8;
    if (ki0 >= nbgp) return;
    const int qchunk = (nfg + QCH - 1) / QCH;
    const int q0 = qc * qchunk, q1 = min(q0 + qchunk, nfg);
    const ushort* base = P + (size_t)b * PBS + (size_t)q0 * nbgp + ki0;
    const float* ib = inv + (size_t)b * N;
    float acc[8] = {};
    int q = q0;
    for (; q + 4 <= q1; q += 4) {
        uint4 v0 = *(const uint4*)(base);
        uint4 v1 = *(const uint4*)(base + (size_t)nbgp);
        uint4 v2 = *(const uint4*)(base + 2 * (size_t)nbgp);
        uint4 v3 = *(const uint4*)(base + 3 * (size_t)nbgp);
        float i0 = ib[q], i1 = ib[q + 1], i2 = ib[q + 2], i3 = ib[q + 3];
        const ushort* u0 = (const ushort*)&v0;
        const ushort* u1 = (const ushort*)&v1;
        const ushort* u2 = (const ushort*)&v2;
        const ushort* u3 = (const ushort*)&v3;
        #pragma unroll
        for (int e = 0; e < 8; e++)
            acc[e] += bf2f(u0[e]) * i0 + bf2f(u1[e]) * i1 + bf2f(u2[e]) * i2 + bf2f(u3[e]) * i3;
        base += 4 * (size_t)nbgp;
    }
    for (; q < q1; q++) {
        uint4 v = *(const uint4*)(base);
        float iq = ib[q];
        const ushort* u = (const ushort*)&v;
        #pragma unroll
        for (int e = 0; e < 8; e++) acc[e] += bf2f(u[e]) * iq;
        base += (size_t)nbgp;
    }
    float* pp = part + (size_t)qc * (BATCH * N) + (size_t)b * N + ki0;
    float4 o0 = {acc[0], acc[1], acc[2], acc[3]};
    float4 o1 = {acc[4], acc[5], acc[6], acc[7]};
    *(float4*)(pp)     = o0;
    *(float4*)(pp + 4) = o1;
}

// reduce colsum partials, scatter to vis, track global max (uint atomicMax, vis>=0)
__global__ void k_colsum_final(const float* __restrict__ part, const int* __restrict__ bgi,
                               const int* __restrict__ counts, float* __restrict__ vis,
                               uint* __restrict__ maxv)
{
    int g = blockIdx.x * 256 + threadIdx.x;
    int b = g >> 12, ki = g & 4095;
    int t = threadIdx.x;
    float s = 0.f;
    if (ki < counts[b * 4 + 2]) {
        #pragma unroll
        for (int j = 0; j < QCH; j++) s += part[(size_t)j * (BATCH * N) + g];
        vis[(size_t)b * N + bgi[(size_t)b * N + ki]] = s;
    }
    __shared__ float red[256];
    red[t] = s; __syncthreads();
    for (int st = 128; st > 0; st >>= 1) { if (t < st) red[t] = fmaxf(red[t], red[t + st]); __syncthreads(); }
    if (t == 0) atomicMax(maxv, __float_as_uint(red[0]));
}

__global__ void k_attmask(const float* __restrict__ vis, const float* __restrict__ maxv,
                          float* __restrict__ amask)
{
    int idx = blockIdx.x * 256 + threadIdx.x;
    int b = idx >> 18;
    int r = idx & 262143;
    int Y = r >> 9, X = r & 511;
    amask[idx] = vis[(size_t)b * N + (Y >> 3) * 64 + (X >> 3)] / maxv[0];
}

// ---------------- launch ----------------
extern "C" void kernel_launch(void* const* d_in, const int* in_sizes, int n_in,
                              void* d_out, int out_size, void* d_ws, size_t ws_size,
                              hipStream_t stream)
{
    const float* x    = (const float*)d_in[0];
    const float* mask = (const float*)d_in[1];
    const float* dvt  = (const float*)d_in[2];
    const float* Kw   = (const float*)d_in[3];
    const float* Kb   = (const float*)d_in[4];
    const float* fw   = (const float*)d_in[5];
    float* out = (float*)d_out;

    char* ws = (char*)d_ws;
    float*  m    = (float*)(ws + OFF_M);
    float*  inv  = (float*)(ws + OFF_INV);
    float*  vis  = (float*)(ws + OFF_VIS);
    float*  maxv = (float*)(ws + OFF_MAXV);
    int*    cnt  = (int*)  (ws + OFF_CNT);
    int*    fgi  = (int*)  (ws + OFF_FGI);
    int*    bgi  = (int*)  (ws + OFF_BGI);
    int*    p2s  = (int*)  (ws + OFF_P2S);
    float*  kmc  = (float*)(ws + OFF_KMC);
    float*  part = (float*)(ws + OFF_PART);
    ushort* Kwb  = (ushort*)(ws + OFF_KWB);
    ushort* fwb  = (ushort*)(ws + OFF_FWB);
    ushort* xT   = (ushort*)(ws + OFF_XT);
    ushort* Qc   = (ushort*)(ws + OFF_QC);
    ushort* Kcc  = (ushort*)(ws + OFF_KCC);
    ushort* xc   = (ushort*)(ws + OFF_XC);
    ushort* AFt  = (ushort*)(ws + OFF_AFT);
    ushort* P    = (ushort*)(ws + OFF_P);
    ushort* AFp  = (ushort*)(ws + OFF_AFP);

    k_prep       <<<dim3(64 + (CH * CIN + CH * KC) / 256), 256, 0, stream>>>(
                     mask, Kw, fw, m, vis, (uint*)maxv, Kwb, fwb);
    k_scan       <<<dim3(BATCH), 256, 0, stream>>>(m, fgi, bgi, cnt, kmc, p2s);
    k_tr         <<<dim3(CH / 64, 64, BATCH), 256, 0, stream>>>(x, xT, CH);
    k_feats      <<<dim3(N / 64, 1, BATCH), 256, 0, stream>>>(Kwb, xT, dvt, Kb, p2s, Qc, Kcc);
    k_vgather    <<<dim3(N / 64, BATCH), 256, 0, stream>>>(xT, bgi, cnt, xc);
    k_score      <<<dim3(N / 64, N / 128, BATCH), 128, 0, stream>>>(Qc, Kcc, kmc, cnt, P);
    k_att_fore   <<<dim3(N / 64, 1, BATCH * SPLITK), 256, 0, stream>>>(xc, P, cnt, AFp);
    k_rowaf      <<<dim3(BATCH * N / 4), 256, 0, stream>>>(P, AFp, fgi, cnt, inv, AFt);
    k_colsum     <<<dim3(2, QCH, BATCH), 256, 0, stream>>>(P, inv, cnt, part);
    k_colsum_final<<<dim3(BATCH * N / 256), 256, 0, stream>>>(part, bgi, cnt, vis, (uint*)maxv);
    k_fused      <<<dim3(N / 128, CH / 64, BATCH), 128, 0, stream>>>(fwb, AFt, xT, x, m, out);
    k_attmask    <<<dim3(BATCH * 512 * 512 / 256), 256, 0, stream>>>(vis, maxv, out + (size_t)BATCH * CH * N);
}

// Round 15
// 162.304 us; speedup vs baseline: 1.3350x; 1.0190x over previous
//
#include <hip/hip_runtime.h>
#include <hip/hip_bf16.h>

typedef __attribute__((ext_vector_type(8))) short short8;
typedef __attribute__((ext_vector_type(4))) float f32x4;
typedef unsigned int uint;
typedef unsigned short ushort;

constexpr int BATCH = 4;
constexpr int CH    = 256;
constexpr int N     = 4096;   // 64*64
constexpr int DVC   = 768;
constexpr int CIN   = 1024;   // CH + DVC
constexpr int KC    = 512;    // 2*CH
constexpr int PBS   = 5 * 1024 * 1024;  // P per-batch stride (elements)
constexpr int QCH   = 32;     // colsum q-chunks
constexpr int SPLITK = 4;     // att_fore K-split

// ---------------- workspace layout (bytes) ----------------
constexpr size_t OFF_M    = 0;                       // 16384 f32
constexpr size_t OFF_INV  = 64ull << 10;             // 16384 f32
constexpr size_t OFF_VIS  = 128ull << 10;            // 16384 f32
constexpr size_t OFF_MAXV = 192ull << 10;            // 1 f32
constexpr size_t OFF_CNT  = 196ull << 10;            // 16 ints
constexpr size_t OFF_FGI  = 256ull << 10;            // 16384 int
constexpr size_t OFF_BGI  = 320ull << 10;            // 16384 int
constexpr size_t OFF_P2S  = 384ull << 10;            // 16384 int
constexpr size_t OFF_KMC  = 448ull << 10;            // 16384 f32
constexpr size_t OFF_PART = 1ull << 20;              // 4MB partials
constexpr size_t OFF_KWB  = 5ull << 20;              // 512KB bf16
constexpr size_t OFF_FWB  = OFF_KWB + (512ull << 10);// 256KB bf16
constexpr size_t OFF_XT   = 6ull << 20;              // [b][n][256] bf16 = 8MB
constexpr size_t OFF_QC   = 38ull << 20;             // [b][qi][256] bf16 = 8MB
constexpr size_t OFF_KCC  = 46ull << 20;             // [b][ki][256] bf16 = 8MB
constexpr size_t OFF_XC   = 54ull << 20;             // [b][c][4096] bf16 = 8MB
constexpr size_t OFF_AFT  = 62ull << 20;             // [b][n][256] bf16 = 8MB
constexpr size_t OFF_P    = 70ull << 20;             // compact P bf16, 4 x PBS = 40MB
constexpr size_t OFF_AFP  = 110ull << 20;            // bf16 partials [sk][b][qi][c] = 32MB

// ---------------- helpers ----------------
__device__ __forceinline__ ushort f2bf(float f) {
    __hip_bfloat16 h = __float2bfloat16(f);
    return __builtin_bit_cast(ushort, h);
}
__device__ __forceinline__ float bf2f(ushort u) {
    uint v = (uint)u << 16;
    return __builtin_bit_cast(float, v);
}

typedef const __attribute__((address_space(1))) uint* gptr_t;
typedef __attribute__((address_space(3))) uint* lptr_t;
__device__ __forceinline__ void gload_lds16(const void* g, void* l) {
    __builtin_amdgcn_global_load_lds((gptr_t)g, (lptr_t)l, 16, 0, 0);
}

// ---------------- shared GEMM mainloop ----------------
template<int WM, int WN>
__device__ __forceinline__ void gemm_core(
    const ushort* __restrict__ A0, int lda, int m0,
    const ushort* __restrict__ B0, int ldb0, int kend0,
    const ushort* __restrict__ B1, int ldb1,
    int n0, int K,
    ushort* AsL, ushort* BsL, f32x4 acc[4][4])
{
    constexpr int NW = WM * WN, BM = WM * 64, BN = WN * 64;
    const int t = threadIdx.x, lane = t & 63, wid = t >> 6;
    const int wm = (wid / WN) * 64, wn = (wid % WN) * 64;

    for (int k0 = 0; k0 < K; k0 += 64) {
        #pragma unroll
        for (int c = wid; c < BM / 8; c += NW) {
            const ushort* g = A0 + (size_t)(m0 + c * 8 + (lane >> 3)) * lda + (k0 + (lane & 7) * 8);
            gload_lds16(g, AsL + c * 512);
        }
        const ushort* Bsrc = (k0 < kend0) ? B0 : B1;
        const int ldb = (k0 < kend0) ? ldb0 : ldb1;
        const int kc  = (k0 < kend0) ? k0 : (k0 - kend0);
        #pragma unroll
        for (int c = wid; c < BN / 8; c += NW) {
            const ushort* g = Bsrc + (size_t)(n0 + c * 8 + (lane >> 3)) * ldb + (kc + (lane & 7) * 8);
            gload_lds16(g, BsL + c * 512);
        }
        __syncthreads();

        const int ra = wm + (lane & 15), rb = wn + (lane & 15), ko = (lane >> 4) * 8;
        #pragma unroll
        for (int kk = 0; kk < 64; kk += 32) {
            short8 a[4], b[4];
            #pragma unroll
            for (int i = 0; i < 4; i++) a[i] = *(const short8*)(AsL + (ra + i * 16) * 64 + kk + ko);
            #pragma unroll
            for (int j = 0; j < 4; j++) b[j] = *(const short8*)(BsL + (rb + j * 16) * 64 + kk + ko);
            #pragma unroll
            for (int i = 0; i < 4; i++)
                #pragma unroll
                for (int j = 0; j < 4; j++)
                    acc[i][j] = __builtin_amdgcn_mfma_f32_16x16x32_bf16(a[i], b[j], acc[i][j], 0, 0, 0);
        }
        __syncthreads();
    }
}

__device__ __forceinline__ void zero_acc(f32x4 acc[4][4]) {
    f32x4 z = {0.f, 0.f, 0.f, 0.f};
    #pragma unroll
    for (int i = 0; i < 4; i++)
        #pragma unroll
        for (int j = 0; j < 4; j++) acc[i][j] = z;
}

// ---------------- prep: maskpool + vis/maxv init + weight conversion ----------------
__global__ void k_prep(const float* __restrict__ mask, const float* __restrict__ Kw,
                       const float* __restrict__ fw, float* __restrict__ m,
                       float* __restrict__ vis, uint* __restrict__ maxv,
                       ushort* __restrict__ Kwb, ushort* __restrict__ fwb)
{
    const int bid = blockIdx.x;
    if (bid < 64) {
        int idx = bid * 256 + threadIdx.x;
        int b = idx >> 12, p = idx & 4095;
        int y = p >> 6, x = p & 63;
        const float* base = mask + (size_t)b * 512 * 512 + (y * 8) * 512 + x * 8;
        float mx = 0.f;
        for (int dy = 0; dy < 8; dy++) {
            #pragma unroll
            for (int dx = 0; dx < 8; dx++) mx = fmaxf(mx, base[dy * 512 + dx]);
        }
        m[idx] = (mx > 0.f) ? 1.f : 0.f;
        vis[idx] = 0.f;
        if (idx == 0) maxv[0] = 0u;
    } else {
        int i = (bid - 64) * 256 + threadIdx.x;
        if (i < CH * CIN) Kwb[i] = f2bf(Kw[i]);
        else              fwb[i - CH * CIN] = f2bf(fw[i - CH * CIN]);
    }
}

__global__ __launch_bounds__(256) void k_scan(
    const float* __restrict__ m, int* __restrict__ fgi, int* __restrict__ bgi,
    int* __restrict__ counts, float* __restrict__ kmc, int* __restrict__ p2s)
{
    const int b = blockIdx.x, t = threadIdx.x;
    const float* mb = m + (size_t)b * N;
    __shared__ int sfg[256], sbg[256];
    bool isf[16];
    int cf = 0, cb_ = 0;
    #pragma unroll
    for (int j = 0; j < 16; j++) {
        bool f = mb[t * 16 + j] != 0.f;
        isf[j] = f; cf += f ? 1 : 0; cb_ += f ? 0 : 1;
    }
    sfg[t] = cf; sbg[t] = cb_;
    __syncthreads();
    for (int off = 1; off < 256; off <<= 1) {
        int vf = (t >= off) ? sfg[t - off] : 0;
        int vb = (t >= off) ? sbg[t - off] : 0;
        __syncthreads();
        sfg[t] += vf; sbg[t] += vb;
        __syncthreads();
    }
    int basef = sfg[t] - cf, baseb = sbg[t] - cb_;
    int nfg = sfg[255], nbg = sbg[255];
    #pragma unroll
    for (int j = 0; j < 16; j++) {
        int p = t * 16 + j;
        if (isf[j]) { fgi[b * N + basef] = p; p2s[b * N + p] = basef | (1 << 30); basef++; }
        else        { bgi[b * N + baseb] = p; p2s[b * N + p] = baseb; baseb++; }
    }
    if (t == 0) {
        counts[b * 4 + 0] = nfg;
        counts[b * 4 + 1] = (nfg + 127) & ~127;
        counts[b * 4 + 2] = nbg;
        counts[b * 4 + 3] = (nbg + 127) & ~127;
    }
    for (int j = t; j < N; j += 256) kmc[b * N + j] = (j < nbg) ? 1.f : 0.f;
}

// ---------------- transpose x: f32 [b][C][4096] -> bf16 [b][4096][C] ----------------
__global__ __launch_bounds__(256) void k_tr(const float* __restrict__ src,
                                            ushort* __restrict__ dst, int C)
{
    __shared__ float Ls[64][65];
    const int ci0 = blockIdx.x * 64, n0 = blockIdx.y * 64, b = blockIdx.z;
    const float* s = src + (size_t)b * C * 4096;
    const int t = threadIdx.x;
    #pragma unroll
    for (int it = 0; it < 4; it++) {
        int f4 = it * 256 + t;
        int r = f4 >> 4, c4 = f4 & 15;
        float4 v = *(const float4*)(s + (size_t)(ci0 + r) * 4096 + n0 + c4 * 4);
        Ls[r][c4 * 4 + 0] = v.x; Ls[r][c4 * 4 + 1] = v.y;
        Ls[r][c4 * 4 + 2] = v.z; Ls[r][c4 * 4 + 3] = v.w;
    }
    __syncthreads();
    ushort* d = dst + (size_t)b * 4096 * C;
    #pragma unroll
    for (int it = 0; it < 8; it++) {
        int p = it * 256 + t;
        int rn = p >> 5, cc2 = p & 31;
        uint val = (uint)f2bf(Ls[cc2 * 2][rn]) | ((uint)f2bf(Ls[cc2 * 2 + 1][rn]) << 16);
        *(uint*)(d + (size_t)(n0 + rn) * C + ci0 + cc2 * 2) = val;
    }
}

// gather-transpose V compact from bf16 xT: xc[b][c][j] = xT[b][bgi[j]][c]
__global__ __launch_bounds__(256) void k_vgather(
    const ushort* __restrict__ xT, const int* __restrict__ bgi,
    const int* __restrict__ counts, ushort* __restrict__ xc)
{
    __shared__ ushort Xs[64][264];
    const int b = blockIdx.y;
    const int ki0 = blockIdx.x * 64;
    const int nbg = counts[b * 4 + 2], nbgp = counts[b * 4 + 3];
    if (ki0 >= nbgp) return;
    const int t = threadIdx.x;
    const int j = t >> 2, part = t & 3;
    const int ki = ki0 + j;
    if (ki < nbg) {
        const ushort* src = xT + ((size_t)b * N + bgi[(size_t)b * N + ki]) * CH + part * 64;
        #pragma unroll
        for (int q = 0; q < 8; q++)
            *(uint4*)&Xs[j][part * 64 + q * 8] = *(const uint4*)(src + q * 8);
    } else {
        uint4 z = {0, 0, 0, 0};
        #pragma unroll
        for (int q = 0; q < 8; q++)
            *(uint4*)&Xs[j][part * 64 + q * 8] = z;
    }
    __syncthreads();
    const int c = t;
    ushort* dst = xc + ((size_t)b * CH + c) * N + ki0;
    uint w[32];
    #pragma unroll
    for (int jj = 0; jj < 32; jj++)
        w[jj] = (uint)Xs[2 * jj][c] | ((uint)Xs[2 * jj + 1][c] << 16);
    #pragma unroll
    for (int q = 0; q < 8; q++) {
        uint4 o = { w[q * 4], w[q * 4 + 1], w[q * 4 + 2], w[q * 4 + 3] };
        *(uint4*)(dst + q * 8) = o;
    }
}

// ---------------- feats GEMM (dense, fused dvt-transpose + bias/L2-norm/scatter) ----------------
__global__ __launch_bounds__(256) void k_feats(
    const ushort* __restrict__ Kwb, const ushort* __restrict__ xT,
    const float* __restrict__ dvt, const float* __restrict__ Kb,
    const int* __restrict__ p2s, ushort* __restrict__ Qc, ushort* __restrict__ Kc)
{
    __shared__ ushort As[256 * 64];   // 32 KB
    __shared__ ushort Bs[64 * 64];    // 8 KB
    __shared__ float  Ls[64][65];     // 16.25 KB (f32 transpose staging)
    __shared__ float  red[4][64];
    const int b = blockIdx.z;
    const int n0 = blockIdx.x * 64;
    const int t = threadIdx.x, lane = t & 63, wid = t >> 6;
    const ushort* xTb = xT + (size_t)b * N * CH;
    const float* dvb = dvt + (size_t)b * DVC * N;
    f32x4 acc[4][4]; zero_acc(acc);

    // phase 1: k = 0..255, B from xT (linear LDS)
    for (int k0 = 0; k0 < 256; k0 += 64) {
        #pragma unroll
        for (int c = wid; c < 32; c += 4)
            gload_lds16(Kwb + (size_t)(c * 8 + (lane >> 3)) * CIN + k0 + (lane & 7) * 8, As + c * 512);
        #pragma unroll
        for (int c = wid; c < 8; c += 4)
            gload_lds16(xTb + (size_t)(n0 + c * 8 + (lane >> 3)) * CH + k0 + (lane & 7) * 8, Bs + c * 512);
        __syncthreads();
        const int ra = wid * 64 + (lane & 15), rb = lane & 15, ko = (lane >> 4) * 8;
        #pragma unroll
        for (int kk = 0; kk < 64; kk += 32) {
            short8 a[4], bb[4];
            #pragma unroll
            for (int i = 0; i < 4; i++) a[i] = *(const short8*)(As + (ra + i * 16) * 64 + kk + ko);
            #pragma unroll
            for (int j = 0; j < 4; j++) bb[j] = *(const short8*)(Bs + (rb + j * 16) * 64 + kk + ko);
            #pragma unroll
            for (int i = 0; i < 4; i++)
                #pragma unroll
                for (int j = 0; j < 4; j++)
                    acc[i][j] = __builtin_amdgcn_mfma_f32_16x16x32_bf16(a[i], bb[j], acc[i][j], 0, 0, 0);
        }
        __syncthreads();
    }
    // phase 2: k = 256..1023, B transposed in-kernel from dvt f32, XOR-swizzled
    for (int k0 = 256; k0 < 1024; k0 += 64) {
        #pragma unroll
        for (int c = wid; c < 32; c += 4)
            gload_lds16(Kwb + (size_t)(c * 8 + (lane >> 3)) * CIN + k0 + (lane & 7) * 8, As + c * 512);
        const float* dsrc = dvb + (size_t)(k0 - 256) * N + n0;
        #pragma unroll
        for (int it = 0; it < 4; it++) {
            int f4 = it * 256 + t;
            int r = f4 >> 4, c4 = (f4 & 15) * 4;
            float4 v = *(const float4*)(dsrc + (size_t)r * N + c4);
            Ls[r][c4 + 0] = v.x; Ls[r][c4 + 1] = v.y;
            Ls[r][c4 + 2] = v.z; Ls[r][c4 + 3] = v.w;
        }
        __syncthreads();
        {
            int rn = t >> 2;            // n row 0..63
            int ks = (t & 3) * 16;      // k start
            #pragma unroll
            for (int j2 = 0; j2 < 8; j2++) {
                int kk = ks + j2 * 2;
                uint val = (uint)f2bf(Ls[kk][rn]) | ((uint)f2bf(Ls[kk + 1][rn]) << 16);
                int idx = (rn * 64 + kk) ^ ((rn & 7) << 3);
                *(uint*)(Bs + idx) = val;
            }
        }
        __syncthreads();
        const int ra = wid * 64 + (lane & 15), rb = lane & 15, ko = (lane >> 4) * 8;
        #pragma unroll
        for (int kk = 0; kk < 64; kk += 32) {
            short8 a[4], bb[4];
            #pragma unroll
            for (int i = 0; i < 4; i++) a[i] = *(const short8*)(As + (ra + i * 16) * 64 + kk + ko);
            #pragma unroll
            for (int j = 0; j < 4; j++) {
                int row = rb + j * 16;
                int idx = (row * 64 + kk + ko) ^ ((row & 7) << 3);
                bb[j] = *(const short8*)(Bs + idx);
            }
            #pragma unroll
            for (int i = 0; i < 4; i++)
                #pragma unroll
                for (int j = 0; j < 4; j++)
                    acc[i][j] = __builtin_amdgcn_mfma_f32_16x16x32_bf16(a[i], bb[j], acc[i][j], 0, 0, 0);
        }
        __syncthreads();
    }

    // epilogue: bias, per-position L2 norm (cross-wave), scatter to Qc/Kc
    const int wm = wid * 64;
    float sj[4] = {0.f, 0.f, 0.f, 0.f};
    #pragma unroll
    for (int i = 0; i < 4; i++) {
        int mbase = wm + i * 16 + ((lane >> 4) * 4);
        float4 bias = *(const float4*)(Kb + mbase);
        #pragma unroll
        for (int j = 0; j < 4; j++) {
            acc[i][j][0] += bias.x; acc[i][j][1] += bias.y;
            acc[i][j][2] += bias.z; acc[i][j][3] += bias.w;
            sj[j] += acc[i][j][0] * acc[i][j][0] + acc[i][j][1] * acc[i][j][1]
                   + acc[i][j][2] * acc[i][j][2] + acc[i][j][3] * acc[i][j][3];
        }
    }
    #pragma unroll
    for (int j = 0; j < 4; j++) {
        sj[j] += __shfl_xor(sj[j], 16);
        sj[j] += __shfl_xor(sj[j], 32);
    }
    if (lane < 16) {
        #pragma unroll
        for (int j = 0; j < 4; j++) red[wid][j * 16 + lane] = sj[j];
    }
    __syncthreads();
    const int* pb = p2s + (size_t)b * N + n0;
    #pragma unroll
    for (int j = 0; j < 4; j++) {
        int n = j * 16 + (lane & 15);
        float s = red[0][n] + red[1][n] + red[2][n] + red[3][n];
        float invn = 1.f / (sqrtf(s) + 1e-8f);
        int sl = pb[n];
        ushort* dst = (sl & (1 << 30)) ? Qc : Kc;
        int slot = sl & 0x3FFFFFFF;
        ushort* drow = dst + ((size_t)b * N + slot) * CH;
        #pragma unroll
        for (int i = 0; i < 4; i++) {
            int mbase = wm + i * 16 + ((lane >> 4) * 4);
            ushort4 o = { f2bf(acc[i][j][0] * invn), f2bf(acc[i][j][1] * invn),
                          f2bf(acc[i][j][2] * invn), f2bf(acc[i][j][3] * invn) };
            *(ushort4*)(drow + mbase) = o;
        }
    }
}

// ---------------- score GEMM (compact, 128q x 64k tiles, 2 waves) ----------------
__global__ __launch_bounds__(128) void k_score(
    const ushort* __restrict__ Qc, const ushort* __restrict__ Kc,
    const float* __restrict__ kmc, const int* __restrict__ counts,
    ushort* __restrict__ P)
{
    const int b = blockIdx.z;
    const int nfgp = counts[b * 4 + 1], nbgp = counts[b * 4 + 3];
    const int m0 = blockIdx.y * 128;   // q tile
    const int n0 = blockIdx.x * 64;    // k tile
    if (m0 >= nfgp || n0 >= nbgp) return;
    __shared__ ushort SH[(128 + 64) * 64];
    const int t = threadIdx.x, lane = t & 63, wid = t >> 6;
    const ushort* Qb = Qc + (size_t)b * N * CH;
    const ushort* Kb_ = Kc + (size_t)b * N * CH;
    f32x4 acc[4][4]; zero_acc(acc);
    gemm_core<2, 1>(Qb, CH, m0, Kb_, CH, CH, Kb_, CH, n0, CH, SH, SH + 128 * 64, acc);

    const int wm = wid * 64;
    float km[4];
    #pragma unroll
    for (int j = 0; j < 4; j++) km[j] = kmc[(size_t)b * N + n0 + j * 16 + (lane & 15)];

    ushort* Cs = SH;   // 128 x 64 repack
    #pragma unroll
    for (int i = 0; i < 4; i++) {
        int rbase = wm + i * 16 + ((lane >> 4) * 4);
        #pragma unroll
        for (int j = 0; j < 4; j++) {
            int cl = j * 16 + (lane & 15);
            #pragma unroll
            for (int r = 0; r < 4; r++) {
                float p = (km[j] != 0.f) ? __expf(20.f * acc[i][j][r] - 20.f) : 0.f;
                Cs[(rbase + r) * 64 + cl] = f2bf(p);
            }
        }
    }
    __syncthreads();
    ushort* Pb = P + (size_t)b * PBS;
    #pragma unroll
    for (int it = 0; it < 8; it++) {
        int v8 = it * 128 + t;
        int row = v8 >> 3, c8 = (v8 & 7) * 8;
        *(uint4*)(Pb + (size_t)(m0 + row) * nbgp + n0 + c8) = *(const uint4*)(Cs + row * 64 + c8);
    }
}

// ---------------- PV GEMM (compact, BM=256, split-K bf16 partials) ----------------
__global__ __launch_bounds__(256) void k_att_fore(
    const ushort* __restrict__ xc, const ushort* __restrict__ P,
    const int* __restrict__ counts, ushort* __restrict__ AFp)
{
    const int b = blockIdx.z & (BATCH - 1);
    const int sk = blockIdx.z / BATCH;
    const int nfgp = counts[b * 4 + 1], nbgp = counts[b * 4 + 3];
    const int n0 = blockIdx.x * 64;    // qi tile
    if (n0 >= nfgp) return;
    const int kchunk = ((nbgp / 64 + SPLITK - 1) / SPLITK) * 64;
    const int k0s = sk * kchunk;
    const int len = min(kchunk, nbgp - k0s);

    const int lane = threadIdx.x & 63, wid = threadIdx.x >> 6;
    f32x4 acc[4][4]; zero_acc(acc);
    if (len > 0) {
        __shared__ ushort SH[(256 + 64) * 64];
        const ushort* Pb = P + (size_t)b * PBS + k0s;
        gemm_core<4, 1>(xc + (size_t)b * CH * N + k0s, N, 0,
                        Pb, nbgp, 1 << 30, Pb, nbgp,
                        n0, len, SH, SH + 256 * 64, acc);
    }
    ushort* Ap = AFp + ((size_t)(sk * BATCH + b) * N) * CH;
    const int wm = wid * 64;
    #pragma unroll
    for (int j = 0; j < 4; j++) {
        int qi = n0 + j * 16 + (lane & 15);
        #pragma unroll
        for (int i = 0; i < 4; i++) {
            int mbase = wm + i * 16 + ((lane >> 4) * 4);
            ushort4 o = { f2bf(acc[i][j][0]), f2bf(acc[i][j][1]),
                          f2bf(acc[i][j][2]), f2bf(acc[i][j][3]) };
            *(ushort4*)(Ap + (size_t)qi * CH + mbase) = o;
        }
    }
}

// ---------------- fused rowsum + AF reduce: wave per (b,qi) ----------------
__global__ __launch_bounds__(256) void k_rowaf(
    const ushort* __restrict__ P, const ushort* __restrict__ AFp,
    const int* __restrict__ fgi, const int* __restrict__ counts,
    float* __restrict__ inv, ushort* __restrict__ AFt)
{
    const int t = threadIdx.x, lane = t & 63, wid = t >> 6;
    const int g = blockIdx.x * 4 + wid;       // b*N + qi
    const int b = g >> 12, qi = g & 4095;
    const int nfgp = counts[b * 4 + 1], nbgp = counts[b * 4 + 3];
    if (qi >= nfgp) return;
    const ushort* row = P + (size_t)b * PBS + (size_t)qi * nbgp;
    float s = 0.f;
    for (int it = 0; it < 8; it++) {
        int base = it * 512 + lane * 8;
        if (base < nbgp) {
            uint4 v = *(const uint4*)(row + base);
            const ushort* u = (const ushort*)&v;
            #pragma unroll
            for (int e = 0; e < 8; e++) s += bf2f(u[e]);
        }
    }
    #pragma unroll
    for (int mm = 1; mm < 64; mm <<= 1) s += __shfl_xor(s, mm);
    float iq = (s > 0.f) ? 1.f / s : 0.f;
    if (lane == 0) inv[g] = iq;
    if (qi < counts[b * 4]) {                  // nfg: real fg rows only
        const size_t rowoff = ((size_t)b * N + qi) * CH + lane * 4;
        float s0 = 0.f, s1 = 0.f, s2 = 0.f, s3 = 0.f;
        #pragma unroll
        for (int sk = 0; sk < SPLITK; sk++) {
            ushort4 v = *(const ushort4*)(AFp + (size_t)sk * BATCH * N * CH + rowoff);
            s0 += bf2f(v.x); s1 += bf2f(v.y); s2 += bf2f(v.z); s3 += bf2f(v.w);
        }
        int q = fgi[g];
        ushort4 o = { f2bf(s0 * iq), f2bf(s1 * iq), f2bf(s2 * iq), f2bf(s3 * iq) };
        *(ushort4*)(AFt + ((size_t)b * N + q) * CH + lane * 4) = o;
    }
}

// ---------------- fused GEMM + blend (dense) + attmask epilogue ----------------
__global__ __launch_bounds__(128) void k_fused(
    const ushort* __restrict__ fwb, const ushort* __restrict__ AFt,
    const ushort* __restrict__ xT, const float* __restrict__ x,
    const float* __restrict__ m_, const float* __restrict__ vis,
    const uint* __restrict__ maxv, float* __restrict__ out,
    float* __restrict__ amask)
{
    __shared__ ushort SH[(64 + 128) * 64];
    const int b = blockIdx.z;
    const int n0 = blockIdx.x * 128, m0 = blockIdx.y * 64;
    const int lane = threadIdx.x & 63, wid = threadIdx.x >> 6;
    const int wn = (wid & 1) * 64;
    f32x4 acc[4][4]; zero_acc(acc);
    gemm_core<1, 2>(fwb, KC, m0,
                    AFt + (size_t)b * N * CH, CH, CH,
                    xT + (size_t)b * N * CH, CH,
                    n0, KC, SH, SH + 64 * 64, acc);
    const float* mb = m_ + (size_t)b * N;
    const float* xc_ = x + (size_t)b * CH * N;
    float* ob = out + (size_t)b * CH * N;
    #pragma unroll
    for (int j = 0; j < 4; j++) {
        int n = n0 + wn + j * 16 + (lane & 15);
        float mv = mb[n];
        #pragma unroll
        for (int i = 0; i < 4; i++) {
            int mbase = m0 + i * 16 + ((lane >> 4) * 4);
            #pragma unroll
            for (int r = 0; r < 4; r++) {
                int c = mbase + r;
                ob[(size_t)c * N + n] = (mv != 0.f) ? acc[i][j][r] : xc_[(size_t)c * N + n];
            }
        }
    }
    // fused attmask: each of the 512 blocks writes 2048 upsampled elements
    {
        float rcp = 1.f / __builtin_bit_cast(float, maxv[0]);
        int bid = blockIdx.x + 32 * blockIdx.y + 128 * blockIdx.z;   // 0..511
        int base = bid * 2048;
        #pragma unroll
        for (int it = 0; it < 16; it++) {
            int idx = base + it * 128 + threadIdx.x;
            int bb = idx >> 18;
            int r = idx & 262143;
            int Y = r >> 9, X = r & 511;
            amask[idx] = vis[(size_t)bb * N + (Y >> 3) * 64 + (X >> 3)] * rcp;
        }
    }
}

// ---------------- colsum (coalesced, row-major sweep) ----------------
__global__ __launch_bounds__(256) void k_colsum(
    const ushort* __restrict__ P, const float* __restrict__ inv,
    const int* __restrict__ counts, float* __restrict__ part)
{
    const int b = blockIdx.z, qc = blockIdx.y, t = threadIdx.x;
    const int nfg = counts[b * 4], nbgp = counts[b * 4 + 3];
    const int ki0 = blockIdx.x * 2048 + t * 8;
    if (ki0 >= nbgp) return;
    const int qchunk = (nfg + QCH - 1) / QCH;
    const int q0 = qc * qchunk, q1 = min(q0 + qchunk, nfg);
    const ushort* base = P + (size_t)b * PBS + (size_t)q0 * nbgp + ki0;
    const float* ib = inv + (size_t)b * N;
    float acc[8] = {};
    int q = q0;
    for (; q + 4 <= q1; q += 4) {
        uint4 v0 = *(const uint4*)(base);
        uint4 v1 = *(const uint4*)(base + (size_t)nbgp);
        uint4 v2 = *(const uint4*)(base + 2 * (size_t)nbgp);
        uint4 v3 = *(const uint4*)(base + 3 * (size_t)nbgp);
        float i0 = ib[q], i1 = ib[q + 1], i2 = ib[q + 2], i3 = ib[q + 3];
        const ushort* u0 = (const ushort*)&v0;
        const ushort* u1 = (const ushort*)&v1;
        const ushort* u2 = (const ushort*)&v2;
        const ushort* u3 = (const ushort*)&v3;
        #pragma unroll
        for (int e = 0; e < 8; e++)
            acc[e] += bf2f(u0[e]) * i0 + bf2f(u1[e]) * i1 + bf2f(u2[e]) * i2 + bf2f(u3[e]) * i3;
        base += 4 * (size_t)nbgp;
    }
    for (; q < q1; q++) {
        uint4 v = *(const uint4*)(base);
        float iq = ib[q];
        const ushort* u = (const ushort*)&v;
        #pragma unroll
        for (int e = 0; e < 8; e++) acc[e] += bf2f(u[e]) * iq;
        base += (size_t)nbgp;
    }
    float* pp = part + (size_t)qc * (BATCH * N) + (size_t)b * N + ki0;
    float4 o0 = {acc[0], acc[1], acc[2], acc[3]};
    float4 o1 = {acc[4], acc[5], acc[6], acc[7]};
    *(float4*)(pp)     = o0;
    *(float4*)(pp + 4) = o1;
}

// reduce colsum partials, scatter to vis, track global max (uint atomicMax, vis>=0)
__global__ void k_colsum_final(const float* __restrict__ part, const int* __restrict__ bgi,
                               const int* __restrict__ counts, float* __restrict__ vis,
                               uint* __restrict__ maxv)
{
    int g = blockIdx.x * 256 + threadIdx.x;
    int b = g >> 12, ki = g & 4095;
    int t = threadIdx.x;
    float s = 0.f;
    if (ki < counts[b * 4 + 2]) {
        #pragma unroll
        for (int j = 0; j < QCH; j++) s += part[(size_t)j * (BATCH * N) + g];
        vis[(size_t)b * N + bgi[(size_t)b * N + ki]] = s;
    }
    __shared__ float red[256];
    red[t] = s; __syncthreads();
    for (int st = 128; st > 0; st >>= 1) { if (t < st) red[t] = fmaxf(red[t], red[t + st]); __syncthreads(); }
    if (t == 0) atomicMax(maxv, __float_as_uint(red[0]));
}

// ---------------- launch ----------------
extern "C" void kernel_launch(void* const* d_in, const int* in_sizes, int n_in,
                              void* d_out, int out_size, void* d_ws, size_t ws_size,
                              hipStream_t stream)
{
    const float* x    = (const float*)d_in[0];
    const float* mask = (const float*)d_in[1];
    const float* dvt  = (const float*)d_in[2];
    const float* Kw   = (const float*)d_in[3];
    const float* Kb   = (const float*)d_in[4];
    const float* fw   = (const float*)d_in[5];
    float* out = (float*)d_out;

    char* ws = (char*)d_ws;
    float*  m    = (float*)(ws + OFF_M);
    float*  inv  = (float*)(ws + OFF_INV);
    float*  vis  = (float*)(ws + OFF_VIS);
    float*  maxv = (float*)(ws + OFF_MAXV);
    int*    cnt  = (int*)  (ws + OFF_CNT);
    int*    fgi  = (int*)  (ws + OFF_FGI);
    int*    bgi  = (int*)  (ws + OFF_BGI);
    int*    p2s  = (int*)  (ws + OFF_P2S);
    float*  kmc  = (float*)(ws + OFF_KMC);
    float*  part = (float*)(ws + OFF_PART);
    ushort* Kwb  = (ushort*)(ws + OFF_KWB);
    ushort* fwb  = (ushort*)(ws + OFF_FWB);
    ushort* xT   = (ushort*)(ws + OFF_XT);
    ushort* Qc   = (ushort*)(ws + OFF_QC);
    ushort* Kcc  = (ushort*)(ws + OFF_KCC);
    ushort* xc   = (ushort*)(ws + OFF_XC);
    ushort* AFt  = (ushort*)(ws + OFF_AFT);
    ushort* P    = (ushort*)(ws + OFF_P);
    ushort* AFp  = (ushort*)(ws + OFF_AFP);

    k_prep       <<<dim3(64 + (CH * CIN + CH * KC) / 256), 256, 0, stream>>>(
                     mask, Kw, fw, m, vis, (uint*)maxv, Kwb, fwb);
    k_scan       <<<dim3(BATCH), 256, 0, stream>>>(m, fgi, bgi, cnt, kmc, p2s);
    k_tr         <<<dim3(CH / 64, 64, BATCH), 256, 0, stream>>>(x, xT, CH);
    k_feats      <<<dim3(N / 64, 1, BATCH), 256, 0, stream>>>(Kwb, xT, dvt, Kb, p2s, Qc, Kcc);
    k_vgather    <<<dim3(N / 64, BATCH), 256, 0, stream>>>(xT, bgi, cnt, xc);
    k_score      <<<dim3(N / 64, N / 128, BATCH), 128, 0, stream>>>(Qc, Kcc, kmc, cnt, P);
    k_att_fore   <<<dim3(N / 64, 1, BATCH * SPLITK), 256, 0, stream>>>(xc, P, cnt, AFp);
    k_rowaf      <<<dim3(BATCH * N / 4), 256, 0, stream>>>(P, AFp, fgi, cnt, inv, AFt);
    k_colsum     <<<dim3(2, QCH, BATCH), 256, 0, stream>>>(P, inv, cnt, part);
    k_colsum_final<<<dim3(BATCH * N / 256), 256, 0, stream>>>(part, bgi, cnt, vis, (uint*)maxv);
    k_fused      <<<dim3(N / 128, CH / 64, BATCH), 128, 0, stream>>>(
                     fwb, AFt, xT, x, m, vis, (const uint*)maxv, out, out + (size_t)BATCH * CH * N);
}

// Round 16
// 156.551 us; speedup vs baseline: 1.3841x; 1.0367x over previous
//
#include <hip/hip_runtime.h>
#include <hip/hip_bf16.h>

typedef __attribute__((ext_vector_type(8))) short short8;
typedef __attribute__((ext_vector_type(4))) float f32x4;
typedef unsigned int uint;
typedef unsigned short ushort;

constexpr int BATCH = 4;
constexpr int CH    = 256;
constexpr int N     = 4096;   // 64*64
constexpr int DVC   = 768;
constexpr int CIN   = 1024;   // CH + DVC
constexpr int KC    = 512;    // 2*CH
constexpr int PBS   = 5 * 1024 * 1024;  // P per-batch stride (elements)
constexpr int QCH   = 32;     // colsum q-chunks
constexpr int SPLITK = 4;     // att_fore K-split

// ---------------- workspace layout (bytes) ----------------
constexpr size_t OFF_M    = 0;                       // 16384 f32
constexpr size_t OFF_INV  = 64ull << 10;             // 16384 f32
constexpr size_t OFF_VIS  = 128ull << 10;            // 16384 f32
constexpr size_t OFF_MAXV = 192ull << 10;            // 1 f32
constexpr size_t OFF_CNT  = 196ull << 10;            // 16 ints
constexpr size_t OFF_FGI  = 256ull << 10;            // 16384 int
constexpr size_t OFF_BGI  = 320ull << 10;            // 16384 int
constexpr size_t OFF_P2S  = 384ull << 10;            // 16384 int
constexpr size_t OFF_KMC  = 448ull << 10;            // 16384 f32
constexpr size_t OFF_PART = 1ull << 20;              // 4MB partials
constexpr size_t OFF_KWB  = 5ull << 20;              // 512KB bf16
constexpr size_t OFF_FWB  = OFF_KWB + (512ull << 10);// 256KB bf16
constexpr size_t OFF_XT   = 6ull << 20;              // [b][n][256] bf16 = 8MB
constexpr size_t OFF_QC   = 38ull << 20;             // [b][qi][256] bf16 = 8MB
constexpr size_t OFF_KCC  = 46ull << 20;             // [b][ki][256] bf16 = 8MB
constexpr size_t OFF_XC   = 54ull << 20;             // [b][c][4096] bf16 = 8MB
constexpr size_t OFF_AFT  = 62ull << 20;             // [b][n][256] bf16 = 8MB
constexpr size_t OFF_P    = 70ull << 20;             // compact P bf16, 4 x PBS = 40MB
constexpr size_t OFF_AFP  = 110ull << 20;            // bf16 partials [sk][b][qi][c] = 32MB

// ---------------- helpers ----------------
__device__ __forceinline__ ushort f2bf(float f) {
    __hip_bfloat16 h = __float2bfloat16(f);
    return __builtin_bit_cast(ushort, h);
}
__device__ __forceinline__ float bf2f(ushort u) {
    uint v = (uint)u << 16;
    return __builtin_bit_cast(float, v);
}

typedef const __attribute__((address_space(1))) uint* gptr_t;
typedef __attribute__((address_space(3))) uint* lptr_t;
__device__ __forceinline__ void gload_lds16(const void* g, void* l) {
    __builtin_amdgcn_global_load_lds((gptr_t)g, (lptr_t)l, 16, 0, 0);
}

// ---------------- shared GEMM mainloop ----------------
template<int WM, int WN>
__device__ __forceinline__ void gemm_core(
    const ushort* __restrict__ A0, int lda, int m0,
    const ushort* __restrict__ B0, int ldb0, int kend0,
    const ushort* __restrict__ B1, int ldb1,
    int n0, int K,
    ushort* AsL, ushort* BsL, f32x4 acc[4][4])
{
    constexpr int NW = WM * WN, BM = WM * 64, BN = WN * 64;
    const int t = threadIdx.x, lane = t & 63, wid = t >> 6;
    const int wm = (wid / WN) * 64, wn = (wid % WN) * 64;

    for (int k0 = 0; k0 < K; k0 += 64) {
        #pragma unroll
        for (int c = wid; c < BM / 8; c += NW) {
            const ushort* g = A0 + (size_t)(m0 + c * 8 + (lane >> 3)) * lda + (k0 + (lane & 7) * 8);
            gload_lds16(g, AsL + c * 512);
        }
        const ushort* Bsrc = (k0 < kend0) ? B0 : B1;
        const int ldb = (k0 < kend0) ? ldb0 : ldb1;
        const int kc  = (k0 < kend0) ? k0 : (k0 - kend0);
        #pragma unroll
        for (int c = wid; c < BN / 8; c += NW) {
            const ushort* g = Bsrc + (size_t)(n0 + c * 8 + (lane >> 3)) * ldb + (kc + (lane & 7) * 8);
            gload_lds16(g, BsL + c * 512);
        }
        __syncthreads();

        const int ra = wm + (lane & 15), rb = wn + (lane & 15), ko = (lane >> 4) * 8;
        #pragma unroll
        for (int kk = 0; kk < 64; kk += 32) {
            short8 a[4], b[4];
            #pragma unroll
            for (int i = 0; i < 4; i++) a[i] = *(const short8*)(AsL + (ra + i * 16) * 64 + kk + ko);
            #pragma unroll
            for (int j = 0; j < 4; j++) b[j] = *(const short8*)(BsL + (rb + j * 16) * 64 + kk + ko);
            #pragma unroll
            for (int i = 0; i < 4; i++)
                #pragma unroll
                for (int j = 0; j < 4; j++)
                    acc[i][j] = __builtin_amdgcn_mfma_f32_16x16x32_bf16(a[i], b[j], acc[i][j], 0, 0, 0);
        }
        __syncthreads();
    }
}

__device__ __forceinline__ void zero_acc(f32x4 acc[4][4]) {
    f32x4 z = {0.f, 0.f, 0.f, 0.f};
    #pragma unroll
    for (int i = 0; i < 4; i++)
        #pragma unroll
        for (int j = 0; j < 4; j++) acc[i][j] = z;
}

// ---------------- prep + x-transpose (merged, independent halves) ----------------
// bid < 64          : maskpool + vis/maxv init
// 64 <= bid < 1600  : weight conversion
// bid >= 1600       : transpose x f32 [b][256][4096] -> bf16 xT [b][4096][256]
__global__ __launch_bounds__(256) void k_prep_tr(
    const float* __restrict__ mask, const float* __restrict__ Kw,
    const float* __restrict__ fw, const float* __restrict__ x,
    float* __restrict__ m, float* __restrict__ vis, uint* __restrict__ maxv,
    ushort* __restrict__ Kwb, ushort* __restrict__ fwb, ushort* __restrict__ xT)
{
    __shared__ float Ls[64][65];
    const int bid = blockIdx.x;
    const int t = threadIdx.x;
    if (bid < 64) {
        int idx = bid * 256 + t;
        int b = idx >> 12, p = idx & 4095;
        int y = p >> 6, xx = p & 63;
        const float* base = mask + (size_t)b * 512 * 512 + (y * 8) * 512 + xx * 8;
        float mx = 0.f;
        for (int dy = 0; dy < 8; dy++) {
            #pragma unroll
            for (int dx = 0; dx < 8; dx++) mx = fmaxf(mx, base[dy * 512 + dx]);
        }
        m[idx] = (mx > 0.f) ? 1.f : 0.f;
        vis[idx] = 0.f;
        if (idx == 0) maxv[0] = 0u;
    } else if (bid < 1600) {
        int i = (bid - 64) * 256 + t;
        if (i < CH * CIN) Kwb[i] = f2bf(Kw[i]);
        else              fwb[i - CH * CIN] = f2bf(fw[i - CH * CIN]);
    } else {
        const int tr_id = bid - 1600;               // [0,1024)
        const int ci0 = (tr_id & 3) * 64;
        const int n0 = ((tr_id >> 2) & 63) * 64;
        const int b = tr_id >> 8;
        const float* s = x + (size_t)b * CH * 4096;
        #pragma unroll
        for (int it = 0; it < 4; it++) {
            int f4 = it * 256 + t;
            int r = f4 >> 4, c4 = f4 & 15;
            float4 v = *(const float4*)(s + (size_t)(ci0 + r) * 4096 + n0 + c4 * 4);
            Ls[r][c4 * 4 + 0] = v.x; Ls[r][c4 * 4 + 1] = v.y;
            Ls[r][c4 * 4 + 2] = v.z; Ls[r][c4 * 4 + 3] = v.w;
        }
        __syncthreads();
        ushort* d = xT + (size_t)b * 4096 * CH;
        #pragma unroll
        for (int it = 0; it < 8; it++) {
            int p = it * 256 + t;
            int rn = p >> 5, cc2 = p & 31;
            uint val = (uint)f2bf(Ls[cc2 * 2][rn]) | ((uint)f2bf(Ls[cc2 * 2 + 1][rn]) << 16);
            *(uint*)(d + (size_t)(n0 + rn) * CH + ci0 + cc2 * 2) = val;
        }
    }
}

__global__ __launch_bounds__(256) void k_scan(
    const float* __restrict__ m, int* __restrict__ fgi, int* __restrict__ bgi,
    int* __restrict__ counts, float* __restrict__ kmc, int* __restrict__ p2s)
{
    const int b = blockIdx.x, t = threadIdx.x;
    const float* mb = m + (size_t)b * N;
    __shared__ int sfg[256], sbg[256];
    bool isf[16];
    int cf = 0, cb_ = 0;
    #pragma unroll
    for (int j = 0; j < 16; j++) {
        bool f = mb[t * 16 + j] != 0.f;
        isf[j] = f; cf += f ? 1 : 0; cb_ += f ? 0 : 1;
    }
    sfg[t] = cf; sbg[t] = cb_;
    __syncthreads();
    for (int off = 1; off < 256; off <<= 1) {
        int vf = (t >= off) ? sfg[t - off] : 0;
        int vb = (t >= off) ? sbg[t - off] : 0;
        __syncthreads();
        sfg[t] += vf; sbg[t] += vb;
        __syncthreads();
    }
    int basef = sfg[t] - cf, baseb = sbg[t] - cb_;
    int nfg = sfg[255], nbg = sbg[255];
    #pragma unroll
    for (int j = 0; j < 16; j++) {
        int p = t * 16 + j;
        if (isf[j]) { fgi[b * N + basef] = p; p2s[b * N + p] = basef | (1 << 30); basef++; }
        else        { bgi[b * N + baseb] = p; p2s[b * N + p] = baseb; baseb++; }
    }
    if (t == 0) {
        counts[b * 4 + 0] = nfg;
        counts[b * 4 + 1] = (nfg + 127) & ~127;
        counts[b * 4 + 2] = nbg;
        counts[b * 4 + 3] = (nbg + 127) & ~127;
    }
    for (int j = t; j < N; j += 256) kmc[b * N + j] = (j < nbg) ? 1.f : 0.f;
}

// ---------------- feats GEMM + V gather (merged, independent halves) ----------------
// bid < 256 : feats (fused dvt-transpose + bias/L2-norm/scatter to Qc/Kc)
// bid >= 256: vgather (xc[b][c][j] = xT[b][bgi[j]][c])
__global__ __launch_bounds__(256) void k_feats_vg(
    const ushort* __restrict__ Kwb, const ushort* __restrict__ xT,
    const float* __restrict__ dvt, const float* __restrict__ Kb,
    const int* __restrict__ p2s, const int* __restrict__ bgi,
    const int* __restrict__ counts,
    ushort* __restrict__ Qc, ushort* __restrict__ Kc, ushort* __restrict__ xc)
{
    __shared__ __align__(16) char smem[58624];
    const int bid = blockIdx.x;
    const int t = threadIdx.x, lane = t & 63, wid = t >> 6;

    if (bid >= 256) {
        // ---- vgather half ----
        ushort (*Xs)[264] = (ushort(*)[264])smem;
        const int vid = bid - 256;
        const int b = vid >> 6;
        const int ki0 = (vid & 63) * 64;
        const int nbg = counts[b * 4 + 2], nbgp = counts[b * 4 + 3];
        if (ki0 >= nbgp) return;
        const int j = t >> 2, part = t & 3;
        const int ki = ki0 + j;
        if (ki < nbg) {
            const ushort* src = xT + ((size_t)b * N + bgi[(size_t)b * N + ki]) * CH + part * 64;
            #pragma unroll
            for (int q = 0; q < 8; q++)
                *(uint4*)&Xs[j][part * 64 + q * 8] = *(const uint4*)(src + q * 8);
        } else {
            uint4 z = {0, 0, 0, 0};
            #pragma unroll
            for (int q = 0; q < 8; q++)
                *(uint4*)&Xs[j][part * 64 + q * 8] = z;
        }
        __syncthreads();
        const int c = t;
        ushort* dst = xc + ((size_t)b * CH + c) * N + ki0;
        uint w[32];
        #pragma unroll
        for (int jj = 0; jj < 32; jj++)
            w[jj] = (uint)Xs[2 * jj][c] | ((uint)Xs[2 * jj + 1][c] << 16);
        #pragma unroll
        for (int q = 0; q < 8; q++) {
            uint4 o = { w[q * 4], w[q * 4 + 1], w[q * 4 + 2], w[q * 4 + 3] };
            *(uint4*)(dst + q * 8) = o;
        }
        return;
    }

    // ---- feats half ----
    ushort* As = (ushort*)smem;                       // 32 KB
    ushort* Bs = (ushort*)(smem + 32768);             // 8 KB
    float (*Ls)[65] = (float(*)[65])(smem + 40960);   // 16.25 KB
    float (*red)[64] = (float(*)[64])(smem + 57600);  // 1 KB
    const int b = bid >> 6;
    const int n0 = (bid & 63) * 64;
    const ushort* xTb = xT + (size_t)b * N * CH;
    const float* dvb = dvt + (size_t)b * DVC * N;
    f32x4 acc[4][4]; zero_acc(acc);

    // phase 1: k = 0..255, B from xT (linear LDS)
    for (int k0 = 0; k0 < 256; k0 += 64) {
        #pragma unroll
        for (int c = wid; c < 32; c += 4)
            gload_lds16(Kwb + (size_t)(c * 8 + (lane >> 3)) * CIN + k0 + (lane & 7) * 8, As + c * 512);
        #pragma unroll
        for (int c = wid; c < 8; c += 4)
            gload_lds16(xTb + (size_t)(n0 + c * 8 + (lane >> 3)) * CH + k0 + (lane & 7) * 8, Bs + c * 512);
        __syncthreads();
        const int ra = wid * 64 + (lane & 15), rb = lane & 15, ko = (lane >> 4) * 8;
        #pragma unroll
        for (int kk = 0; kk < 64; kk += 32) {
            short8 a[4], bb[4];
            #pragma unroll
            for (int i = 0; i < 4; i++) a[i] = *(const short8*)(As + (ra + i * 16) * 64 + kk + ko);
            #pragma unroll
            for (int j = 0; j < 4; j++) bb[j] = *(const short8*)(Bs + (rb + j * 16) * 64 + kk + ko);
            #pragma unroll
            for (int i = 0; i < 4; i++)
                #pragma unroll
                for (int j = 0; j < 4; j++)
                    acc[i][j] = __builtin_amdgcn_mfma_f32_16x16x32_bf16(a[i], bb[j], acc[i][j], 0, 0, 0);
        }
        __syncthreads();
    }
    // phase 2: k = 256..1023, B transposed in-kernel from dvt f32, XOR-swizzled
    for (int k0 = 256; k0 < 1024; k0 += 64) {
        #pragma unroll
        for (int c = wid; c < 32; c += 4)
            gload_lds16(Kwb + (size_t)(c * 8 + (lane >> 3)) * CIN + k0 + (lane & 7) * 8, As + c * 512);
        const float* dsrc = dvb + (size_t)(k0 - 256) * N + n0;
        #pragma unroll
        for (int it = 0; it < 4; it++) {
            int f4 = it * 256 + t;
            int r = f4 >> 4, c4 = (f4 & 15) * 4;
            float4 v = *(const float4*)(dsrc + (size_t)r * N + c4);
            Ls[r][c4 + 0] = v.x; Ls[r][c4 + 1] = v.y;
            Ls[r][c4 + 2] = v.z; Ls[r][c4 + 3] = v.w;
        }
        __syncthreads();
        {
            int rn = t >> 2;            // n row 0..63
            int ks = (t & 3) * 16;      // k start
            #pragma unroll
            for (int j2 = 0; j2 < 8; j2++) {
                int kk = ks + j2 * 2;
                uint val = (uint)f2bf(Ls[kk][rn]) | ((uint)f2bf(Ls[kk + 1][rn]) << 16);
                int idx = (rn * 64 + kk) ^ ((rn & 7) << 3);
                *(uint*)(Bs + idx) = val;
            }
        }
        __syncthreads();
        const int ra = wid * 64 + (lane & 15), rb = lane & 15, ko = (lane >> 4) * 8;
        #pragma unroll
        for (int kk = 0; kk < 64; kk += 32) {
            short8 a[4], bb[4];
            #pragma unroll
            for (int i = 0; i < 4; i++) a[i] = *(const short8*)(As + (ra + i * 16) * 64 + kk + ko);
            #pragma unroll
            for (int j = 0; j < 4; j++) {
                int row = rb + j * 16;
                int idx = (row * 64 + kk + ko) ^ ((row & 7) << 3);
                bb[j] = *(const short8*)(Bs + idx);
            }
            #pragma unroll
            for (int i = 0; i < 4; i++)
                #pragma unroll
                for (int j = 0; j < 4; j++)
                    acc[i][j] = __builtin_amdgcn_mfma_f32_16x16x32_bf16(a[i], bb[j], acc[i][j], 0, 0, 0);
        }
        __syncthreads();
    }

    // epilogue: bias, per-position L2 norm (cross-wave), scatter to Qc/Kc
    const int wm = wid * 64;
    float sj[4] = {0.f, 0.f, 0.f, 0.f};
    #pragma unroll
    for (int i = 0; i < 4; i++) {
        int mbase = wm + i * 16 + ((lane >> 4) * 4);
        float4 bias = *(const float4*)(Kb + mbase);
        #pragma unroll
        for (int j = 0; j < 4; j++) {
            acc[i][j][0] += bias.x; acc[i][j][1] += bias.y;
            acc[i][j][2] += bias.z; acc[i][j][3] += bias.w;
            sj[j] += acc[i][j][0] * acc[i][j][0] + acc[i][j][1] * acc[i][j][1]
                   + acc[i][j][2] * acc[i][j][2] + acc[i][j][3] * acc[i][j][3];
        }
    }
    #pragma unroll
    for (int j = 0; j < 4; j++) {
        sj[j] += __shfl_xor(sj[j], 16);
        sj[j] += __shfl_xor(sj[j], 32);
    }
    if (lane < 16) {
        #pragma unroll
        for (int j = 0; j < 4; j++) red[wid][j * 16 + lane] = sj[j];
    }
    __syncthreads();
    const int* pb = p2s + (size_t)b * N + n0;
    #pragma unroll
    for (int j = 0; j < 4; j++) {
        int n = j * 16 + (lane & 15);
        float s = red[0][n] + red[1][n] + red[2][n] + red[3][n];
        float invn = 1.f / (sqrtf(s) + 1e-8f);
        int sl = pb[n];
        ushort* dst = (sl & (1 << 30)) ? Qc : Kc;
        int slot = sl & 0x3FFFFFFF;
        ushort* drow = dst + ((size_t)b * N + slot) * CH;
        #pragma unroll
        for (int i = 0; i < 4; i++) {
            int mbase = wm + i * 16 + ((lane >> 4) * 4);
            ushort4 o = { f2bf(acc[i][j][0] * invn), f2bf(acc[i][j][1] * invn),
                          f2bf(acc[i][j][2] * invn), f2bf(acc[i][j][3] * invn) };
            *(ushort4*)(drow + mbase) = o;
        }
    }
}

// ---------------- score GEMM (compact, 128q x 64k tiles, 2 waves) ----------------
__global__ __launch_bounds__(128) void k_score(
    const ushort* __restrict__ Qc, const ushort* __restrict__ Kc,
    const float* __restrict__ kmc, const int* __restrict__ counts,
    ushort* __restrict__ P)
{
    const int b = blockIdx.z;
    const int nfgp = counts[b * 4 + 1], nbgp = counts[b * 4 + 3];
    const int m0 = blockIdx.y * 128;   // q tile
    const int n0 = blockIdx.x * 64;    // k tile
    if (m0 >= nfgp || n0 >= nbgp) return;
    __shared__ ushort SH[(128 + 64) * 64];
    const int t = threadIdx.x, lane = t & 63, wid = t >> 6;
    const ushort* Qb = Qc + (size_t)b * N * CH;
    const ushort* Kb_ = Kc + (size_t)b * N * CH;
    f32x4 acc[4][4]; zero_acc(acc);
    gemm_core<2, 1>(Qb, CH, m0, Kb_, CH, CH, Kb_, CH, n0, CH, SH, SH + 128 * 64, acc);

    const int wm = wid * 64;
    float km[4];
    #pragma unroll
    for (int j = 0; j < 4; j++) km[j] = kmc[(size_t)b * N + n0 + j * 16 + (lane & 15)];

    ushort* Cs = SH;   // 128 x 64 repack
    #pragma unroll
    for (int i = 0; i < 4; i++) {
        int rbase = wm + i * 16 + ((lane >> 4) * 4);
        #pragma unroll
        for (int j = 0; j < 4; j++) {
            int cl = j * 16 + (lane & 15);
            #pragma unroll
            for (int r = 0; r < 4; r++) {
                float p = (km[j] != 0.f) ? __expf(20.f * acc[i][j][r] - 20.f) : 0.f;
                Cs[(rbase + r) * 64 + cl] = f2bf(p);
            }
        }
    }
    __syncthreads();
    ushort* Pb = P + (size_t)b * PBS;
    #pragma unroll
    for (int it = 0; it < 8; it++) {
        int v8 = it * 128 + t;
        int row = v8 >> 3, c8 = (v8 & 7) * 8;
        *(uint4*)(Pb + (size_t)(m0 + row) * nbgp + n0 + c8) = *(const uint4*)(Cs + row * 64 + c8);
    }
}

// ---------------- PV GEMM (compact, BM=256, split-K bf16 partials) ----------------
__global__ __launch_bounds__(256) void k_att_fore(
    const ushort* __restrict__ xc, const ushort* __restrict__ P,
    const int* __restrict__ counts, ushort* __restrict__ AFp)
{
    const int b = blockIdx.z & (BATCH - 1);
    const int sk = blockIdx.z / BATCH;
    const int nfgp = counts[b * 4 + 1], nbgp = counts[b * 4 + 3];
    const int n0 = blockIdx.x * 64;    // qi tile
    if (n0 >= nfgp) return;
    const int kchunk = ((nbgp / 64 + SPLITK - 1) / SPLITK) * 64;
    const int k0s = sk * kchunk;
    const int len = min(kchunk, nbgp - k0s);

    const int lane = threadIdx.x & 63, wid = threadIdx.x >> 6;
    f32x4 acc[4][4]; zero_acc(acc);
    if (len > 0) {
        __shared__ ushort SH[(256 + 64) * 64];
        const ushort* Pb = P + (size_t)b * PBS + k0s;
        gemm_core<4, 1>(xc + (size_t)b * CH * N + k0s, N, 0,
                        Pb, nbgp, 1 << 30, Pb, nbgp,
                        n0, len, SH, SH + 256 * 64, acc);
    }
    ushort* Ap = AFp + ((size_t)(sk * BATCH + b) * N) * CH;
    const int wm = wid * 64;
    #pragma unroll
    for (int j = 0; j < 4; j++) {
        int qi = n0 + j * 16 + (lane & 15);
        #pragma unroll
        for (int i = 0; i < 4; i++) {
            int mbase = wm + i * 16 + ((lane >> 4) * 4);
            ushort4 o = { f2bf(acc[i][j][0]), f2bf(acc[i][j][1]),
                          f2bf(acc[i][j][2]), f2bf(acc[i][j][3]) };
            *(ushort4*)(Ap + (size_t)qi * CH + mbase) = o;
        }
    }
}

// ---------------- fused rowsum + AF reduce: wave per (b,qi) ----------------
__global__ __launch_bounds__(256) void k_rowaf(
    const ushort* __restrict__ P, const ushort* __restrict__ AFp,
    const int* __restrict__ fgi, const int* __restrict__ counts,
    float* __restrict__ inv, ushort* __restrict__ AFt)
{
    const int t = threadIdx.x, lane = t & 63, wid = t >> 6;
    const int g = blockIdx.x * 4 + wid;       // b*N + qi
    const int b = g >> 12, qi = g & 4095;
    const int nfgp = counts[b * 4 + 1], nbgp = counts[b * 4 + 3];
    if (qi >= nfgp) return;
    const ushort* row = P + (size_t)b * PBS + (size_t)qi * nbgp;
    float s = 0.f;
    for (int it = 0; it < 8; it++) {
        int base = it * 512 + lane * 8;
        if (base < nbgp) {
            uint4 v = *(const uint4*)(row + base);
            const ushort* u = (const ushort*)&v;
            #pragma unroll
            for (int e = 0; e < 8; e++) s += bf2f(u[e]);
        }
    }
    #pragma unroll
    for (int mm = 1; mm < 64; mm <<= 1) s += __shfl_xor(s, mm);
    float iq = (s > 0.f) ? 1.f / s : 0.f;
    if (lane == 0) inv[g] = iq;
    if (qi < counts[b * 4]) {                  // nfg: real fg rows only
        const size_t rowoff = ((size_t)b * N + qi) * CH + lane * 4;
        float s0 = 0.f, s1 = 0.f, s2 = 0.f, s3 = 0.f;
        #pragma unroll
        for (int sk = 0; sk < SPLITK; sk++) {
            ushort4 v = *(const ushort4*)(AFp + (size_t)sk * BATCH * N * CH + rowoff);
            s0 += bf2f(v.x); s1 += bf2f(v.y); s2 += bf2f(v.z); s3 += bf2f(v.w);
        }
        int q = fgi[g];
        ushort4 o = { f2bf(s0 * iq), f2bf(s1 * iq), f2bf(s2 * iq), f2bf(s3 * iq) };
        *(ushort4*)(AFt + ((size_t)b * N + q) * CH + lane * 4) = o;
    }
}

// ---------------- fused GEMM + blend (dense) + attmask epilogue ----------------
__global__ __launch_bounds__(128) void k_fused(
    const ushort* __restrict__ fwb, const ushort* __restrict__ AFt,
    const ushort* __restrict__ xT, const float* __restrict__ x,
    const float* __restrict__ m_, const float* __restrict__ vis,
    const uint* __restrict__ maxv, float* __restrict__ out,
    float* __restrict__ amask)
{
    __shared__ ushort SH[(64 + 128) * 64];
    const int b = blockIdx.z;
    const int n0 = blockIdx.x * 128, m0 = blockIdx.y * 64;
    const int lane = threadIdx.x & 63, wid = threadIdx.x >> 6;
    const int wn = (wid & 1) * 64;
    f32x4 acc[4][4]; zero_acc(acc);
    gemm_core<1, 2>(fwb, KC, m0,
                    AFt + (size_t)b * N * CH, CH, CH,
                    xT + (size_t)b * N * CH, CH,
                    n0, KC, SH, SH + 64 * 64, acc);
    const float* mb = m_ + (size_t)b * N;
    const float* xc_ = x + (size_t)b * CH * N;
    float* ob = out + (size_t)b * CH * N;
    #pragma unroll
    for (int j = 0; j < 4; j++) {
        int n = n0 + wn + j * 16 + (lane & 15);
        float mv = mb[n];
        #pragma unroll
        for (int i = 0; i < 4; i++) {
            int mbase = m0 + i * 16 + ((lane >> 4) * 4);
            #pragma unroll
            for (int r = 0; r < 4; r++) {
                int c = mbase + r;
                ob[(size_t)c * N + n] = (mv != 0.f) ? acc[i][j][r] : xc_[(size_t)c * N + n];
            }
        }
    }
    // fused attmask: each of the 512 blocks writes 2048 upsampled elements
    {
        float rcp = 1.f / __builtin_bit_cast(float, maxv[0]);
        int bid = blockIdx.x + 32 * blockIdx.y + 128 * blockIdx.z;   // 0..511
        int base = bid * 2048;
        #pragma unroll
        for (int it = 0; it < 16; it++) {
            int idx = base + it * 128 + threadIdx.x;
            int bb = idx >> 18;
            int r = idx & 262143;
            int Y = r >> 9, X = r & 511;
            amask[idx] = vis[(size_t)bb * N + (Y >> 3) * 64 + (X >> 3)] * rcp;
        }
    }
}

// ---------------- colsum (coalesced, row-major sweep) ----------------
__global__ __launch_bounds__(256) void k_colsum(
    const ushort* __restrict__ P, const float* __restrict__ inv,
    const int* __restrict__ counts, float* __restrict__ part)
{
    const int b = blockIdx.z, qc = blockIdx.y, t = threadIdx.x;
    const int nfg = counts[b * 4], nbgp = counts[b * 4 + 3];
    const int ki0 = blockIdx.x * 2048 + t * 8;
    if (ki0 >= nbgp) return;
    const int qchunk = (nfg + QCH - 1) / QCH;
    const int q0 = qc * qchunk, q1 = min(q0 + qchunk, nfg);
    const ushort* base = P + (size_t)b * PBS + (size_t)q0 * nbgp + ki0;
    const float* ib = inv + (size_t)b * N;
    float acc[8] = {};
    int q = q0;
    for (; q + 4 <= q1; q += 4) {
        uint4 v0 = *(const uint4*)(base);
        uint4 v1 = *(const uint4*)(base + (size_t)nbgp);
        uint4 v2 = *(const uint4*)(base + 2 * (size_t)nbgp);
        uint4 v3 = *(const uint4*)(base + 3 * (size_t)nbgp);
        float i0 = ib[q], i1 = ib[q + 1], i2 = ib[q + 2], i3 = ib[q + 3];
        const ushort* u0 = (const ushort*)&v0;
        const ushort* u1 = (const ushort*)&v1;
        const ushort* u2 = (const ushort*)&v2;
        const ushort* u3 = (const ushort*)&v3;
        #pragma unroll
        for (int e = 0; e < 8; e++)
            acc[e] += bf2f(u0[e]) * i0 + bf2f(u1[e]) * i1 + bf2f(u2[e]) * i2 + bf2f(u3[e]) * i3;
        base += 4 * (size_t)nbgp;
    }
    for (; q < q1; q++) {
        uint4 v = *(const uint4*)(base);
        float iq = ib[q];
        const ushort* u = (const ushort*)&v;
        #pragma unroll
        for (int e = 0; e < 8; e++) acc[e] += bf2f(u[e]) * iq;
        base += (size_t)nbgp;
    }
    float* pp = part + (size_t)qc * (BATCH * N) + (size_t)b * N + ki0;
    float4 o0 = {acc[0], acc[1], acc[2], acc[3]};
    float4 o1 = {acc[4], acc[5], acc[6], acc[7]};
    *(float4*)(pp)     = o0;
    *(float4*)(pp + 4) = o1;
}

// reduce colsum partials, scatter to vis, track global max (uint atomicMax, vis>=0)
__global__ void k_colsum_final(const float* __restrict__ part, const int* __restrict__ bgi,
                               const int* __restrict__ counts, float* __restrict__ vis,
                               uint* __restrict__ maxv)
{
    int g = blockIdx.x * 256 + threadIdx.x;
    int b = g >> 12, ki = g & 4095;
    int t = threadIdx.x;
    float s = 0.f;
    if (ki < counts[b * 4 + 2]) {
        #pragma unroll
        for (int j = 0; j < QCH; j++) s += part[(size_t)j * (BATCH * N) + g];
        vis[(size_t)b * N + bgi[(size_t)b * N + ki]] = s;
    }
    __shared__ float red[256];
    red[t] = s; __syncthreads();
    for (int st = 128; st > 0; st >>= 1) { if (t < st) red[t] = fmaxf(red[t], red[t + st]); __syncthreads(); }
    if (t == 0) atomicMax(maxv, __float_as_uint(red[0]));
}

// ---------------- launch ----------------
extern "C" void kernel_launch(void* const* d_in, const int* in_sizes, int n_in,
                              void* d_out, int out_size, void* d_ws, size_t ws_size,
                              hipStream_t stream)
{
    const float* x    = (const float*)d_in[0];
    const float* mask = (const float*)d_in[1];
    const float* dvt  = (const float*)d_in[2];
    const float* Kw   = (const float*)d_in[3];
    const float* Kb   = (const float*)d_in[4];
    const float* fw   = (const float*)d_in[5];
    float* out = (float*)d_out;

    char* ws = (char*)d_ws;
    float*  m    = (float*)(ws + OFF_M);
    float*  inv  = (float*)(ws + OFF_INV);
    float*  vis  = (float*)(ws + OFF_VIS);
    float*  maxv = (float*)(ws + OFF_MAXV);
    int*    cnt  = (int*)  (ws + OFF_CNT);
    int*    fgi  = (int*)  (ws + OFF_FGI);
    int*    bgi  = (int*)  (ws + OFF_BGI);
    int*    p2s  = (int*)  (ws + OFF_P2S);
    float*  kmc  = (float*)(ws + OFF_KMC);
    float*  part = (float*)(ws + OFF_PART);
    ushort* Kwb  = (ushort*)(ws + OFF_KWB);
    ushort* fwb  = (ushort*)(ws + OFF_FWB);
    ushort* xT   = (ushort*)(ws + OFF_XT);
    ushort* Qc   = (ushort*)(ws + OFF_QC);
    ushort* Kcc  = (ushort*)(ws + OFF_KCC);
    ushort* xc   = (ushort*)(ws + OFF_XC);
    ushort* AFt  = (ushort*)(ws + OFF_AFT);
    ushort* P    = (ushort*)(ws + OFF_P);
    ushort* AFp  = (ushort*)(ws + OFF_AFP);

    k_prep_tr    <<<dim3(1600 + 1024), 256, 0, stream>>>(
                     mask, Kw, fw, x, m, vis, (uint*)maxv, Kwb, fwb, xT);
    k_scan       <<<dim3(BATCH), 256, 0, stream>>>(m, fgi, bgi, cnt, kmc, p2s);
    k_feats_vg   <<<dim3(256 + 256), 256, 0, stream>>>(
                     Kwb, xT, dvt, Kb, p2s, bgi, cnt, Qc, Kcc, xc);
    k_score      <<<dim3(N / 64, N / 128, BATCH), 128, 0, stream>>>(Qc, Kcc, kmc, cnt, P);
    k_att_fore   <<<dim3(N / 64, 1, BATCH * SPLITK), 256, 0, stream>>>(xc, P, cnt, AFp);
    k_rowaf      <<<dim3(BATCH * N / 4), 256, 0, stream>>>(P, AFp, fgi, cnt, inv, AFt);
    k_colsum     <<<dim3(2, QCH, BATCH), 256, 0, stream>>>(P, inv, cnt, part);
    k_colsum_final<<<dim3(BATCH * N / 256), 256, 0, stream>>>(part, bgi, cnt, vis, (uint*)maxv);
    k_fused      <<<dim3(N / 128, CH / 64, BATCH), 128, 0, stream>>>(
                     fwb, AFt, xT, x, m, vis, (const uint*)maxv, out, out + (size_t)BATCH * CH * N);
}

// Round 17
// 154.718 us; speedup vs baseline: 1.4005x; 1.0118x over previous
//
#include <hip/hip_runtime.h>
#include <hip/hip_bf16.h>

typedef __attribute__((ext_vector_type(8))) short short8;
typedef __attribute__((ext_vector_type(4))) float f32x4;
typedef unsigned int uint;
typedef unsigned short ushort;

constexpr int BATCH = 4;
constexpr int CH    = 256;
constexpr int N     = 4096;   // 64*64
constexpr int DVC   = 768;
constexpr int CIN   = 1024;   // CH + DVC
constexpr int KC    = 512;    // 2*CH
constexpr int PBS   = 5 * 1024 * 1024;  // P per-batch stride (elements)
constexpr int QCH   = 32;     // colsum q-chunks
constexpr int SPLITK = 4;     // att_fore K-split

// ---------------- workspace layout (bytes) ----------------
constexpr size_t OFF_M    = 0;                       // 16384 f32
constexpr size_t OFF_INV  = 64ull << 10;             // 16384 f32
constexpr size_t OFF_VIS  = 128ull << 10;            // 16384 f32
constexpr size_t OFF_MAXV = 192ull << 10;            // 1 f32
constexpr size_t OFF_CNT  = 196ull << 10;            // 16 ints
constexpr size_t OFF_FGI  = 256ull << 10;            // 16384 int
constexpr size_t OFF_BGI  = 320ull << 10;            // 16384 int
constexpr size_t OFF_P2S  = 384ull << 10;            // 16384 int
constexpr size_t OFF_KMC  = 448ull << 10;            // 16384 f32
constexpr size_t OFF_PART = 1ull << 20;              // 4MB: rowpart [g][64] then colsum partials
constexpr size_t OFF_KWB  = 5ull << 20;              // 512KB bf16
constexpr size_t OFF_FWB  = OFF_KWB + (512ull << 10);// 256KB bf16
constexpr size_t OFF_XT   = 6ull << 20;              // [b][n][256] bf16 = 8MB
constexpr size_t OFF_QC   = 38ull << 20;             // [b][qi][256] bf16 = 8MB
constexpr size_t OFF_KCC  = 46ull << 20;             // [b][ki][256] bf16 = 8MB
constexpr size_t OFF_XC   = 54ull << 20;             // [b][c][4096] bf16 = 8MB
constexpr size_t OFF_AFT  = 62ull << 20;             // [b][n][256] bf16 = 8MB
constexpr size_t OFF_P    = 70ull << 20;             // compact P bf16, 4 x PBS = 40MB
constexpr size_t OFF_AFP  = 110ull << 20;            // bf16 partials [sk][b][qi][c] = 32MB

// ---------------- helpers ----------------
__device__ __forceinline__ ushort f2bf(float f) {
    __hip_bfloat16 h = __float2bfloat16(f);
    return __builtin_bit_cast(ushort, h);
}
__device__ __forceinline__ float bf2f(ushort u) {
    uint v = (uint)u << 16;
    return __builtin_bit_cast(float, v);
}

typedef const __attribute__((address_space(1))) uint* gptr_t;
typedef __attribute__((address_space(3))) uint* lptr_t;
__device__ __forceinline__ void gload_lds16(const void* g, void* l) {
    __builtin_amdgcn_global_load_lds((gptr_t)g, (lptr_t)l, 16, 0, 0);
}

// ---------------- shared GEMM mainloop ----------------
template<int WM, int WN>
__device__ __forceinline__ void gemm_core(
    const ushort* __restrict__ A0, int lda, int m0,
    const ushort* __restrict__ B0, int ldb0, int kend0,
    const ushort* __restrict__ B1, int ldb1,
    int n0, int K,
    ushort* AsL, ushort* BsL, f32x4 acc[4][4])
{
    constexpr int NW = WM * WN, BM = WM * 64, BN = WN * 64;
    const int t = threadIdx.x, lane = t & 63, wid = t >> 6;
    const int wm = (wid / WN) * 64, wn = (wid % WN) * 64;

    for (int k0 = 0; k0 < K; k0 += 64) {
        #pragma unroll
        for (int c = wid; c < BM / 8; c += NW) {
            const ushort* g = A0 + (size_t)(m0 + c * 8 + (lane >> 3)) * lda + (k0 + (lane & 7) * 8);
            gload_lds16(g, AsL + c * 512);
        }
        const ushort* Bsrc = (k0 < kend0) ? B0 : B1;
        const int ldb = (k0 < kend0) ? ldb0 : ldb1;
        const int kc  = (k0 < kend0) ? k0 : (k0 - kend0);
        #pragma unroll
        for (int c = wid; c < BN / 8; c += NW) {
            const ushort* g = Bsrc + (size_t)(n0 + c * 8 + (lane >> 3)) * ldb + (kc + (lane & 7) * 8);
            gload_lds16(g, BsL + c * 512);
        }
        __syncthreads();

        const int ra = wm + (lane & 15), rb = wn + (lane & 15), ko = (lane >> 4) * 8;
        #pragma unroll
        for (int kk = 0; kk < 64; kk += 32) {
            short8 a[4], b[4];
            #pragma unroll
            for (int i = 0; i < 4; i++) a[i] = *(const short8*)(AsL + (ra + i * 16) * 64 + kk + ko);
            #pragma unroll
            for (int j = 0; j < 4; j++) b[j] = *(const short8*)(BsL + (rb + j * 16) * 64 + kk + ko);
            #pragma unroll
            for (int i = 0; i < 4; i++)
                #pragma unroll
                for (int j = 0; j < 4; j++)
                    acc[i][j] = __builtin_amdgcn_mfma_f32_16x16x32_bf16(a[i], b[j], acc[i][j], 0, 0, 0);
        }
        __syncthreads();
    }
}

__device__ __forceinline__ void zero_acc(f32x4 acc[4][4]) {
    f32x4 z = {0.f, 0.f, 0.f, 0.f};
    #pragma unroll
    for (int i = 0; i < 4; i++)
        #pragma unroll
        for (int j = 0; j < 4; j++) acc[i][j] = z;
}

// ---------------- prep + x-transpose (merged, independent halves) ----------------
__global__ __launch_bounds__(256) void k_prep_tr(
    const float* __restrict__ mask, const float* __restrict__ Kw,
    const float* __restrict__ fw, const float* __restrict__ x,
    float* __restrict__ m, float* __restrict__ vis, uint* __restrict__ maxv,
    ushort* __restrict__ Kwb, ushort* __restrict__ fwb, ushort* __restrict__ xT)
{
    __shared__ float Ls[64][65];
    const int bid = blockIdx.x;
    const int t = threadIdx.x;
    if (bid < 64) {
        int idx = bid * 256 + t;
        int b = idx >> 12, p = idx & 4095;
        int y = p >> 6, xx = p & 63;
        const float* base = mask + (size_t)b * 512 * 512 + (y * 8) * 512 + xx * 8;
        float mx = 0.f;
        for (int dy = 0; dy < 8; dy++) {
            #pragma unroll
            for (int dx = 0; dx < 8; dx++) mx = fmaxf(mx, base[dy * 512 + dx]);
        }
        m[idx] = (mx > 0.f) ? 1.f : 0.f;
        vis[idx] = 0.f;
        if (idx == 0) maxv[0] = 0u;
    } else if (bid < 1600) {
        int i = (bid - 64) * 256 + t;
        if (i < CH * CIN) Kwb[i] = f2bf(Kw[i]);
        else              fwb[i - CH * CIN] = f2bf(fw[i - CH * CIN]);
    } else {
        const int tr_id = bid - 1600;               // [0,1024)
        const int ci0 = (tr_id & 3) * 64;
        const int n0 = ((tr_id >> 2) & 63) * 64;
        const int b = tr_id >> 8;
        const float* s = x + (size_t)b * CH * 4096;
        #pragma unroll
        for (int it = 0; it < 4; it++) {
            int f4 = it * 256 + t;
            int r = f4 >> 4, c4 = f4 & 15;
            float4 v = *(const float4*)(s + (size_t)(ci0 + r) * 4096 + n0 + c4 * 4);
            Ls[r][c4 * 4 + 0] = v.x; Ls[r][c4 * 4 + 1] = v.y;
            Ls[r][c4 * 4 + 2] = v.z; Ls[r][c4 * 4 + 3] = v.w;
        }
        __syncthreads();
        ushort* d = xT + (size_t)b * 4096 * CH;
        #pragma unroll
        for (int it = 0; it < 8; it++) {
            int p = it * 256 + t;
            int rn = p >> 5, cc2 = p & 31;
            uint val = (uint)f2bf(Ls[cc2 * 2][rn]) | ((uint)f2bf(Ls[cc2 * 2 + 1][rn]) << 16);
            *(uint*)(d + (size_t)(n0 + rn) * CH + ci0 + cc2 * 2) = val;
        }
    }
}

__global__ __launch_bounds__(256) void k_scan(
    const float* __restrict__ m, int* __restrict__ fgi, int* __restrict__ bgi,
    int* __restrict__ counts, float* __restrict__ kmc, int* __restrict__ p2s)
{
    const int b = blockIdx.x, t = threadIdx.x;
    const float* mb = m + (size_t)b * N;
    __shared__ int sfg[256], sbg[256];
    bool isf[16];
    int cf = 0, cb_ = 0;
    #pragma unroll
    for (int j = 0; j < 16; j++) {
        bool f = mb[t * 16 + j] != 0.f;
        isf[j] = f; cf += f ? 1 : 0; cb_ += f ? 0 : 1;
    }
    sfg[t] = cf; sbg[t] = cb_;
    __syncthreads();
    for (int off = 1; off < 256; off <<= 1) {
        int vf = (t >= off) ? sfg[t - off] : 0;
        int vb = (t >= off) ? sbg[t - off] : 0;
        __syncthreads();
        sfg[t] += vf; sbg[t] += vb;
        __syncthreads();
    }
    int basef = sfg[t] - cf, baseb = sbg[t] - cb_;
    int nfg = sfg[255], nbg = sbg[255];
    #pragma unroll
    for (int j = 0; j < 16; j++) {
        int p = t * 16 + j;
        if (isf[j]) { fgi[b * N + basef] = p; p2s[b * N + p] = basef | (1 << 30); basef++; }
        else        { bgi[b * N + baseb] = p; p2s[b * N + p] = baseb; baseb++; }
    }
    if (t == 0) {
        counts[b * 4 + 0] = nfg;
        counts[b * 4 + 1] = (nfg + 127) & ~127;
        counts[b * 4 + 2] = nbg;
        counts[b * 4 + 3] = (nbg + 127) & ~127;
    }
    for (int j = t; j < N; j += 256) kmc[b * N + j] = (j < nbg) ? 1.f : 0.f;
}

// ---------------- feats GEMM + V gather (merged, independent halves) ----------------
__global__ __launch_bounds__(256) void k_feats_vg(
    const ushort* __restrict__ Kwb, const ushort* __restrict__ xT,
    const float* __restrict__ dvt, const float* __restrict__ Kb,
    const int* __restrict__ p2s, const int* __restrict__ bgi,
    const int* __restrict__ counts,
    ushort* __restrict__ Qc, ushort* __restrict__ Kc, ushort* __restrict__ xc)
{
    __shared__ __align__(16) char smem[58624];
    const int bid = blockIdx.x;
    const int t = threadIdx.x, lane = t & 63, wid = t >> 6;

    if (bid >= 256) {
        // ---- vgather half ----
        ushort (*Xs)[264] = (ushort(*)[264])smem;
        const int vid = bid - 256;
        const int b = vid >> 6;
        const int ki0 = (vid & 63) * 64;
        const int nbg = counts[b * 4 + 2], nbgp = counts[b * 4 + 3];
        if (ki0 >= nbgp) return;
        const int j = t >> 2, part = t & 3;
        const int ki = ki0 + j;
        if (ki < nbg) {
            const ushort* src = xT + ((size_t)b * N + bgi[(size_t)b * N + ki]) * CH + part * 64;
            #pragma unroll
            for (int q = 0; q < 8; q++)
                *(uint4*)&Xs[j][part * 64 + q * 8] = *(const uint4*)(src + q * 8);
        } else {
            uint4 z = {0, 0, 0, 0};
            #pragma unroll
            for (int q = 0; q < 8; q++)
                *(uint4*)&Xs[j][part * 64 + q * 8] = z;
        }
        __syncthreads();
        const int c = t;
        ushort* dst = xc + ((size_t)b * CH + c) * N + ki0;
        uint w[32];
        #pragma unroll
        for (int jj = 0; jj < 32; jj++)
            w[jj] = (uint)Xs[2 * jj][c] | ((uint)Xs[2 * jj + 1][c] << 16);
        #pragma unroll
        for (int q = 0; q < 8; q++) {
            uint4 o = { w[q * 4], w[q * 4 + 1], w[q * 4 + 2], w[q * 4 + 3] };
            *(uint4*)(dst + q * 8) = o;
        }
        return;
    }

    // ---- feats half ----
    ushort* As = (ushort*)smem;                       // 32 KB
    ushort* Bs = (ushort*)(smem + 32768);             // 8 KB
    float (*Ls)[65] = (float(*)[65])(smem + 40960);   // 16.25 KB
    float (*red)[64] = (float(*)[64])(smem + 57600);  // 1 KB
    const int b = bid >> 6;
    const int n0 = (bid & 63) * 64;
    const ushort* xTb = xT + (size_t)b * N * CH;
    const float* dvb = dvt + (size_t)b * DVC * N;
    f32x4 acc[4][4]; zero_acc(acc);

    // phase 1: k = 0..255, B from xT (linear LDS)
    for (int k0 = 0; k0 < 256; k0 += 64) {
        #pragma unroll
        for (int c = wid; c < 32; c += 4)
            gload_lds16(Kwb + (size_t)(c * 8 + (lane >> 3)) * CIN + k0 + (lane & 7) * 8, As + c * 512);
        #pragma unroll
        for (int c = wid; c < 8; c += 4)
            gload_lds16(xTb + (size_t)(n0 + c * 8 + (lane >> 3)) * CH + k0 + (lane & 7) * 8, Bs + c * 512);
        __syncthreads();
        const int ra = wid * 64 + (lane & 15), rb = lane & 15, ko = (lane >> 4) * 8;
        #pragma unroll
        for (int kk = 0; kk < 64; kk += 32) {
            short8 a[4], bb[4];
            #pragma unroll
            for (int i = 0; i < 4; i++) a[i] = *(const short8*)(As + (ra + i * 16) * 64 + kk + ko);
            #pragma unroll
            for (int j = 0; j < 4; j++) bb[j] = *(const short8*)(Bs + (rb + j * 16) * 64 + kk + ko);
            #pragma unroll
            for (int i = 0; i < 4; i++)
                #pragma unroll
                for (int j = 0; j < 4; j++)
                    acc[i][j] = __builtin_amdgcn_mfma_f32_16x16x32_bf16(a[i], bb[j], acc[i][j], 0, 0, 0);
        }
        __syncthreads();
    }
    // phase 2: k = 256..1023, B transposed in-kernel from dvt f32, XOR-swizzled
    for (int k0 = 256; k0 < 1024; k0 += 64) {
        #pragma unroll
        for (int c = wid; c < 32; c += 4)
            gload_lds16(Kwb + (size_t)(c * 8 + (lane >> 3)) * CIN + k0 + (lane & 7) * 8, As + c * 512);
        const float* dsrc = dvb + (size_t)(k0 - 256) * N + n0;
        #pragma unroll
        for (int it = 0; it < 4; it++) {
            int f4 = it * 256 + t;
            int r = f4 >> 4, c4 = (f4 & 15) * 4;
            float4 v = *(const float4*)(dsrc + (size_t)r * N + c4);
            Ls[r][c4 + 0] = v.x; Ls[r][c4 + 1] = v.y;
            Ls[r][c4 + 2] = v.z; Ls[r][c4 + 3] = v.w;
        }
        __syncthreads();
        {
            int rn = t >> 2;            // n row 0..63
            int ks = (t & 3) * 16;      // k start
            #pragma unroll
            for (int j2 = 0; j2 < 8; j2++) {
                int kk = ks + j2 * 2;
                uint val = (uint)f2bf(Ls[kk][rn]) | ((uint)f2bf(Ls[kk + 1][rn]) << 16);
                int idx = (rn * 64 + kk) ^ ((rn & 7) << 3);
                *(uint*)(Bs + idx) = val;
            }
        }
        __syncthreads();
        const int ra = wid * 64 + (lane & 15), rb = lane & 15, ko = (lane >> 4) * 8;
        #pragma unroll
        for (int kk = 0; kk < 64; kk += 32) {
            short8 a[4], bb[4];
            #pragma unroll
            for (int i = 0; i < 4; i++) a[i] = *(const short8*)(As + (ra + i * 16) * 64 + kk + ko);
            #pragma unroll
            for (int j = 0; j < 4; j++) {
                int row = rb + j * 16;
                int idx = (row * 64 + kk + ko) ^ ((row & 7) << 3);
                bb[j] = *(const short8*)(Bs + idx);
            }
            #pragma unroll
            for (int i = 0; i < 4; i++)
                #pragma unroll
                for (int j = 0; j < 4; j++)
                    acc[i][j] = __builtin_amdgcn_mfma_f32_16x16x32_bf16(a[i], bb[j], acc[i][j], 0, 0, 0);
        }
        __syncthreads();
    }

    // epilogue: bias, per-position L2 norm (cross-wave), scatter to Qc/Kc
    const int wm = wid * 64;
    float sj[4] = {0.f, 0.f, 0.f, 0.f};
    #pragma unroll
    for (int i = 0; i < 4; i++) {
        int mbase = wm + i * 16 + ((lane >> 4) * 4);
        float4 bias = *(const float4*)(Kb + mbase);
        #pragma unroll
        for (int j = 0; j < 4; j++) {
            acc[i][j][0] += bias.x; acc[i][j][1] += bias.y;
            acc[i][j][2] += bias.z; acc[i][j][3] += bias.w;
            sj[j] += acc[i][j][0] * acc[i][j][0] + acc[i][j][1] * acc[i][j][1]
                   + acc[i][j][2] * acc[i][j][2] + acc[i][j][3] * acc[i][j][3];
        }
    }
    #pragma unroll
    for (int j = 0; j < 4; j++) {
        sj[j] += __shfl_xor(sj[j], 16);
        sj[j] += __shfl_xor(sj[j], 32);
    }
    if (lane < 16) {
        #pragma unroll
        for (int j = 0; j < 4; j++) red[wid][j * 16 + lane] = sj[j];
    }
    __syncthreads();
    const int* pb = p2s + (size_t)b * N + n0;
    #pragma unroll
    for (int j = 0; j < 4; j++) {
        int n = j * 16 + (lane & 15);
        float s = red[0][n] + red[1][n] + red[2][n] + red[3][n];
        float invn = 1.f / (sqrtf(s) + 1e-8f);
        int sl = pb[n];
        ushort* dst = (sl & (1 << 30)) ? Qc : Kc;
        int slot = sl & 0x3FFFFFFF;
        ushort* drow = dst + ((size_t)b * N + slot) * CH;
        #pragma unroll
        for (int i = 0; i < 4; i++) {
            int mbase = wm + i * 16 + ((lane >> 4) * 4);
            ushort4 o = { f2bf(acc[i][j][0] * invn), f2bf(acc[i][j][1] * invn),
                          f2bf(acc[i][j][2] * invn), f2bf(acc[i][j][3] * invn) };
            *(ushort4*)(drow + mbase) = o;
        }
    }
}

// ---------------- score GEMM (compact, 128q x 64k) + transposed row partials ----------------
__global__ __launch_bounds__(128) void k_score(
    const ushort* __restrict__ Qc, const ushort* __restrict__ Kc,
    const float* __restrict__ kmc, const int* __restrict__ counts,
    ushort* __restrict__ P, float* __restrict__ rowpart)
{
    const int b = blockIdx.z;
    const int nfgp = counts[b * 4 + 1], nbgp = counts[b * 4 + 3];
    const int m0 = blockIdx.y * 128;   // q tile
    const int n0 = blockIdx.x * 64;    // k tile
    if (m0 >= nfgp || n0 >= nbgp) return;
    __shared__ ushort SH[(128 + 64) * 64];
    const int t = threadIdx.x, lane = t & 63, wid = t >> 6;
    const ushort* Qb = Qc + (size_t)b * N * CH;
    const ushort* Kb_ = Kc + (size_t)b * N * CH;
    f32x4 acc[4][4]; zero_acc(acc);
    gemm_core<2, 1>(Qb, CH, m0, Kb_, CH, CH, Kb_, CH, n0, CH, SH, SH + 128 * 64, acc);

    const int wm = wid * 64;
    float km[4];
    #pragma unroll
    for (int j = 0; j < 4; j++) km[j] = kmc[(size_t)b * N + n0 + j * 16 + (lane & 15)];

    ushort* Cs = SH;   // 128 x 64 repack
    float sir[4][4] = {};
    #pragma unroll
    for (int i = 0; i < 4; i++) {
        int rbase = wm + i * 16 + ((lane >> 4) * 4);
        #pragma unroll
        for (int j = 0; j < 4; j++) {
            int cl = j * 16 + (lane & 15);
            #pragma unroll
            for (int r = 0; r < 4; r++) {
                float p = (km[j] != 0.f) ? __expf(20.f * acc[i][j][r] - 20.f) : 0.f;
                Cs[(rbase + r) * 64 + cl] = f2bf(p);
                sir[i][r] += p;
            }
        }
    }
    // reduce the 16 col-lanes -> per-row partial sums (deterministic, no atomics)
    #pragma unroll
    for (int i = 0; i < 4; i++)
        #pragma unroll
        for (int r = 0; r < 4; r++) {
            float s = sir[i][r];
            s += __shfl_xor(s, 1); s += __shfl_xor(s, 2);
            s += __shfl_xor(s, 4); s += __shfl_xor(s, 8);
            sir[i][r] = s;
        }
    if ((lane & 15) == 0) {
        const int sl = n0 >> 6;
        #pragma unroll
        for (int i = 0; i < 4; i++)
            #pragma unroll
            for (int r = 0; r < 4; r++) {
                int row = wm + i * 16 + ((lane >> 4) * 4) + r;
                rowpart[((size_t)b * N + m0 + row) * 64 + sl] = sir[i][r];
            }
    }
    __syncthreads();
    ushort* Pb = P + (size_t)b * PBS;
    #pragma unroll
    for (int it = 0; it < 8; it++) {
        int v8 = it * 128 + t;
        int row = v8 >> 3, c8 = (v8 & 7) * 8;
        *(uint4*)(Pb + (size_t)(m0 + row) * nbgp + n0 + c8) = *(const uint4*)(Cs + row * 64 + c8);
    }
}

// ---------------- PV GEMM (compact, BM=256, split-K bf16 partials) ----------------
__global__ __launch_bounds__(256) void k_att_fore(
    const ushort* __restrict__ xc, const ushort* __restrict__ P,
    const int* __restrict__ counts, ushort* __restrict__ AFp)
{
    const int b = blockIdx.z & (BATCH - 1);
    const int sk = blockIdx.z / BATCH;
    const int nfgp = counts[b * 4 + 1], nbgp = counts[b * 4 + 3];
    const int n0 = blockIdx.x * 64;    // qi tile
    if (n0 >= nfgp) return;
    const int kchunk = ((nbgp / 64 + SPLITK - 1) / SPLITK) * 64;
    const int k0s = sk * kchunk;
    const int len = min(kchunk, nbgp - k0s);

    const int lane = threadIdx.x & 63, wid = threadIdx.x >> 6;
    f32x4 acc[4][4]; zero_acc(acc);
    if (len > 0) {
        __shared__ ushort SH[(256 + 64) * 64];
        const ushort* Pb = P + (size_t)b * PBS + k0s;
        gemm_core<4, 1>(xc + (size_t)b * CH * N + k0s, N, 0,
                        Pb, nbgp, 1 << 30, Pb, nbgp,
                        n0, len, SH, SH + 256 * 64, acc);
    }
    ushort* Ap = AFp + ((size_t)(sk * BATCH + b) * N) * CH;
    const int wm = wid * 64;
    #pragma unroll
    for (int j = 0; j < 4; j++) {
        int qi = n0 + j * 16 + (lane & 15);
        #pragma unroll
        for (int i = 0; i < 4; i++) {
            int mbase = wm + i * 16 + ((lane >> 4) * 4);
            ushort4 o = { f2bf(acc[i][j][0]), f2bf(acc[i][j][1]),
                          f2bf(acc[i][j][2]), f2bf(acc[i][j][3]) };
            *(ushort4*)(Ap + (size_t)qi * CH + mbase) = o;
        }
    }
}

// ---------------- fused rowsum (from transposed partials) + AF reduce: wave per (b,qi) ----------------
__global__ __launch_bounds__(256) void k_rowaf(
    const float* __restrict__ rowpart, const ushort* __restrict__ AFp,
    const int* __restrict__ fgi, const int* __restrict__ counts,
    float* __restrict__ inv, ushort* __restrict__ AFt)
{
    const int t = threadIdx.x, lane = t & 63, wid = t >> 6;
    const int g = blockIdx.x * 4 + wid;       // b*N + qi
    const int b = g >> 12, qi = g & 4095;
    const int nfgp = counts[b * 4 + 1], nbgp = counts[b * 4 + 3];
    if (qi >= nfgp) return;
    const int nsl = nbgp >> 6;
    float s = (lane < nsl) ? rowpart[(size_t)g * 64 + lane] : 0.f;
    #pragma unroll
    for (int mm = 1; mm < 64; mm <<= 1) s += __shfl_xor(s, mm);
    float iq = (s > 0.f) ? 1.f / s : 0.f;
    if (lane == 0) inv[g] = iq;
    if (qi < counts[b * 4]) {                  // nfg: real fg rows only
        const size_t rowoff = ((size_t)b * N + qi) * CH + lane * 4;
        float s0 = 0.f, s1 = 0.f, s2 = 0.f, s3 = 0.f;
        #pragma unroll
        for (int sk = 0; sk < SPLITK; sk++) {
            ushort4 v = *(const ushort4*)(AFp + (size_t)sk * BATCH * N * CH + rowoff);
            s0 += bf2f(v.x); s1 += bf2f(v.y); s2 += bf2f(v.z); s3 += bf2f(v.w);
        }
        int q = fgi[g];
        ushort4 o = { f2bf(s0 * iq), f2bf(s1 * iq), f2bf(s2 * iq), f2bf(s3 * iq) };
        *(ushort4*)(AFt + ((size_t)b * N + q) * CH + lane * 4) = o;
    }
}

// ---------------- fused GEMM + blend (dense) + attmask epilogue ----------------
__global__ __launch_bounds__(128) void k_fused(
    const ushort* __restrict__ fwb, const ushort* __restrict__ AFt,
    const ushort* __restrict__ xT, const float* __restrict__ x,
    const float* __restrict__ m_, const float* __restrict__ vis,
    const uint* __restrict__ maxv, float* __restrict__ out,
    float* __restrict__ amask)
{
    __shared__ ushort SH[(64 + 128) * 64];
    const int b = blockIdx.z;
    const int n0 = blockIdx.x * 128, m0 = blockIdx.y * 64;
    const int lane = threadIdx.x & 63, wid = threadIdx.x >> 6;
    const int wn = (wid & 1) * 64;
    f32x4 acc[4][4]; zero_acc(acc);
    gemm_core<1, 2>(fwb, KC, m0,
                    AFt + (size_t)b * N * CH, CH, CH,
                    xT + (size_t)b * N * CH, CH,
                    n0, KC, SH, SH + 64 * 64, acc);
    const float* mb = m_ + (size_t)b * N;
    const float* xc_ = x + (size_t)b * CH * N;
    float* ob = out + (size_t)b * CH * N;
    #pragma unroll
    for (int j = 0; j < 4; j++) {
        int n = n0 + wn + j * 16 + (lane & 15);
        float mv = mb[n];
        #pragma unroll
        for (int i = 0; i < 4; i++) {
            int mbase = m0 + i * 16 + ((lane >> 4) * 4);
            #pragma unroll
            for (int r = 0; r < 4; r++) {
                int c = mbase + r;
                ob[(size_t)c * N + n] = (mv != 0.f) ? acc[i][j][r] : xc_[(size_t)c * N + n];
            }
        }
    }
    // fused attmask: each of the 512 blocks writes 2048 upsampled elements
    {
        float rcp = 1.f / __builtin_bit_cast(float, maxv[0]);
        int bid = blockIdx.x + 32 * blockIdx.y + 128 * blockIdx.z;   // 0..511
        int base = bid * 2048;
        #pragma unroll
        for (int it = 0; it < 16; it++) {
            int idx = base + it * 128 + threadIdx.x;
            int bb = idx >> 18;
            int r = idx & 262143;
            int Y = r >> 9, X = r & 511;
            amask[idx] = vis[(size_t)bb * N + (Y >> 3) * 64 + (X >> 3)] * rcp;
        }
    }
}

// ---------------- colsum (coalesced, row-major sweep) ----------------
__global__ __launch_bounds__(256) void k_colsum(
    const ushort* __restrict__ P, const float* __restrict__ inv,
    const int* __restrict__ counts, float* __restrict__ part)
{
    const int b = blockIdx.z, qc = blockIdx.y, t = threadIdx.x;
    const int nfg = counts[b * 4], nbgp = counts[b * 4 + 3];
    const int ki0 = blockIdx.x * 2048 + t * 8;
    if (ki0 >= nbgp) return;
    const int qchunk = (nfg + QCH - 1) / QCH;
    const int q0 = qc * qchunk, q1 = min(q0 + qchunk, nfg);
    const ushort* base = P + (size_t)b * PBS + (size_t)q0 * nbgp + ki0;
    const float* ib = inv + (size_t)b * N;
    float acc[8] = {};
    int q = q0;
    for (; q + 4 <= q1; q += 4) {
        uint4 v0 = *(const uint4*)(base);
        uint4 v1 = *(const uint4*)(base + (size_t)nbgp);
        uint4 v2 = *(const uint4*)(base + 2 * (size_t)nbgp);
        uint4 v3 = *(const uint4*)(base + 3 * (size_t)nbgp);
        float i0 = ib[q], i1 = ib[q + 1], i2 = ib[q + 2], i3 = ib[q + 3];
        const ushort* u0 = (const ushort*)&v0;
        const ushort* u1 = (const ushort*)&v1;
        const ushort* u2 = (const ushort*)&v2;
        const ushort* u3 = (const ushort*)&v3;
        #pragma unroll
        for (int e = 0; e < 8; e++)
            acc[e] += bf2f(u0[e]) * i0 + bf2f(u1[e]) * i1 + bf2f(u2[e]) * i2 + bf2f(u3[e]) * i3;
        base += 4 * (size_t)nbgp;
    }
    for (; q < q1; q++) {
        uint4 v = *(const uint4*)(base);
        float iq = ib[q];
        const ushort* u = (const ushort*)&v;
        #pragma unroll
        for (int e = 0; e < 8; e++) acc[e] += bf2f(u[e]) * iq;
        base += (size_t)nbgp;
    }
    float* pp = part + (size_t)qc * (BATCH * N) + (size_t)b * N + ki0;
    float4 o0 = {acc[0], acc[1], acc[2], acc[3]};
    float4 o1 = {acc[4], acc[5], acc[6], acc[7]};
    *(float4*)(pp)     = o0;
    *(float4*)(pp + 4) = o1;
}

// reduce colsum partials, scatter to vis, track global max (uint atomicMax, vis>=0)
__global__ void k_colsum_final(const float* __restrict__ part, const int* __restrict__ bgi,
                               const int* __restrict__ counts, float* __restrict__ vis,
                               uint* __restrict__ maxv)
{
    int g = blockIdx.x * 256 + threadIdx.x;
    int b = g >> 12, ki = g & 4095;
    int t = threadIdx.x;
    float s = 0.f;
    if (ki < counts[b * 4 + 2]) {
        #pragma unroll
        for (int j = 0; j < QCH; j++) s += part[(size_t)j * (BATCH * N) + g];
        vis[(size_t)b * N + bgi[(size_t)b * N + ki]] = s;
    }
    __shared__ float red[256];
    red[t] = s; __syncthreads();
    for (int st = 128; st > 0; st >>= 1) { if (t < st) red[t] = fmaxf(red[t], red[t + st]); __syncthreads(); }
    if (t == 0) atomicMax(maxv, __float_as_uint(red[0]));
}

// ---------------- launch ----------------
extern "C" void kernel_launch(void* const* d_in, const int* in_sizes, int n_in,
                              void* d_out, int out_size, void* d_ws, size_t ws_size,
                              hipStream_t stream)
{
    const float* x    = (const float*)d_in[0];
    const float* mask = (const float*)d_in[1];
    const float* dvt  = (const float*)d_in[2];
    const float* Kw   = (const float*)d_in[3];
    const float* Kb   = (const float*)d_in[4];
    const float* fw   = (const float*)d_in[5];
    float* out = (float*)d_out;

    char* ws = (char*)d_ws;
    float*  m    = (float*)(ws + OFF_M);
    float*  inv  = (float*)(ws + OFF_INV);
    float*  vis  = (float*)(ws + OFF_VIS);
    float*  maxv = (float*)(ws + OFF_MAXV);
    int*    cnt  = (int*)  (ws + OFF_CNT);
    int*    fgi  = (int*)  (ws + OFF_FGI);
    int*    bgi  = (int*)  (ws + OFF_BGI);
    int*    p2s  = (int*)  (ws + OFF_P2S);
    float*  kmc  = (float*)(ws + OFF_KMC);
    float*  part = (float*)(ws + OFF_PART);   // rowpart [g][64] first, colsum partials later
    ushort* Kwb  = (ushort*)(ws + OFF_KWB);
    ushort* fwb  = (ushort*)(ws + OFF_FWB);
    ushort* xT   = (ushort*)(ws + OFF_XT);
    ushort* Qc   = (ushort*)(ws + OFF_QC);
    ushort* Kcc  = (ushort*)(ws + OFF_KCC);
    ushort* xc   = (ushort*)(ws + OFF_XC);
    ushort* AFt  = (ushort*)(ws + OFF_AFT);
    ushort* P    = (ushort*)(ws + OFF_P);
    ushort* AFp  = (ushort*)(ws + OFF_AFP);

    k_prep_tr    <<<dim3(1600 + 1024), 256, 0, stream>>>(
                     mask, Kw, fw, x, m, vis, (uint*)maxv, Kwb, fwb, xT);
    k_scan       <<<dim3(BATCH), 256, 0, stream>>>(m, fgi, bgi, cnt, kmc, p2s);
    k_feats_vg   <<<dim3(256 + 256), 256, 0, stream>>>(
                     Kwb, xT, dvt, Kb, p2s, bgi, cnt, Qc, Kcc, xc);
    k_score      <<<dim3(N / 64, N / 128, BATCH), 128, 0, stream>>>(Qc, Kcc, kmc, cnt, P, part);
    k_att_fore   <<<dim3(N / 64, 1, BATCH * SPLITK), 256, 0, stream>>>(xc, P, cnt, AFp);
    k_rowaf      <<<dim3(BATCH * N / 4), 256, 0, stream>>>(part, AFp, fgi, cnt, inv, AFt);
    k_colsum     <<<dim3(2, QCH, BATCH), 256, 0, stream>>>(P, inv, cnt, part);
    k_colsum_final<<<dim3(BATCH * N / 256), 256, 0, stream>>>(part, bgi, cnt, vis, (uint*)maxv);
    k_fused      <<<dim3(N / 128, CH / 64, BATCH), 128, 0, stream>>>(
                     fwb, AFt, xT, x, m, vis, (const uint*)maxv, out, out + (size_t)BATCH * CH * N);
}

// Round 18
// 148.351 us; speedup vs baseline: 1.4606x; 1.0429x over previous
//
#include <hip/hip_runtime.h>
#include <hip/hip_bf16.h>

typedef __attribute__((ext_vector_type(8))) short short8;
typedef __attribute__((ext_vector_type(4))) float f32x4;
typedef unsigned int uint;
typedef unsigned short ushort;

constexpr int BATCH = 4;
constexpr int CH    = 256;
constexpr int N     = 4096;   // 64*64
constexpr int DVC   = 768;
constexpr int CIN   = 1024;   // CH + DVC
constexpr int KC    = 512;    // 2*CH
constexpr int PBS   = 5 * 1024 * 1024;  // P per-batch stride (elements)
constexpr int QCH   = 32;     // colsum q-chunks
constexpr int SPLITK = 4;     // att_fore K-split

// ---------------- workspace layout (bytes) ----------------
constexpr size_t OFF_M    = 0;                       // 16384 f32
constexpr size_t OFF_INV  = 64ull << 10;             // 16384 f32
constexpr size_t OFF_VIS  = 128ull << 10;            // 16384 f32
constexpr size_t OFF_MAXV = 192ull << 10;            // 1 f32
constexpr size_t OFF_CNT  = 196ull << 10;            // 16 ints
constexpr size_t OFF_FGI  = 256ull << 10;            // 16384 int
constexpr size_t OFF_BGI  = 320ull << 10;            // 16384 int
constexpr size_t OFF_P2S  = 384ull << 10;            // 16384 int
constexpr size_t OFF_KMC  = 448ull << 10;            // 16384 f32
constexpr size_t OFF_PART = 1ull << 20;              // 4MB: rowpart [g][64] then colsum partials
constexpr size_t OFF_KWB  = 5ull << 20;              // 512KB bf16
constexpr size_t OFF_FWB  = OFF_KWB + (512ull << 10);// 256KB bf16
constexpr size_t OFF_XT   = 6ull << 20;              // [b][n][256] bf16 = 8MB
constexpr size_t OFF_QC   = 38ull << 20;             // [b][qi][256] bf16 = 8MB
constexpr size_t OFF_KCC  = 46ull << 20;             // [b][ki][256] bf16 = 8MB
constexpr size_t OFF_XC   = 54ull << 20;             // [b][c][4096] bf16 = 8MB
constexpr size_t OFF_AFT  = 62ull << 20;             // [b][n][256] bf16 = 8MB
constexpr size_t OFF_P    = 70ull << 20;             // compact P bf16, 4 x PBS = 40MB
constexpr size_t OFF_AFP  = 110ull << 20;            // bf16 partials [sk][b][qi][c] = 32MB

// ---------------- helpers ----------------
__device__ __forceinline__ ushort f2bf(float f) {
    __hip_bfloat16 h = __float2bfloat16(f);
    return __builtin_bit_cast(ushort, h);
}
__device__ __forceinline__ float bf2f(ushort u) {
    uint v = (uint)u << 16;
    return __builtin_bit_cast(float, v);
}

typedef const __attribute__((address_space(1))) uint* gptr_t;
typedef __attribute__((address_space(3))) uint* lptr_t;
__device__ __forceinline__ void gload_lds16(const void* g, void* l) {
    __builtin_amdgcn_global_load_lds((gptr_t)g, (lptr_t)l, 16, 0, 0);
}

// ---------------- shared GEMM mainloop ----------------
template<int WM, int WN>
__device__ __forceinline__ void gemm_core(
    const ushort* __restrict__ A0, int lda, int m0,
    const ushort* __restrict__ B0, int ldb0, int kend0,
    const ushort* __restrict__ B1, int ldb1,
    int n0, int K,
    ushort* AsL, ushort* BsL, f32x4 acc[4][4])
{
    constexpr int NW = WM * WN, BM = WM * 64, BN = WN * 64;
    const int t = threadIdx.x, lane = t & 63, wid = t >> 6;
    const int wm = (wid / WN) * 64, wn = (wid % WN) * 64;

    for (int k0 = 0; k0 < K; k0 += 64) {
        #pragma unroll
        for (int c = wid; c < BM / 8; c += NW) {
            const ushort* g = A0 + (size_t)(m0 + c * 8 + (lane >> 3)) * lda + (k0 + (lane & 7) * 8);
            gload_lds16(g, AsL + c * 512);
        }
        const ushort* Bsrc = (k0 < kend0) ? B0 : B1;
        const int ldb = (k0 < kend0) ? ldb0 : ldb1;
        const int kc  = (k0 < kend0) ? k0 : (k0 - kend0);
        #pragma unroll
        for (int c = wid; c < BN / 8; c += NW) {
            const ushort* g = Bsrc + (size_t)(n0 + c * 8 + (lane >> 3)) * ldb + (kc + (lane & 7) * 8);
            gload_lds16(g, BsL + c * 512);
        }
        __syncthreads();

        const int ra = wm + (lane & 15), rb = wn + (lane & 15), ko = (lane >> 4) * 8;
        #pragma unroll
        for (int kk = 0; kk < 64; kk += 32) {
            short8 a[4], b[4];
            #pragma unroll
            for (int i = 0; i < 4; i++) a[i] = *(const short8*)(AsL + (ra + i * 16) * 64 + kk + ko);
            #pragma unroll
            for (int j = 0; j < 4; j++) b[j] = *(const short8*)(BsL + (rb + j * 16) * 64 + kk + ko);
            #pragma unroll
            for (int i = 0; i < 4; i++)
                #pragma unroll
                for (int j = 0; j < 4; j++)
                    acc[i][j] = __builtin_amdgcn_mfma_f32_16x16x32_bf16(a[i], b[j], acc[i][j], 0, 0, 0);
        }
        __syncthreads();
    }
}

__device__ __forceinline__ void zero_acc(f32x4 acc[4][4]) {
    f32x4 z = {0.f, 0.f, 0.f, 0.f};
    #pragma unroll
    for (int i = 0; i < 4; i++)
        #pragma unroll
        for (int j = 0; j < 4; j++) acc[i][j] = z;
}

// ---------------- prep + x-transpose (merged, independent halves) ----------------
__global__ __launch_bounds__(256) void k_prep_tr(
    const float* __restrict__ mask, const float* __restrict__ Kw,
    const float* __restrict__ fw, const float* __restrict__ x,
    float* __restrict__ m, float* __restrict__ vis, uint* __restrict__ maxv,
    ushort* __restrict__ Kwb, ushort* __restrict__ fwb, ushort* __restrict__ xT)
{
    __shared__ float Ls[64][65];
    const int bid = blockIdx.x;
    const int t = threadIdx.x;
    if (bid < 64) {
        int idx = bid * 256 + t;
        int b = idx >> 12, p = idx & 4095;
        int y = p >> 6, xx = p & 63;
        const float* base = mask + (size_t)b * 512 * 512 + (y * 8) * 512 + xx * 8;
        float mx = 0.f;
        for (int dy = 0; dy < 8; dy++) {
            #pragma unroll
            for (int dx = 0; dx < 8; dx++) mx = fmaxf(mx, base[dy * 512 + dx]);
        }
        m[idx] = (mx > 0.f) ? 1.f : 0.f;
        vis[idx] = 0.f;
        if (idx == 0) maxv[0] = 0u;
    } else if (bid < 1600) {
        int i = (bid - 64) * 256 + t;
        if (i < CH * CIN) Kwb[i] = f2bf(Kw[i]);
        else              fwb[i - CH * CIN] = f2bf(fw[i - CH * CIN]);
    } else {
        const int tr_id = bid - 1600;               // [0,1024)
        const int ci0 = (tr_id & 3) * 64;
        const int n0 = ((tr_id >> 2) & 63) * 64;
        const int b = tr_id >> 8;
        const float* s = x + (size_t)b * CH * 4096;
        #pragma unroll
        for (int it = 0; it < 4; it++) {
            int f4 = it * 256 + t;
            int r = f4 >> 4, c4 = f4 & 15;
            float4 v = *(const float4*)(s + (size_t)(ci0 + r) * 4096 + n0 + c4 * 4);
            Ls[r][c4 * 4 + 0] = v.x; Ls[r][c4 * 4 + 1] = v.y;
            Ls[r][c4 * 4 + 2] = v.z; Ls[r][c4 * 4 + 3] = v.w;
        }
        __syncthreads();
        ushort* d = xT + (size_t)b * 4096 * CH;
        #pragma unroll
        for (int it = 0; it < 8; it++) {
            int p = it * 256 + t;
            int rn = p >> 5, cc2 = p & 31;
            uint val = (uint)f2bf(Ls[cc2 * 2][rn]) | ((uint)f2bf(Ls[cc2 * 2 + 1][rn]) << 16);
            *(uint*)(d + (size_t)(n0 + rn) * CH + ci0 + cc2 * 2) = val;
        }
    }
}

__global__ __launch_bounds__(256) void k_scan(
    const float* __restrict__ m, int* __restrict__ fgi, int* __restrict__ bgi,
    int* __restrict__ counts, float* __restrict__ kmc, int* __restrict__ p2s)
{
    const int b = blockIdx.x, t = threadIdx.x;
    const float* mb = m + (size_t)b * N;
    __shared__ int sfg[256], sbg[256];
    bool isf[16];
    int cf = 0, cb_ = 0;
    #pragma unroll
    for (int j = 0; j < 16; j++) {
        bool f = mb[t * 16 + j] != 0.f;
        isf[j] = f; cf += f ? 1 : 0; cb_ += f ? 0 : 1;
    }
    sfg[t] = cf; sbg[t] = cb_;
    __syncthreads();
    for (int off = 1; off < 256; off <<= 1) {
        int vf = (t >= off) ? sfg[t - off] : 0;
        int vb = (t >= off) ? sbg[t - off] : 0;
        __syncthreads();
        sfg[t] += vf; sbg[t] += vb;
        __syncthreads();
    }
    int basef = sfg[t] - cf, baseb = sbg[t] - cb_;
    int nfg = sfg[255], nbg = sbg[255];
    #pragma unroll
    for (int j = 0; j < 16; j++) {
        int p = t * 16 + j;
        if (isf[j]) { fgi[b * N + basef] = p; p2s[b * N + p] = basef | (1 << 30); basef++; }
        else        { bgi[b * N + baseb] = p; p2s[b * N + p] = baseb; baseb++; }
    }
    if (t == 0) {
        counts[b * 4 + 0] = nfg;
        counts[b * 4 + 1] = (nfg + 127) & ~127;
        counts[b * 4 + 2] = nbg;
        counts[b * 4 + 3] = (nbg + 127) & ~127;
    }
    for (int j = t; j < N; j += 256) kmc[b * N + j] = (j < nbg) ? 1.f : 0.f;
}

// ---------------- feats GEMM + V gather (merged, independent halves) ----------------
__global__ __launch_bounds__(256) void k_feats_vg(
    const ushort* __restrict__ Kwb, const ushort* __restrict__ xT,
    const float* __restrict__ dvt, const float* __restrict__ Kb,
    const int* __restrict__ p2s, const int* __restrict__ bgi,
    const int* __restrict__ counts,
    ushort* __restrict__ Qc, ushort* __restrict__ Kc, ushort* __restrict__ xc)
{
    __shared__ __align__(16) char smem[58624];
    const int bid = blockIdx.x;
    const int t = threadIdx.x, lane = t & 63, wid = t >> 6;

    if (bid >= 256) {
        // ---- vgather half ----
        ushort (*Xs)[264] = (ushort(*)[264])smem;
        const int vid = bid - 256;
        const int b = vid >> 6;
        const int ki0 = (vid & 63) * 64;
        const int nbg = counts[b * 4 + 2], nbgp = counts[b * 4 + 3];
        if (ki0 >= nbgp) return;
        const int j = t >> 2, part = t & 3;
        const int ki = ki0 + j;
        if (ki < nbg) {
            const ushort* src = xT + ((size_t)b * N + bgi[(size_t)b * N + ki]) * CH + part * 64;
            #pragma unroll
            for (int q = 0; q < 8; q++)
                *(uint4*)&Xs[j][part * 64 + q * 8] = *(const uint4*)(src + q * 8);
        } else {
            uint4 z = {0, 0, 0, 0};
            #pragma unroll
            for (int q = 0; q < 8; q++)
                *(uint4*)&Xs[j][part * 64 + q * 8] = z;
        }
        __syncthreads();
        const int c = t;
        ushort* dst = xc + ((size_t)b * CH + c) * N + ki0;
        uint w[32];
        #pragma unroll
        for (int jj = 0; jj < 32; jj++)
            w[jj] = (uint)Xs[2 * jj][c] | ((uint)Xs[2 * jj + 1][c] << 16);
        #pragma unroll
        for (int q = 0; q < 8; q++) {
            uint4 o = { w[q * 4], w[q * 4 + 1], w[q * 4 + 2], w[q * 4 + 3] };
            *(uint4*)(dst + q * 8) = o;
        }
        return;
    }

    // ---- feats half ----
    ushort* As = (ushort*)smem;                       // 32 KB
    ushort* Bs = (ushort*)(smem + 32768);             // 8 KB
    float (*Ls)[65] = (float(*)[65])(smem + 40960);   // 16.25 KB
    float (*red)[64] = (float(*)[64])(smem + 57600);  // 1 KB
    const int b = bid >> 6;
    const int n0 = (bid & 63) * 64;
    const ushort* xTb = xT + (size_t)b * N * CH;
    const float* dvb = dvt + (size_t)b * DVC * N;
    f32x4 acc[4][4]; zero_acc(acc);

    // phase 1: k = 0..255, B from xT (linear LDS)
    for (int k0 = 0; k0 < 256; k0 += 64) {
        #pragma unroll
        for (int c = wid; c < 32; c += 4)
            gload_lds16(Kwb + (size_t)(c * 8 + (lane >> 3)) * CIN + k0 + (lane & 7) * 8, As + c * 512);
        #pragma unroll
        for (int c = wid; c < 8; c += 4)
            gload_lds16(xTb + (size_t)(n0 + c * 8 + (lane >> 3)) * CH + k0 + (lane & 7) * 8, Bs + c * 512);
        __syncthreads();
        const int ra = wid * 64 + (lane & 15), rb = lane & 15, ko = (lane >> 4) * 8;
        #pragma unroll
        for (int kk = 0; kk < 64; kk += 32) {
            short8 a[4], bb[4];
            #pragma unroll
            for (int i = 0; i < 4; i++) a[i] = *(const short8*)(As + (ra + i * 16) * 64 + kk + ko);
            #pragma unroll
            for (int j = 0; j < 4; j++) bb[j] = *(const short8*)(Bs + (rb + j * 16) * 64 + kk + ko);
            #pragma unroll
            for (int i = 0; i < 4; i++)
                #pragma unroll
                for (int j = 0; j < 4; j++)
                    acc[i][j] = __builtin_amdgcn_mfma_f32_16x16x32_bf16(a[i], bb[j], acc[i][j], 0, 0, 0);
        }
        __syncthreads();
    }
    // phase 2: k = 256..1023, B transposed in-kernel from dvt f32, XOR-swizzled
    for (int k0 = 256; k0 < 1024; k0 += 64) {
        #pragma unroll
        for (int c = wid; c < 32; c += 4)
            gload_lds16(Kwb + (size_t)(c * 8 + (lane >> 3)) * CIN + k0 + (lane & 7) * 8, As + c * 512);
        const float* dsrc = dvb + (size_t)(k0 - 256) * N + n0;
        #pragma unroll
        for (int it = 0; it < 4; it++) {
            int f4 = it * 256 + t;
            int r = f4 >> 4, c4 = (f4 & 15) * 4;
            float4 v = *(const float4*)(dsrc + (size_t)r * N + c4);
            Ls[r][c4 + 0] = v.x; Ls[r][c4 + 1] = v.y;
            Ls[r][c4 + 2] = v.z; Ls[r][c4 + 3] = v.w;
        }
        __syncthreads();
        {
            int rn = t >> 2;            // n row 0..63
            int ks = (t & 3) * 16;      // k start
            #pragma unroll
            for (int j2 = 0; j2 < 8; j2++) {
                int kk = ks + j2 * 2;
                uint val = (uint)f2bf(Ls[kk][rn]) | ((uint)f2bf(Ls[kk + 1][rn]) << 16);
                int idx = (rn * 64 + kk) ^ ((rn & 7) << 3);
                *(uint*)(Bs + idx) = val;
            }
        }
        __syncthreads();
        const int ra = wid * 64 + (lane & 15), rb = lane & 15, ko = (lane >> 4) * 8;
        #pragma unroll
        for (int kk = 0; kk < 64; kk += 32) {
            short8 a[4], bb[4];
            #pragma unroll
            for (int i = 0; i < 4; i++) a[i] = *(const short8*)(As + (ra + i * 16) * 64 + kk + ko);
            #pragma unroll
            for (int j = 0; j < 4; j++) {
                int row = rb + j * 16;
                int idx = (row * 64 + kk + ko) ^ ((row & 7) << 3);
                bb[j] = *(const short8*)(Bs + idx);
            }
            #pragma unroll
            for (int i = 0; i < 4; i++)
                #pragma unroll
                for (int j = 0; j < 4; j++)
                    acc[i][j] = __builtin_amdgcn_mfma_f32_16x16x32_bf16(a[i], bb[j], acc[i][j], 0, 0, 0);
        }
        __syncthreads();
    }

    // epilogue: bias, per-position L2 norm (cross-wave), scatter to Qc/Kc
    const int wm = wid * 64;
    float sj[4] = {0.f, 0.f, 0.f, 0.f};
    #pragma unroll
    for (int i = 0; i < 4; i++) {
        int mbase = wm + i * 16 + ((lane >> 4) * 4);
        float4 bias = *(const float4*)(Kb + mbase);
        #pragma unroll
        for (int j = 0; j < 4; j++) {
            acc[i][j][0] += bias.x; acc[i][j][1] += bias.y;
            acc[i][j][2] += bias.z; acc[i][j][3] += bias.w;
            sj[j] += acc[i][j][0] * acc[i][j][0] + acc[i][j][1] * acc[i][j][1]
                   + acc[i][j][2] * acc[i][j][2] + acc[i][j][3] * acc[i][j][3];
        }
    }
    #pragma unroll
    for (int j = 0; j < 4; j++) {
        sj[j] += __shfl_xor(sj[j], 16);
        sj[j] += __shfl_xor(sj[j], 32);
    }
    if (lane < 16) {
        #pragma unroll
        for (int j = 0; j < 4; j++) red[wid][j * 16 + lane] = sj[j];
    }
    __syncthreads();
    const int* pb = p2s + (size_t)b * N + n0;
    #pragma unroll
    for (int j = 0; j < 4; j++) {
        int n = j * 16 + (lane & 15);
        float s = red[0][n] + red[1][n] + red[2][n] + red[3][n];
        float invn = 1.f / (sqrtf(s) + 1e-8f);
        int sl = pb[n];
        ushort* dst = (sl & (1 << 30)) ? Qc : Kc;
        int slot = sl & 0x3FFFFFFF;
        ushort* drow = dst + ((size_t)b * N + slot) * CH;
        #pragma unroll
        for (int i = 0; i < 4; i++) {
            int mbase = wm + i * 16 + ((lane >> 4) * 4);
            ushort4 o = { f2bf(acc[i][j][0] * invn), f2bf(acc[i][j][1] * invn),
                          f2bf(acc[i][j][2] * invn), f2bf(acc[i][j][3] * invn) };
            *(ushort4*)(drow + mbase) = o;
        }
    }
}

// ---------------- score GEMM (compact, 128q x 64k) + transposed row partials ----------------
__global__ __launch_bounds__(128) void k_score(
    const ushort* __restrict__ Qc, const ushort* __restrict__ Kc,
    const float* __restrict__ kmc, const int* __restrict__ counts,
    ushort* __restrict__ P, float* __restrict__ rowpart)
{
    const int b = blockIdx.z;
    const int nfgp = counts[b * 4 + 1], nbgp = counts[b * 4 + 3];
    const int m0 = blockIdx.y * 128;   // q tile
    const int n0 = blockIdx.x * 64;    // k tile
    if (m0 >= nfgp || n0 >= nbgp) return;
    __shared__ ushort SH[(128 + 64) * 64];
    const int t = threadIdx.x, lane = t & 63, wid = t >> 6;
    const ushort* Qb = Qc + (size_t)b * N * CH;
    const ushort* Kb_ = Kc + (size_t)b * N * CH;
    f32x4 acc[4][4]; zero_acc(acc);
    gemm_core<2, 1>(Qb, CH, m0, Kb_, CH, CH, Kb_, CH, n0, CH, SH, SH + 128 * 64, acc);

    const int wm = wid * 64;
    float km[4];
    #pragma unroll
    for (int j = 0; j < 4; j++) km[j] = kmc[(size_t)b * N + n0 + j * 16 + (lane & 15)];

    ushort* Cs = SH;   // 128 x 64 repack
    float sir[4][4] = {};
    #pragma unroll
    for (int i = 0; i < 4; i++) {
        int rbase = wm + i * 16 + ((lane >> 4) * 4);
        #pragma unroll
        for (int j = 0; j < 4; j++) {
            int cl = j * 16 + (lane & 15);
            #pragma unroll
            for (int r = 0; r < 4; r++) {
                float p = (km[j] != 0.f) ? __expf(20.f * acc[i][j][r] - 20.f) : 0.f;
                Cs[(rbase + r) * 64 + cl] = f2bf(p);
                sir[i][r] += p;
            }
        }
    }
    #pragma unroll
    for (int i = 0; i < 4; i++)
        #pragma unroll
        for (int r = 0; r < 4; r++) {
            float s = sir[i][r];
            s += __shfl_xor(s, 1); s += __shfl_xor(s, 2);
            s += __shfl_xor(s, 4); s += __shfl_xor(s, 8);
            sir[i][r] = s;
        }
    if ((lane & 15) == 0) {
        const int sl = n0 >> 6;
        #pragma unroll
        for (int i = 0; i < 4; i++)
            #pragma unroll
            for (int r = 0; r < 4; r++) {
                int row = wm + i * 16 + ((lane >> 4) * 4) + r;
                rowpart[((size_t)b * N + m0 + row) * 64 + sl] = sir[i][r];
            }
    }
    __syncthreads();
    ushort* Pb = P + (size_t)b * PBS;
    #pragma unroll
    for (int it = 0; it < 8; it++) {
        int v8 = it * 128 + t;
        int row = v8 >> 3, c8 = (v8 & 7) * 8;
        *(uint4*)(Pb + (size_t)(m0 + row) * nbgp + n0 + c8) = *(const uint4*)(Cs + row * 64 + c8);
    }
}

// ---------------- rowinv: reduce transposed row partials -> inv (wave per row) ----------------
__global__ __launch_bounds__(256) void k_rowinv(
    const float* __restrict__ rowpart, const int* __restrict__ counts,
    float* __restrict__ inv)
{
    const int t = threadIdx.x, lane = t & 63, wid = t >> 6;
    const int g = blockIdx.x * 4 + wid;       // b*N + qi
    const int b = g >> 12, qi = g & 4095;
    const int nfgp = counts[b * 4 + 1], nbgp = counts[b * 4 + 3];
    if (qi >= nfgp) return;
    const int nsl = nbgp >> 6;
    float s = (lane < nsl) ? rowpart[(size_t)g * 64 + lane] : 0.f;
    #pragma unroll
    for (int mm = 1; mm < 64; mm <<= 1) s += __shfl_xor(s, mm);
    if (lane == 0) inv[g] = (s > 0.f) ? 1.f / s : 0.f;
}

// ---------------- merged: PV GEMM (1024 blocks) + colsum (256 blocks) ----------------
__global__ __launch_bounds__(256) void k_afc(
    const ushort* __restrict__ xc, const ushort* __restrict__ P,
    const float* __restrict__ inv, const int* __restrict__ counts,
    ushort* __restrict__ AFp, float* __restrict__ part)
{
    __shared__ ushort SH[(256 + 64) * 64];
    const int bid = blockIdx.x;
    const int t = threadIdx.x;

    if (bid >= 1024) {
        // ---- colsum half: part[qc][b*N+ki] = sum_{q in chunk} inv[q]*P[q][ki] ----
        const int vid = bid - 1024;           // [0,256)
        const int xb = vid & 1;
        const int qc = (vid >> 1) & 31;
        const int b = vid >> 6;
        const int nfg = counts[b * 4], nbgp = counts[b * 4 + 3];
        const int ki0 = xb * 2048 + t * 8;
        if (ki0 >= nbgp) return;
        const int qchunk = (nfg + QCH - 1) / QCH;
        const int q0 = qc * qchunk, q1 = min(q0 + qchunk, nfg);
        const ushort* base = P + (size_t)b * PBS + (size_t)q0 * nbgp + ki0;
        const float* ib = inv + (size_t)b * N;
        float acc[8] = {};
        int q = q0;
        for (; q + 4 <= q1; q += 4) {
            uint4 v0 = *(const uint4*)(base);
            uint4 v1 = *(const uint4*)(base + (size_t)nbgp);
            uint4 v2 = *(const uint4*)(base + 2 * (size_t)nbgp);
            uint4 v3 = *(const uint4*)(base + 3 * (size_t)nbgp);
            float i0 = ib[q], i1 = ib[q + 1], i2 = ib[q + 2], i3 = ib[q + 3];
            const ushort* u0 = (const ushort*)&v0;
            const ushort* u1 = (const ushort*)&v1;
            const ushort* u2 = (const ushort*)&v2;
            const ushort* u3 = (const ushort*)&v3;
            #pragma unroll
            for (int e = 0; e < 8; e++)
                acc[e] += bf2f(u0[e]) * i0 + bf2f(u1[e]) * i1 + bf2f(u2[e]) * i2 + bf2f(u3[e]) * i3;
            base += 4 * (size_t)nbgp;
        }
        for (; q < q1; q++) {
            uint4 v = *(const uint4*)(base);
            float iq = ib[q];
            const ushort* u = (const ushort*)&v;
            #pragma unroll
            for (int e = 0; e < 8; e++) acc[e] += bf2f(u[e]) * iq;
            base += (size_t)nbgp;
        }
        float* pp = part + (size_t)qc * (BATCH * N) + (size_t)b * N + ki0;
        float4 o0 = {acc[0], acc[1], acc[2], acc[3]};
        float4 o1 = {acc[4], acc[5], acc[6], acc[7]};
        *(float4*)(pp)     = o0;
        *(float4*)(pp + 4) = o1;
        return;
    }

    // ---- att_fore half ----
    const int z = bid >> 6;                   // [0,16)
    const int b = z & (BATCH - 1);
    const int sk = z / BATCH;
    const int nfgp = counts[b * 4 + 1], nbgp = counts[b * 4 + 3];
    const int n0 = (bid & 63) * 64;           // qi tile
    if (n0 >= nfgp) return;
    const int kchunk = ((nbgp / 64 + SPLITK - 1) / SPLITK) * 64;
    const int k0s = sk * kchunk;
    const int len = min(kchunk, nbgp - k0s);

    const int lane = t & 63, wid = t >> 6;
    f32x4 acc[4][4]; zero_acc(acc);
    if (len > 0) {
        const ushort* Pb = P + (size_t)b * PBS + k0s;
        gemm_core<4, 1>(xc + (size_t)b * CH * N + k0s, N, 0,
                        Pb, nbgp, 1 << 30, Pb, nbgp,
                        n0, len, SH, SH + 256 * 64, acc);
    }
    ushort* Ap = AFp + ((size_t)(sk * BATCH + b) * N) * CH;
    const int wm = wid * 64;
    #pragma unroll
    for (int j = 0; j < 4; j++) {
        int qi = n0 + j * 16 + (lane & 15);
        #pragma unroll
        for (int i = 0; i < 4; i++) {
            int mbase = wm + i * 16 + ((lane >> 4) * 4);
            ushort4 o = { f2bf(acc[i][j][0]), f2bf(acc[i][j][1]),
                          f2bf(acc[i][j][2]), f2bf(acc[i][j][3]) };
            *(ushort4*)(Ap + (size_t)qi * CH + mbase) = o;
        }
    }
}

// ---------------- merged: AF reduce (4096 blocks) + colsum final (64 blocks) ----------------
__global__ __launch_bounds__(256) void k_afc_final(
    const ushort* __restrict__ AFp, const float* __restrict__ inv,
    const float* __restrict__ part, const int* __restrict__ fgi,
    const int* __restrict__ bgi, const int* __restrict__ counts,
    ushort* __restrict__ AFt, float* __restrict__ vis, uint* __restrict__ maxv)
{
    __shared__ float red[256];
    const int bid = blockIdx.x;
    const int t = threadIdx.x;

    if (bid >= 4096) {
        // ---- colsum_final half ----
        int g = (bid - 4096) * 256 + t;
        int b = g >> 12, ki = g & 4095;
        float s = 0.f;
        if (ki < counts[b * 4 + 2]) {
            #pragma unroll
            for (int j = 0; j < QCH; j++) s += part[(size_t)j * (BATCH * N) + g];
            vis[(size_t)b * N + bgi[(size_t)b * N + ki]] = s;
        }
        red[t] = s; __syncthreads();
        for (int st = 128; st > 0; st >>= 1) { if (t < st) red[t] = fmaxf(red[t], red[t + st]); __syncthreads(); }
        if (t == 0) atomicMax(maxv, __float_as_uint(red[0]));
        return;
    }

    // ---- afreduce half ----
    const int lane = t & 63, wid = t >> 6;
    const int g = bid * 4 + wid;              // b*N + qi
    const int b = g >> 12, qi = g & 4095;
    if (qi >= counts[b * 4]) return;          // nfg
    const size_t rowoff = ((size_t)b * N + qi) * CH + lane * 4;
    float s0 = 0.f, s1 = 0.f, s2 = 0.f, s3 = 0.f;
    #pragma unroll
    for (int sk = 0; sk < SPLITK; sk++) {
        ushort4 v = *(const ushort4*)(AFp + (size_t)sk * BATCH * N * CH + rowoff);
        s0 += bf2f(v.x); s1 += bf2f(v.y); s2 += bf2f(v.z); s3 += bf2f(v.w);
    }
    float iq = inv[g];
    int q = fgi[g];
    ushort4 o = { f2bf(s0 * iq), f2bf(s1 * iq), f2bf(s2 * iq), f2bf(s3 * iq) };
    *(ushort4*)(AFt + ((size_t)b * N + q) * CH + lane * 4) = o;
}

// ---------------- fused GEMM + blend (dense) + attmask epilogue ----------------
__global__ __launch_bounds__(128) void k_fused(
    const ushort* __restrict__ fwb, const ushort* __restrict__ AFt,
    const ushort* __restrict__ xT, const float* __restrict__ x,
    const float* __restrict__ m_, const float* __restrict__ vis,
    const uint* __restrict__ maxv, float* __restrict__ out,
    float* __restrict__ amask)
{
    __shared__ ushort SH[(64 + 128) * 64];
    const int b = blockIdx.z;
    const int n0 = blockIdx.x * 128, m0 = blockIdx.y * 64;
    const int lane = threadIdx.x & 63, wid = threadIdx.x >> 6;
    const int wn = (wid & 1) * 64;
    f32x4 acc[4][4]; zero_acc(acc);
    gemm_core<1, 2>(fwb, KC, m0,
                    AFt + (size_t)b * N * CH, CH, CH,
                    xT + (size_t)b * N * CH, CH,
                    n0, KC, SH, SH + 64 * 64, acc);
    const float* mb = m_ + (size_t)b * N;
    const float* xc_ = x + (size_t)b * CH * N;
    float* ob = out + (size_t)b * CH * N;
    #pragma unroll
    for (int j = 0; j < 4; j++) {
        int n = n0 + wn + j * 16 + (lane & 15);
        float mv = mb[n];
        #pragma unroll
        for (int i = 0; i < 4; i++) {
            int mbase = m0 + i * 16 + ((lane >> 4) * 4);
            #pragma unroll
            for (int r = 0; r < 4; r++) {
                int c = mbase + r;
                ob[(size_t)c * N + n] = (mv != 0.f) ? acc[i][j][r] : xc_[(size_t)c * N + n];
            }
        }
    }
    // fused attmask: each of the 512 blocks writes 2048 upsampled elements
    {
        float rcp = 1.f / __builtin_bit_cast(float, maxv[0]);
        int bid = blockIdx.x + 32 * blockIdx.y + 128 * blockIdx.z;   // 0..511
        int base = bid * 2048;
        #pragma unroll
        for (int it = 0; it < 16; it++) {
            int idx = base + it * 128 + threadIdx.x;
            int bb = idx >> 18;
            int r = idx & 262143;
            int Y = r >> 9, X = r & 511;
            amask[idx] = vis[(size_t)bb * N + (Y >> 3) * 64 + (X >> 3)] * rcp;
        }
    }
}

// ---------------- launch ----------------
extern "C" void kernel_launch(void* const* d_in, const int* in_sizes, int n_in,
                              void* d_out, int out_size, void* d_ws, size_t ws_size,
                              hipStream_t stream)
{
    const float* x    = (const float*)d_in[0];
    const float* mask = (const float*)d_in[1];
    const float* dvt  = (const float*)d_in[2];
    const float* Kw   = (const float*)d_in[3];
    const float* Kb   = (const float*)d_in[4];
    const float* fw   = (const float*)d_in[5];
    float* out = (float*)d_out;

    char* ws = (char*)d_ws;
    float*  m    = (float*)(ws + OFF_M);
    float*  inv  = (float*)(ws + OFF_INV);
    float*  vis  = (float*)(ws + OFF_VIS);
    float*  maxv = (float*)(ws + OFF_MAXV);
    int*    cnt  = (int*)  (ws + OFF_CNT);
    int*    fgi  = (int*)  (ws + OFF_FGI);
    int*    bgi  = (int*)  (ws + OFF_BGI);
    int*    p2s  = (int*)  (ws + OFF_P2S);
    float*  kmc  = (float*)(ws + OFF_KMC);
    float*  part = (float*)(ws + OFF_PART);   // rowpart [g][64] first, colsum partials later
    ushort* Kwb  = (ushort*)(ws + OFF_KWB);
    ushort* fwb  = (ushort*)(ws + OFF_FWB);
    ushort* xT   = (ushort*)(ws + OFF_XT);
    ushort* Qc   = (ushort*)(ws + OFF_QC);
    ushort* Kcc  = (ushort*)(ws + OFF_KCC);
    ushort* xc   = (ushort*)(ws + OFF_XC);
    ushort* AFt  = (ushort*)(ws + OFF_AFT);
    ushort* P    = (ushort*)(ws + OFF_P);
    ushort* AFp  = (ushort*)(ws + OFF_AFP);

    k_prep_tr    <<<dim3(1600 + 1024), 256, 0, stream>>>(
                     mask, Kw, fw, x, m, vis, (uint*)maxv, Kwb, fwb, xT);
    k_scan       <<<dim3(BATCH), 256, 0, stream>>>(m, fgi, bgi, cnt, kmc, p2s);
    k_feats_vg   <<<dim3(256 + 256), 256, 0, stream>>>(
                     Kwb, xT, dvt, Kb, p2s, bgi, cnt, Qc, Kcc, xc);
    k_score      <<<dim3(N / 64, N / 128, BATCH), 128, 0, stream>>>(Qc, Kcc, kmc, cnt, P, part);
    k_rowinv     <<<dim3(BATCH * N / 4), 256, 0, stream>>>(part, cnt, inv);
    k_afc        <<<dim3(1024 + 256), 256, 0, stream>>>(xc, P, inv, cnt, AFp, part);
    k_afc_final  <<<dim3(4096 + 64), 256, 0, stream>>>(
                     AFp, inv, part, fgi, bgi, cnt, AFt, vis, (uint*)maxv);
    k_fused      <<<dim3(N / 128, CH / 64, BATCH), 128, 0, stream>>>(
                     fwb, AFt, xT, x, m, vis, (const uint*)maxv, out, out + (size_t)BATCH * CH * N);
}

// Round 19
// 145.772 us; speedup vs baseline: 1.4864x; 1.0177x over previous
//
#include <hip/hip_runtime.h>
#include <hip/hip_bf16.h>

typedef __attribute__((ext_vector_type(8))) short short8;
typedef __attribute__((ext_vector_type(4))) float f32x4;
typedef unsigned int uint;
typedef unsigned short ushort;

constexpr int BATCH = 4;
constexpr int CH    = 256;
constexpr int N     = 4096;   // 64*64
constexpr int DVC   = 768;
constexpr int CIN   = 1024;   // CH + DVC
constexpr int KC    = 512;    // 2*CH
constexpr int PBS   = 5 * 1024 * 1024;  // P per-batch stride (elements)
constexpr int QCH   = 32;     // colsum q-chunks
constexpr int SPLITK = 4;     // att_fore K-split

// ---------------- workspace layout (bytes) ----------------
constexpr size_t OFF_M    = 0;                       // 16384 f32
constexpr size_t OFF_INV  = 64ull << 10;             // 16384 f32
constexpr size_t OFF_VIS  = 128ull << 10;            // 16384 f32
constexpr size_t OFF_MAXV = 192ull << 10;            // 1 f32
constexpr size_t OFF_CNT  = 196ull << 10;            // 16 ints
constexpr size_t OFF_FGI  = 256ull << 10;            // 16384 int
constexpr size_t OFF_BGI  = 320ull << 10;            // 16384 int
constexpr size_t OFF_P2S  = 384ull << 10;            // 16384 int
constexpr size_t OFF_KMC  = 448ull << 10;            // 16384 f32
constexpr size_t OFF_PART = 1ull << 20;              // 4MB: rowpart [g][64] then colsum partials
constexpr size_t OFF_KWB  = 5ull << 20;              // 512KB bf16
constexpr size_t OFF_FWB  = OFF_KWB + (512ull << 10);// 256KB bf16
constexpr size_t OFF_XT   = 6ull << 20;              // [b][n][256] bf16 = 8MB
constexpr size_t OFF_QC   = 38ull << 20;             // [b][qi][256] bf16 = 8MB
constexpr size_t OFF_KCC  = 46ull << 20;             // [b][ki][256] bf16 = 8MB
constexpr size_t OFF_XC   = 54ull << 20;             // [b][c][4096] bf16 = 8MB
constexpr size_t OFF_AFT  = 62ull << 20;             // [b][n][256] bf16 = 8MB
constexpr size_t OFF_P    = 70ull << 20;             // compact P bf16, 4 x PBS = 40MB
constexpr size_t OFF_AFP  = 110ull << 20;            // bf16 partials [sk][b][qi][c] = 32MB

// ---------------- helpers ----------------
__device__ __forceinline__ ushort f2bf(float f) {
    __hip_bfloat16 h = __float2bfloat16(f);
    return __builtin_bit_cast(ushort, h);
}
__device__ __forceinline__ float bf2f(ushort u) {
    uint v = (uint)u << 16;
    return __builtin_bit_cast(float, v);
}

typedef const __attribute__((address_space(1))) uint* gptr_t;
typedef __attribute__((address_space(3))) uint* lptr_t;
__device__ __forceinline__ void gload_lds16(const void* g, void* l) {
    __builtin_amdgcn_global_load_lds((gptr_t)g, (lptr_t)l, 16, 0, 0);
}

// ---------------- shared GEMM mainloop ----------------
template<int WM, int WN>
__device__ __forceinline__ void gemm_core(
    const ushort* __restrict__ A0, int lda, int m0,
    const ushort* __restrict__ B0, int ldb0, int kend0,
    const ushort* __restrict__ B1, int ldb1,
    int n0, int K,
    ushort* AsL, ushort* BsL, f32x4 acc[4][4])
{
    constexpr int NW = WM * WN, BM = WM * 64, BN = WN * 64;
    const int t = threadIdx.x, lane = t & 63, wid = t >> 6;
    const int wm = (wid / WN) * 64, wn = (wid % WN) * 64;

    for (int k0 = 0; k0 < K; k0 += 64) {
        #pragma unroll
        for (int c = wid; c < BM / 8; c += NW) {
            const ushort* g = A0 + (size_t)(m0 + c * 8 + (lane >> 3)) * lda + (k0 + (lane & 7) * 8);
            gload_lds16(g, AsL + c * 512);
        }
        const ushort* Bsrc = (k0 < kend0) ? B0 : B1;
        const int ldb = (k0 < kend0) ? ldb0 : ldb1;
        const int kc  = (k0 < kend0) ? k0 : (k0 - kend0);
        #pragma unroll
        for (int c = wid; c < BN / 8; c += NW) {
            const ushort* g = Bsrc + (size_t)(n0 + c * 8 + (lane >> 3)) * ldb + (kc + (lane & 7) * 8);
            gload_lds16(g, BsL + c * 512);
        }
        __syncthreads();

        const int ra = wm + (lane & 15), rb = wn + (lane & 15), ko = (lane >> 4) * 8;
        #pragma unroll
        for (int kk = 0; kk < 64; kk += 32) {
            short8 a[4], b[4];
            #pragma unroll
            for (int i = 0; i < 4; i++) a[i] = *(const short8*)(AsL + (ra + i * 16) * 64 + kk + ko);
            #pragma unroll
            for (int j = 0; j < 4; j++) b[j] = *(const short8*)(BsL + (rb + j * 16) * 64 + kk + ko);
            #pragma unroll
            for (int i = 0; i < 4; i++)
                #pragma unroll
                for (int j = 0; j < 4; j++)
                    acc[i][j] = __builtin_amdgcn_mfma_f32_16x16x32_bf16(a[i], b[j], acc[i][j], 0, 0, 0);
        }
        __syncthreads();
    }
}

__device__ __forceinline__ void zero_acc(f32x4 acc[4][4]) {
    f32x4 z = {0.f, 0.f, 0.f, 0.f};
    #pragma unroll
    for (int i = 0; i < 4; i++)
        #pragma unroll
        for (int j = 0; j < 4; j++) acc[i][j] = z;
}

// ---------------- prep + x-transpose (merged, independent halves) ----------------
__global__ __launch_bounds__(256) void k_prep_tr(
    const float* __restrict__ mask, const float* __restrict__ Kw,
    const float* __restrict__ fw, const float* __restrict__ x,
    float* __restrict__ m, float* __restrict__ vis, uint* __restrict__ maxv,
    ushort* __restrict__ Kwb, ushort* __restrict__ fwb, ushort* __restrict__ xT)
{
    __shared__ float Ls[64][65];
    const int bid = blockIdx.x;
    const int t = threadIdx.x;
    if (bid < 64) {
        int idx = bid * 256 + t;
        int b = idx >> 12, p = idx & 4095;
        int y = p >> 6, xx = p & 63;
        const float* base = mask + (size_t)b * 512 * 512 + (y * 8) * 512 + xx * 8;
        float mx = 0.f;
        for (int dy = 0; dy < 8; dy++) {
            #pragma unroll
            for (int dx = 0; dx < 8; dx++) mx = fmaxf(mx, base[dy * 512 + dx]);
        }
        m[idx] = (mx > 0.f) ? 1.f : 0.f;
        vis[idx] = 0.f;
        if (idx == 0) maxv[0] = 0u;
    } else if (bid < 1600) {
        int i = (bid - 64) * 256 + t;
        if (i < CH * CIN) Kwb[i] = f2bf(Kw[i]);
        else              fwb[i - CH * CIN] = f2bf(fw[i - CH * CIN]);
    } else {
        const int tr_id = bid - 1600;               // [0,1024)
        const int ci0 = (tr_id & 3) * 64;
        const int n0 = ((tr_id >> 2) & 63) * 64;
        const int b = tr_id >> 8;
        const float* s = x + (size_t)b * CH * 4096;
        #pragma unroll
        for (int it = 0; it < 4; it++) {
            int f4 = it * 256 + t;
            int r = f4 >> 4, c4 = f4 & 15;
            float4 v = *(const float4*)(s + (size_t)(ci0 + r) * 4096 + n0 + c4 * 4);
            Ls[r][c4 * 4 + 0] = v.x; Ls[r][c4 * 4 + 1] = v.y;
            Ls[r][c4 * 4 + 2] = v.z; Ls[r][c4 * 4 + 3] = v.w;
        }
        __syncthreads();
        ushort* d = xT + (size_t)b * 4096 * CH;
        #pragma unroll
        for (int it = 0; it < 8; it++) {
            int p = it * 256 + t;
            int rn = p >> 5, cc2 = p & 31;
            uint val = (uint)f2bf(Ls[cc2 * 2][rn]) | ((uint)f2bf(Ls[cc2 * 2 + 1][rn]) << 16);
            *(uint*)(d + (size_t)(n0 + rn) * CH + ci0 + cc2 * 2) = val;
        }
    }
}

__global__ __launch_bounds__(256) void k_scan(
    const float* __restrict__ m, int* __restrict__ fgi, int* __restrict__ bgi,
    int* __restrict__ counts, float* __restrict__ kmc, int* __restrict__ p2s)
{
    const int b = blockIdx.x, t = threadIdx.x;
    const float* mb = m + (size_t)b * N;
    __shared__ int sfg[256], sbg[256];
    bool isf[16];
    int cf = 0, cb_ = 0;
    #pragma unroll
    for (int j = 0; j < 16; j++) {
        bool f = mb[t * 16 + j] != 0.f;
        isf[j] = f; cf += f ? 1 : 0; cb_ += f ? 0 : 1;
    }
    sfg[t] = cf; sbg[t] = cb_;
    __syncthreads();
    for (int off = 1; off < 256; off <<= 1) {
        int vf = (t >= off) ? sfg[t - off] : 0;
        int vb = (t >= off) ? sbg[t - off] : 0;
        __syncthreads();
        sfg[t] += vf; sbg[t] += vb;
        __syncthreads();
    }
    int basef = sfg[t] - cf, baseb = sbg[t] - cb_;
    int nfg = sfg[255], nbg = sbg[255];
    #pragma unroll
    for (int j = 0; j < 16; j++) {
        int p = t * 16 + j;
        if (isf[j]) { fgi[b * N + basef] = p; p2s[b * N + p] = basef | (1 << 30); basef++; }
        else        { bgi[b * N + baseb] = p; p2s[b * N + p] = baseb; baseb++; }
    }
    if (t == 0) {
        counts[b * 4 + 0] = nfg;
        counts[b * 4 + 1] = (nfg + 127) & ~127;
        counts[b * 4 + 2] = nbg;
        counts[b * 4 + 3] = (nbg + 127) & ~127;
    }
    for (int j = t; j < N; j += 256) kmc[b * N + j] = (j < nbg) ? 1.f : 0.f;
}

// ---------------- feats GEMM + V gather (merged, independent halves) ----------------
__global__ __launch_bounds__(256) void k_feats_vg(
    const ushort* __restrict__ Kwb, const ushort* __restrict__ xT,
    const float* __restrict__ dvt, const float* __restrict__ Kb,
    const int* __restrict__ p2s, const int* __restrict__ bgi,
    const int* __restrict__ counts,
    ushort* __restrict__ Qc, ushort* __restrict__ Kc, ushort* __restrict__ xc)
{
    __shared__ __align__(16) char smem[58624];
    const int bid = blockIdx.x;
    const int t = threadIdx.x, lane = t & 63, wid = t >> 6;

    if (bid >= 256) {
        // ---- vgather half ----
        ushort (*Xs)[264] = (ushort(*)[264])smem;
        const int vid = bid - 256;
        const int b = vid >> 6;
        const int ki0 = (vid & 63) * 64;
        const int nbg = counts[b * 4 + 2], nbgp = counts[b * 4 + 3];
        if (ki0 >= nbgp) return;
        const int j = t >> 2, part = t & 3;
        const int ki = ki0 + j;
        if (ki < nbg) {
            const ushort* src = xT + ((size_t)b * N + bgi[(size_t)b * N + ki]) * CH + part * 64;
            #pragma unroll
            for (int q = 0; q < 8; q++)
                *(uint4*)&Xs[j][part * 64 + q * 8] = *(const uint4*)(src + q * 8);
        } else {
            uint4 z = {0, 0, 0, 0};
            #pragma unroll
            for (int q = 0; q < 8; q++)
                *(uint4*)&Xs[j][part * 64 + q * 8] = z;
        }
        __syncthreads();
        const int c = t;
        ushort* dst = xc + ((size_t)b * CH + c) * N + ki0;
        uint w[32];
        #pragma unroll
        for (int jj = 0; jj < 32; jj++)
            w[jj] = (uint)Xs[2 * jj][c] | ((uint)Xs[2 * jj + 1][c] << 16);
        #pragma unroll
        for (int q = 0; q < 8; q++) {
            uint4 o = { w[q * 4], w[q * 4 + 1], w[q * 4 + 2], w[q * 4 + 3] };
            *(uint4*)(dst + q * 8) = o;
        }
        return;
    }

    // ---- feats half ----
    ushort* As = (ushort*)smem;                       // 32 KB
    ushort* Bs = (ushort*)(smem + 32768);             // 8 KB
    float (*Ls)[65] = (float(*)[65])(smem + 40960);   // 16.25 KB
    float (*red)[64] = (float(*)[64])(smem + 57600);  // 1 KB
    const int b = bid >> 6;
    const int n0 = (bid & 63) * 64;
    const ushort* xTb = xT + (size_t)b * N * CH;
    const float* dvb = dvt + (size_t)b * DVC * N;
    f32x4 acc[4][4]; zero_acc(acc);

    // phase 1: k = 0..255, B from xT (linear LDS)
    for (int k0 = 0; k0 < 256; k0 += 64) {
        #pragma unroll
        for (int c = wid; c < 32; c += 4)
            gload_lds16(Kwb + (size_t)(c * 8 + (lane >> 3)) * CIN + k0 + (lane & 7) * 8, As + c * 512);
        #pragma unroll
        for (int c = wid; c < 8; c += 4)
            gload_lds16(xTb + (size_t)(n0 + c * 8 + (lane >> 3)) * CH + k0 + (lane & 7) * 8, Bs + c * 512);
        __syncthreads();
        const int ra = wid * 64 + (lane & 15), rb = lane & 15, ko = (lane >> 4) * 8;
        #pragma unroll
        for (int kk = 0; kk < 64; kk += 32) {
            short8 a[4], bb[4];
            #pragma unroll
            for (int i = 0; i < 4; i++) a[i] = *(const short8*)(As + (ra + i * 16) * 64 + kk + ko);
            #pragma unroll
            for (int j = 0; j < 4; j++) bb[j] = *(const short8*)(Bs + (rb + j * 16) * 64 + kk + ko);
            #pragma unroll
            for (int i = 0; i < 4; i++)
                #pragma unroll
                for (int j = 0; j < 4; j++)
                    acc[i][j] = __builtin_amdgcn_mfma_f32_16x16x32_bf16(a[i], bb[j], acc[i][j], 0, 0, 0);
        }
        __syncthreads();
    }
    // phase 2: k = 256..1023, B transposed in-kernel from dvt f32 (T14 register prefetch)
    float4 pre[4];
    {
        const float* dsrc = dvb + n0;   // k0=256 -> offset 0
        #pragma unroll
        for (int it = 0; it < 4; it++) {
            int f4 = it * 256 + t;
            int r = f4 >> 4, c4 = (f4 & 15) * 4;
            pre[it] = *(const float4*)(dsrc + (size_t)r * N + c4);
        }
    }
    for (int k0 = 256; k0 < 1024; k0 += 64) {
        #pragma unroll
        for (int c = wid; c < 32; c += 4)
            gload_lds16(Kwb + (size_t)(c * 8 + (lane >> 3)) * CIN + k0 + (lane & 7) * 8, As + c * 512);
        // write current prefetched dvt tile to Ls
        #pragma unroll
        for (int it = 0; it < 4; it++) {
            int f4 = it * 256 + t;
            int r = f4 >> 4, c4 = (f4 & 15) * 4;
            float4 v = pre[it];
            Ls[r][c4 + 0] = v.x; Ls[r][c4 + 1] = v.y;
            Ls[r][c4 + 2] = v.z; Ls[r][c4 + 3] = v.w;
        }
        // issue next tile's dvt loads into registers (latency hidden under MFMA+barriers)
        if (k0 + 64 < 1024) {
            const float* dsrc = dvb + (size_t)(k0 - 256 + 64) * N + n0;
            #pragma unroll
            for (int it = 0; it < 4; it++) {
                int f4 = it * 256 + t;
                int r = f4 >> 4, c4 = (f4 & 15) * 4;
                pre[it] = *(const float4*)(dsrc + (size_t)r * N + c4);
            }
        }
        __syncthreads();
        {
            int rn = t >> 2;            // n row 0..63
            int ks = (t & 3) * 16;      // k start
            #pragma unroll
            for (int j2 = 0; j2 < 8; j2++) {
                int kk = ks + j2 * 2;
                uint val = (uint)f2bf(Ls[kk][rn]) | ((uint)f2bf(Ls[kk + 1][rn]) << 16);
                int idx = (rn * 64 + kk) ^ ((rn & 7) << 3);
                *(uint*)(Bs + idx) = val;
            }
        }
        __syncthreads();
        const int ra = wid * 64 + (lane & 15), rb = lane & 15, ko = (lane >> 4) * 8;
        #pragma unroll
        for (int kk = 0; kk < 64; kk += 32) {
            short8 a[4], bb[4];
            #pragma unroll
            for (int i = 0; i < 4; i++) a[i] = *(const short8*)(As + (ra + i * 16) * 64 + kk + ko);
            #pragma unroll
            for (int j = 0; j < 4; j++) {
                int row = rb + j * 16;
                int idx = (row * 64 + kk + ko) ^ ((row & 7) << 3);
                bb[j] = *(const short8*)(Bs + idx);
            }
            #pragma unroll
            for (int i = 0; i < 4; i++)
                #pragma unroll
                for (int j = 0; j < 4; j++)
                    acc[i][j] = __builtin_amdgcn_mfma_f32_16x16x32_bf16(a[i], bb[j], acc[i][j], 0, 0, 0);
        }
        __syncthreads();
    }

    // epilogue: bias, per-position L2 norm (cross-wave), scatter to Qc/Kc
    const int wm = wid * 64;
    float sj[4] = {0.f, 0.f, 0.f, 0.f};
    #pragma unroll
    for (int i = 0; i < 4; i++) {
        int mbase = wm + i * 16 + ((lane >> 4) * 4);
        float4 bias = *(const float4*)(Kb + mbase);
        #pragma unroll
        for (int j = 0; j < 4; j++) {
            acc[i][j][0] += bias.x; acc[i][j][1] += bias.y;
            acc[i][j][2] += bias.z; acc[i][j][3] += bias.w;
            sj[j] += acc[i][j][0] * acc[i][j][0] + acc[i][j][1] * acc[i][j][1]
                   + acc[i][j][2] * acc[i][j][2] + acc[i][j][3] * acc[i][j][3];
        }
    }
    #pragma unroll
    for (int j = 0; j < 4; j++) {
        sj[j] += __shfl_xor(sj[j], 16);
        sj[j] += __shfl_xor(sj[j], 32);
    }
    if (lane < 16) {
        #pragma unroll
        for (int j = 0; j < 4; j++) red[wid][j * 16 + lane] = sj[j];
    }
    __syncthreads();
    const int* pb = p2s + (size_t)b * N + n0;
    #pragma unroll
    for (int j = 0; j < 4; j++) {
        int n = j * 16 + (lane & 15);
        float s = red[0][n] + red[1][n] + red[2][n] + red[3][n];
        float invn = 1.f / (sqrtf(s) + 1e-8f);
        int sl = pb[n];
        ushort* dst = (sl & (1 << 30)) ? Qc : Kc;
        int slot = sl & 0x3FFFFFFF;
        ushort* drow = dst + ((size_t)b * N + slot) * CH;
        #pragma unroll
        for (int i = 0; i < 4; i++) {
            int mbase = wm + i * 16 + ((lane >> 4) * 4);
            ushort4 o = { f2bf(acc[i][j][0] * invn), f2bf(acc[i][j][1] * invn),
                          f2bf(acc[i][j][2] * invn), f2bf(acc[i][j][3] * invn) };
            *(ushort4*)(drow + mbase) = o;
        }
    }
}

// ---------------- score GEMM (compact, 128q x 64k) + transposed row partials ----------------
__global__ __launch_bounds__(128) void k_score(
    const ushort* __restrict__ Qc, const ushort* __restrict__ Kc,
    const float* __restrict__ kmc, const int* __restrict__ counts,
    ushort* __restrict__ P, float* __restrict__ rowpart)
{
    const int b = blockIdx.z;
    const int nfgp = counts[b * 4 + 1], nbgp = counts[b * 4 + 3];
    const int m0 = blockIdx.y * 128;   // q tile
    const int n0 = blockIdx.x * 64;    // k tile
    if (m0 >= nfgp || n0 >= nbgp) return;
    __shared__ ushort SH[(128 + 64) * 64];
    const int t = threadIdx.x, lane = t & 63, wid = t >> 6;
    const ushort* Qb = Qc + (size_t)b * N * CH;
    const ushort* Kb_ = Kc + (size_t)b * N * CH;
    f32x4 acc[4][4]; zero_acc(acc);
    gemm_core<2, 1>(Qb, CH, m0, Kb_, CH, CH, Kb_, CH, n0, CH, SH, SH + 128 * 64, acc);

    const int wm = wid * 64;
    float km[4];
    #pragma unroll
    for (int j = 0; j < 4; j++) km[j] = kmc[(size_t)b * N + n0 + j * 16 + (lane & 15)];

    ushort* Cs = SH;   // 128 x 64 repack
    float sir[4][4] = {};
    #pragma unroll
    for (int i = 0; i < 4; i++) {
        int rbase = wm + i * 16 + ((lane >> 4) * 4);
        #pragma unroll
        for (int j = 0; j < 4; j++) {
            int cl = j * 16 + (lane & 15);
            #pragma unroll
            for (int r = 0; r < 4; r++) {
                float p = (km[j] != 0.f) ? __expf(20.f * acc[i][j][r] - 20.f) : 0.f;
                Cs[(rbase + r) * 64 + cl] = f2bf(p);
                sir[i][r] += p;
            }
        }
    }
    #pragma unroll
    for (int i = 0; i < 4; i++)
        #pragma unroll
        for (int r = 0; r < 4; r++) {
            float s = sir[i][r];
            s += __shfl_xor(s, 1); s += __shfl_xor(s, 2);
            s += __shfl_xor(s, 4); s += __shfl_xor(s, 8);
            sir[i][r] = s;
        }
    if ((lane & 15) == 0) {
        const int sl = n0 >> 6;
        #pragma unroll
        for (int i = 0; i < 4; i++)
            #pragma unroll
            for (int r = 0; r < 4; r++) {
                int row = wm + i * 16 + ((lane >> 4) * 4) + r;
                rowpart[((size_t)b * N + m0 + row) * 64 + sl] = sir[i][r];
            }
    }
    __syncthreads();
    ushort* Pb = P + (size_t)b * PBS;
    #pragma unroll
    for (int it = 0; it < 8; it++) {
        int v8 = it * 128 + t;
        int row = v8 >> 3, c8 = (v8 & 7) * 8;
        *(uint4*)(Pb + (size_t)(m0 + row) * nbgp + n0 + c8) = *(const uint4*)(Cs + row * 64 + c8);
    }
}

// ---------------- rowinv: reduce transposed row partials -> inv (wave per row) ----------------
__global__ __launch_bounds__(256) void k_rowinv(
    const float* __restrict__ rowpart, const int* __restrict__ counts,
    float* __restrict__ inv)
{
    const int t = threadIdx.x, lane = t & 63, wid = t >> 6;
    const int g = blockIdx.x * 4 + wid;       // b*N + qi
    const int b = g >> 12, qi = g & 4095;
    const int nfgp = counts[b * 4 + 1], nbgp = counts[b * 4 + 3];
    if (qi >= nfgp) return;
    const int nsl = nbgp >> 6;
    float s = (lane < nsl) ? rowpart[(size_t)g * 64 + lane] : 0.f;
    #pragma unroll
    for (int mm = 1; mm < 64; mm <<= 1) s += __shfl_xor(s, mm);
    if (lane == 0) inv[g] = (s > 0.f) ? 1.f / s : 0.f;
}

// ---------------- merged: PV GEMM (1024 blocks) + colsum (256 blocks) ----------------
__global__ __launch_bounds__(256) void k_afc(
    const ushort* __restrict__ xc, const ushort* __restrict__ P,
    const float* __restrict__ inv, const int* __restrict__ counts,
    ushort* __restrict__ AFp, float* __restrict__ part)
{
    __shared__ ushort SH[(256 + 64) * 64];
    const int bid = blockIdx.x;
    const int t = threadIdx.x;

    if (bid >= 1024) {
        // ---- colsum half: part[qc][b*N+ki] = sum_{q in chunk} inv[q]*P[q][ki] ----
        const int vid = bid - 1024;           // [0,256)
        const int xb = vid & 1;
        const int qc = (vid >> 1) & 31;
        const int b = vid >> 6;
        const int nfg = counts[b * 4], nbgp = counts[b * 4 + 3];
        const int ki0 = xb * 2048 + t * 8;
        if (ki0 >= nbgp) return;
        const int qchunk = (nfg + QCH - 1) / QCH;
        const int q0 = qc * qchunk, q1 = min(q0 + qchunk, nfg);
        const ushort* base = P + (size_t)b * PBS + (size_t)q0 * nbgp + ki0;
        const float* ib = inv + (size_t)b * N;
        float acc[8] = {};
        int q = q0;
        for (; q + 4 <= q1; q += 4) {
            uint4 v0 = *(const uint4*)(base);
            uint4 v1 = *(const uint4*)(base + (size_t)nbgp);
            uint4 v2 = *(const uint4*)(base + 2 * (size_t)nbgp);
            uint4 v3 = *(const uint4*)(base + 3 * (size_t)nbgp);
            float i0 = ib[q], i1 = ib[q + 1], i2 = ib[q + 2], i3 = ib[q + 3];
            const ushort* u0 = (const ushort*)&v0;
            const ushort* u1 = (const ushort*)&v1;
            const ushort* u2 = (const ushort*)&v2;
            const ushort* u3 = (const ushort*)&v3;
            #pragma unroll
            for (int e = 0; e < 8; e++)
                acc[e] += bf2f(u0[e]) * i0 + bf2f(u1[e]) * i1 + bf2f(u2[e]) * i2 + bf2f(u3[e]) * i3;
            base += 4 * (size_t)nbgp;
        }
        for (; q < q1; q++) {
            uint4 v = *(const uint4*)(base);
            float iq = ib[q];
            const ushort* u = (const ushort*)&v;
            #pragma unroll
            for (int e = 0; e < 8; e++) acc[e] += bf2f(u[e]) * iq;
            base += (size_t)nbgp;
        }
        float* pp = part + (size_t)qc * (BATCH * N) + (size_t)b * N + ki0;
        float4 o0 = {acc[0], acc[1], acc[2], acc[3]};
        float4 o1 = {acc[4], acc[5], acc[6], acc[7]};
        *(float4*)(pp)     = o0;
        *(float4*)(pp + 4) = o1;
        return;
    }

    // ---- att_fore half ----
    const int z = bid >> 6;                   // [0,16)
    const int b = z & (BATCH - 1);
    const int sk = z / BATCH;
    const int nfgp = counts[b * 4 + 1], nbgp = counts[b * 4 + 3];
    const int n0 = (bid & 63) * 64;           // qi tile
    if (n0 >= nfgp) return;
    const int kchunk = ((nbgp / 64 + SPLITK - 1) / SPLITK) * 64;
    const int k0s = sk * kchunk;
    const int len = min(kchunk, nbgp - k0s);

    const int lane = t & 63, wid = t >> 6;
    f32x4 acc[4][4]; zero_acc(acc);
    if (len > 0) {
        const ushort* Pb = P + (size_t)b * PBS + k0s;
        gemm_core<4, 1>(xc + (size_t)b * CH * N + k0s, N, 0,
                        Pb, nbgp, 1 << 30, Pb, nbgp,
                        n0, len, SH, SH + 256 * 64, acc);
    }
    ushort* Ap = AFp + ((size_t)(sk * BATCH + b) * N) * CH;
    const int wm = wid * 64;
    #pragma unroll
    for (int j = 0; j < 4; j++) {
        int qi = n0 + j * 16 + (lane & 15);
        #pragma unroll
        for (int i = 0; i < 4; i++) {
            int mbase = wm + i * 16 + ((lane >> 4) * 4);
            ushort4 o = { f2bf(acc[i][j][0]), f2bf(acc[i][j][1]),
                          f2bf(acc[i][j][2]), f2bf(acc[i][j][3]) };
            *(ushort4*)(Ap + (size_t)qi * CH + mbase) = o;
        }
    }
}

// ---------------- merged: AF reduce (4096 blocks) + colsum final (64 blocks) ----------------
__global__ __launch_bounds__(256) void k_afc_final(
    const ushort* __restrict__ AFp, const float* __restrict__ inv,
    const float* __restrict__ part, const int* __restrict__ fgi,
    const int* __restrict__ bgi, const int* __restrict__ counts,
    ushort* __restrict__ AFt, float* __restrict__ vis, uint* __restrict__ maxv)
{
    __shared__ float red[256];
    const int bid = blockIdx.x;
    const int t = threadIdx.x;

    if (bid >= 4096) {
        // ---- colsum_final half ----
        int g = (bid - 4096) * 256 + t;
        int b = g >> 12, ki = g & 4095;
        float s = 0.f;
        if (ki < counts[b * 4 + 2]) {
            #pragma unroll
            for (int j = 0; j < QCH; j++) s += part[(size_t)j * (BATCH * N) + g];
            vis[(size_t)b * N + bgi[(size_t)b * N + ki]] = s;
        }
        red[t] = s; __syncthreads();
        for (int st = 128; st > 0; st >>= 1) { if (t < st) red[t] = fmaxf(red[t], red[t + st]); __syncthreads(); }
        if (t == 0) atomicMax(maxv, __float_as_uint(red[0]));
        return;
    }

    // ---- afreduce half ----
    const int lane = t & 63, wid = t >> 6;
    const int g = bid * 4 + wid;              // b*N + qi
    const int b = g >> 12, qi = g & 4095;
    if (qi >= counts[b * 4]) return;          // nfg
    const size_t rowoff = ((size_t)b * N + qi) * CH + lane * 4;
    float s0 = 0.f, s1 = 0.f, s2 = 0.f, s3 = 0.f;
    #pragma unroll
    for (int sk = 0; sk < SPLITK; sk++) {
        ushort4 v = *(const ushort4*)(AFp + (size_t)sk * BATCH * N * CH + rowoff);
        s0 += bf2f(v.x); s1 += bf2f(v.y); s2 += bf2f(v.z); s3 += bf2f(v.w);
    }
    float iq = inv[g];
    int q = fgi[g];
    ushort4 o = { f2bf(s0 * iq), f2bf(s1 * iq), f2bf(s2 * iq), f2bf(s3 * iq) };
    *(ushort4*)(AFt + ((size_t)b * N + q) * CH + lane * 4) = o;
}

// ---------------- fused GEMM + blend (dense) + attmask epilogue ----------------
__global__ __launch_bounds__(128) void k_fused(
    const ushort* __restrict__ fwb, const ushort* __restrict__ AFt,
    const ushort* __restrict__ xT, const float* __restrict__ x,
    const float* __restrict__ m_, const float* __restrict__ vis,
    const uint* __restrict__ maxv, float* __restrict__ out,
    float* __restrict__ amask)
{
    __shared__ ushort SH[(64 + 128) * 64];
    const int b = blockIdx.z;
    const int n0 = blockIdx.x * 128, m0 = blockIdx.y * 64;
    const int lane = threadIdx.x & 63, wid = threadIdx.x >> 6;
    const int wn = (wid & 1) * 64;
    f32x4 acc[4][4]; zero_acc(acc);
    gemm_core<1, 2>(fwb, KC, m0,
                    AFt + (size_t)b * N * CH, CH, CH,
                    xT + (size_t)b * N * CH, CH,
                    n0, KC, SH, SH + 64 * 64, acc);
    const float* mb = m_ + (size_t)b * N;
    const float* xc_ = x + (size_t)b * CH * N;
    float* ob = out + (size_t)b * CH * N;
    #pragma unroll
    for (int j = 0; j < 4; j++) {
        int n = n0 + wn + j * 16 + (lane & 15);
        float mv = mb[n];
        #pragma unroll
        for (int i = 0; i < 4; i++) {
            int mbase = m0 + i * 16 + ((lane >> 4) * 4);
            #pragma unroll
            for (int r = 0; r < 4; r++) {
                int c = mbase + r;
                ob[(size_t)c * N + n] = (mv != 0.f) ? acc[i][j][r] : xc_[(size_t)c * N + n];
            }
        }
    }
    // fused attmask: each of the 512 blocks writes 2048 upsampled elements
    {
        float rcp = 1.f / __builtin_bit_cast(float, maxv[0]);
        int bid = blockIdx.x + 32 * blockIdx.y + 128 * blockIdx.z;   // 0..511
        int base = bid * 2048;
        #pragma unroll
        for (int it = 0; it < 16; it++) {
            int idx = base + it * 128 + threadIdx.x;
            int bb = idx >> 18;
            int r = idx & 262143;
            int Y = r >> 9, X = r & 511;
            amask[idx] = vis[(size_t)bb * N + (Y >> 3) * 64 + (X >> 3)] * rcp;
        }
    }
}

// ---------------- launch ----------------
extern "C" void kernel_launch(void* const* d_in, const int* in_sizes, int n_in,
                              void* d_out, int out_size, void* d_ws, size_t ws_size,
                              hipStream_t stream)
{
    const float* x    = (const float*)d_in[0];
    const float* mask = (const float*)d_in[1];
    const float* dvt  = (const float*)d_in[2];
    const float* Kw   = (const float*)d_in[3];
    const float* Kb   = (const float*)d_in[4];
    const float* fw   = (const float*)d_in[5];
    float* out = (float*)d_out;

    char* ws = (char*)d_ws;
    float*  m    = (float*)(ws + OFF_M);
    float*  inv  = (float*)(ws + OFF_INV);
    float*  vis  = (float*)(ws + OFF_VIS);
    float*  maxv = (float*)(ws + OFF_MAXV);
    int*    cnt  = (int*)  (ws + OFF_CNT);
    int*    fgi  = (int*)  (ws + OFF_FGI);
    int*    bgi  = (int*)  (ws + OFF_BGI);
    int*    p2s  = (int*)  (ws + OFF_P2S);
    float*  kmc  = (float*)(ws + OFF_KMC);
    float*  part = (float*)(ws + OFF_PART);   // rowpart [g][64] first, colsum partials later
    ushort* Kwb  = (ushort*)(ws + OFF_KWB);
    ushort* fwb  = (ushort*)(ws + OFF_FWB);
    ushort* xT   = (ushort*)(ws + OFF_XT);
    ushort* Qc   = (ushort*)(ws + OFF_QC);
    ushort* Kcc  = (ushort*)(ws + OFF_KCC);
    ushort* xc   = (ushort*)(ws + OFF_XC);
    ushort* AFt  = (ushort*)(ws + OFF_AFT);
    ushort* P    = (ushort*)(ws + OFF_P);
    ushort* AFp  = (ushort*)(ws + OFF_AFP);

    k_prep_tr    <<<dim3(1600 + 1024), 256, 0, stream>>>(
                     mask, Kw, fw, x, m, vis, (uint*)maxv, Kwb, fwb, xT);
    k_scan       <<<dim3(BATCH), 256, 0, stream>>>(m, fgi, bgi, cnt, kmc, p2s);
    k_feats_vg   <<<dim3(256 + 256), 256, 0, stream>>>(
                     Kwb, xT, dvt, Kb, p2s, bgi, cnt, Qc, Kcc, xc);
    k_score      <<<dim3(N / 64, N / 128, BATCH), 128, 0, stream>>>(Qc, Kcc, kmc, cnt, P, part);
    k_rowinv     <<<dim3(BATCH * N / 4), 256, 0, stream>>>(part, cnt, inv);
    k_afc        <<<dim3(1024 + 256), 256, 0, stream>>>(xc, P, inv, cnt, AFp, part);
    k_afc_final  <<<dim3(4096 + 64), 256, 0, stream>>>(
                     AFp, inv, part, fgi, bgi, cnt, AFt, vis, (uint*)maxv);
    k_fused      <<<dim3(N / 128, CH / 64, BATCH), 128, 0, stream>>>(
                     fwb, AFt, xT, x, m, vis, (const uint*)maxv, out, out + (size_t)BATCH * CH * N);
}